// Round 2
// baseline (658.483 us; speedup 1.0000x reference)
//
#include <hip/hip_runtime.h>
#include <hip/hip_bf16.h>

// CrystalHypergraphConv — MI355X implementation.
//
// z[e] = A[idx0[e]] + C[idx1[e]];  A [N,256] bf16-packed; C [NHE,256]
// fp8-e4m3-packed. Lane l owns channels {2l,2l+1,128+2l,129+2l}.
//
// R18 -> R19: k_aggr restructured from 1-node-per-wave to contiguous
// edge-runs (like k_stats): each wave-slot owns all nodes whose rowptr
// start falls in its slot; per-wave setup amortized ~6.5x, 8-deep aligned
// gather prefetch, A-row prefetched one node ahead. Slot->node bounds
// precomputed in parallel (k_slots) so neither edge kernel does a serial
// binary search. BN1 C-moments moved off the edge path entirely
// (sum_e c = sum_m deg1(m)*c[m] via idx1 histogram + k_rowstats C loop);
// k_stats now accumulates only the cross term 2*sum_e a*c.

#define EPS_BN 1e-5f
#define LOG2E 1.4426950408889634f
#define LN2   0.6931471805599453f

typedef __attribute__((ext_vector_type(8))) short bf16x8;
typedef __attribute__((ext_vector_type(4))) float f32x4;
typedef __attribute__((ext_vector_type(2))) float f32x2;

__device__ __forceinline__ float fexp2(float x) {
#if __has_builtin(__builtin_amdgcn_exp2f)
    return __builtin_amdgcn_exp2f(x);
#else
    return __expf(x * LN2);
#endif
}
__device__ __forceinline__ float flog2(float x) {
#if __has_builtin(__builtin_amdgcn_logf)
    return __builtin_amdgcn_logf(x);
#else
    return __logf(x) * LOG2E;
#endif
}
__device__ __forceinline__ float softplus_fast(float x) {
    return LN2 * flog2(1.f + fexp2(x * LOG2E));
}

__device__ __forceinline__ f32x2 pk_fma2(f32x2 a, f32x2 b, f32x2 c) {
#if __has_builtin(__builtin_elementwise_fma)
    return __builtin_elementwise_fma(a, b, c);
#else
    return (f32x2){fmaf(a.x, b.x, c.x), fmaf(a.y, b.y, c.y)};
#endif
}

__device__ __forceinline__ unsigned short f2bf(float f) {
    unsigned u = __float_as_uint(f);
    unsigned r = (u + 0x7fffu + ((u >> 16) & 1u)) >> 16;   // RNE
    return (unsigned short)r;
}
__device__ __forceinline__ float bflo(unsigned u) { return __uint_as_float(u << 16); }
__device__ __forceinline__ float bfhi(unsigned u) { return __uint_as_float(u & 0xffff0000u); }
__device__ __forceinline__ float bfu16(unsigned short v) { return __uint_as_float(((unsigned)v) << 16); }
__device__ __forceinline__ unsigned pack2bf(float x, float y) {
    return (unsigned)f2bf(x) | ((unsigned)f2bf(y) << 16);
}

// ---- fp8 e4m3 encode/decode (OCP; HW path on gfx950) ----
#if __has_builtin(__builtin_amdgcn_cvt_pk_f32_fp8) && __has_builtin(__builtin_amdgcn_cvt_pk_fp8_f32)
#define HW_FP8 1
#else
#define HW_FP8 0
#endif

__device__ __forceinline__ unsigned char f2fp8(float f) {
#if HW_FP8
    int r = __builtin_amdgcn_cvt_pk_fp8_f32(f, f, 0, false);
    return (unsigned char)(r & 0xff);
#else
    unsigned u = __float_as_uint(f);
    unsigned s = (u >> 24) & 0x80u;
    float af = fabsf(f);
    if (!(af >= 0.015625f)) {
        int m = (int)rintf(af * 512.f);
        if (m > 7) m = 7;
        return (unsigned char)(s | (unsigned)m);
    }
    if (af > 448.f) return (unsigned char)(s | 0x7e);
    unsigned au = __float_as_uint(af);
    unsigned r = au + 0x7ffffu + ((au >> 20) & 1u);
    int e8 = (int)(r >> 23) - 120;
    unsigned m = (r >> 20) & 7u;
    if (e8 > 15 || (e8 == 15 && m == 7)) return (unsigned char)(s | 0x7e);
    return (unsigned char)(s | ((unsigned)e8 << 3) | m);
#endif
}

// decode packed word -> lo pair (bytes 0,1 = f channels), hi pair (bytes 2,3 = c channels)
__device__ __forceinline__ void fp8pair(unsigned p, f32x2& lo, f32x2& hi) {
#if HW_FP8
    lo = __builtin_amdgcn_cvt_pk_f32_fp8((int)p, false);
    hi = __builtin_amdgcn_cvt_pk_f32_fp8((int)p, true);
#else
    auto dec = [](unsigned byte) -> float {
        unsigned s = (byte & 0x80u) << 24;
        unsigned em = byte & 0x7fu;
        float nrm = __uint_as_float(s | ((em << 20) + 0x3C000000u));
        float sub = __uint_as_float(s | 0x3F800000u) * (float)em * 0.001953125f;
        return (em >= 8) ? nrm : sub;
    };
    lo = (f32x2){dec(p & 0xff), dec((p >> 8) & 0xff)};
    hi = (f32x2){dec((p >> 16) & 0xff), dec(p >> 24)};
#endif
}

__device__ __forceinline__ int perm256(int j) {
    return (j < 128) ? ((j >> 1) * 4 + (j & 1)) : (((j - 128) >> 1) * 4 + 2 + (j & 1));
}

// ---------------- weight prep: frag-major bf16 B tables ----------------
__global__ __launch_bounds__(256) void k_prepw(const float* __restrict__ ew, const float* __restrict__ bw,
                                               const float* __restrict__ lw,
                                               unsigned short* __restrict__ embB, unsigned short* __restrict__ bembB,
                                               unsigned short* __restrict__ waB, unsigned short* __restrict__ wcB) {
    int i = blockIdx.x * 256 + threadIdx.x;          // 0..81919
    if (i >= 81920) return;
    unsigned short* dst;
    int f, NKC, CT, mode;
    if (i < 12288)      { dst = embB;  f = i;         NKC = 3; CT = 2; mode = 0; }
    else if (i < 20480) { dst = bembB; f = i - 12288; NKC = 2; CT = 2; mode = 1; }
    else if (i < 53248) { dst = waB;   f = i - 20480; NKC = 4; CT = 4; mode = 2; }
    else                { dst = wcB;   f = i - 53248; NKC = 4; CT = 4; mode = 3; }
    int j = f & 7, l = (f >> 3) & 63;
    int r2 = f >> 9;
    int c = r2 % CT;
    int r3 = r2 / CT;
    int kc = r3 % NKC, w = r3 / NKC;
    int k = kc * 32 + ((l >> 4) & 3) * 8 + j;
    int n = (w * CT + c) * 16 + (l & 15);
    float v;
    if (mode == 0)      v = (k < 92) ? ew[k * 128 + n] : 0.f;
    else if (mode == 1) v = (k < 40) ? bw[k * 128 + n] : 0.f;
    else if (mode == 2) v = lw[k * 256 + n] + lw[(k + 256) * 256 + n];
    else                v = lw[(k + 128) * 256 + n];
    dst[f] = f2bf(v);
}

// ---------------- fused 2-stage MFMA GEMM ----------------
// OMODE2: 1 = bf16-packed A + bf16 h out; 2 = fp8-packed C out
template<int KIN, int NKC1, int OMODE2>
__global__ __launch_bounds__(256) void mfma_fused(
    const float* __restrict__ in, const unsigned short* __restrict__ B1, const float* __restrict__ bias1,
    const unsigned short* __restrict__ B2, const float* __restrict__ bias2,
    unsigned short* __restrict__ hout, void* __restrict__ out2, int M)
{
    const int r0 = blockIdx.x * 32;
    const int t = threadIdx.x;
    const int w = t >> 6;
    const int l = t & 63;
    const int m = l & 15, q = l >> 4;

    __shared__ __align__(16) unsigned short als[32 * NKC1 * 32];
    __shared__ __align__(16) unsigned short hls[32 * 136];

    const int KP = NKC1 * 32;
    for (int i = t; i < 32 * KP; i += 256) {
        int r = i / KP, k = i - r * KP;
        int gr = r0 + r;
        float v = (gr < M && k < KIN) ? in[(size_t)gr * KIN + k] : 0.f;
        int idx = (((r >> 4) * NKC1 + (k >> 5)) * 64 + ((k >> 3) & 3) * 16 + (r & 15)) * 8 + (k & 7);
        als[idx] = f2bf(v);
    }
    bf16x8 b1[NKC1][2];
    const bf16x8* B1f = (const bf16x8*)B1;
#pragma unroll
    for (int kc = 0; kc < NKC1; kc++)
#pragma unroll
        for (int c = 0; c < 2; c++)
            b1[kc][c] = B1f[((w * NKC1 + kc) * 2 + c) * 64 + l];
    __syncthreads();

    f32x4 acc1[2][2];
#pragma unroll
    for (int c = 0; c < 2; c++) { acc1[c][0] = (f32x4){0.f,0.f,0.f,0.f}; acc1[c][1] = (f32x4){0.f,0.f,0.f,0.f}; }
    const bf16x8* af = (const bf16x8*)als;
#pragma unroll
    for (int kc = 0; kc < NKC1; kc++) {
        bf16x8 a0 = af[kc * 64 + l];
        bf16x8 a1 = af[(NKC1 + kc) * 64 + l];
#pragma unroll
        for (int c = 0; c < 2; c++) {
            acc1[c][0] = __builtin_amdgcn_mfma_f32_16x16x32_bf16(a0, b1[kc][c], acc1[c][0], 0, 0, 0);
            acc1[c][1] = __builtin_amdgcn_mfma_f32_16x16x32_bf16(a1, b1[kc][c], acc1[c][1], 0, 0, 0);
        }
    }
#pragma unroll
    for (int c = 0; c < 2; c++) {
        int n1 = (w * 2 + c) * 16 + m;
        float bv = bias1[n1];
#pragma unroll
        for (int hh = 0; hh < 2; hh++) {
#pragma unroll
            for (int r = 0; r < 4; r++) {
                int row = hh * 16 + q * 4 + r;
                float val = acc1[c][hh][r] + bv;
                unsigned short bf = f2bf(val);
                hls[row * 136 + n1] = bf;
                if (OMODE2 == 1 && r0 + row < M) hout[(size_t)(r0 + row) * 128 + n1] = bf;
            }
        }
    }
    __syncthreads();

    bf16x8 b2[4][4];
    const bf16x8* B2f = (const bf16x8*)B2;
#pragma unroll
    for (int kc = 0; kc < 4; kc++)
#pragma unroll
        for (int c = 0; c < 4; c++)
            b2[kc][c] = B2f[((w * 4 + kc) * 4 + c) * 64 + l];

    f32x4 acc2[4][2];
#pragma unroll
    for (int c = 0; c < 4; c++) { acc2[c][0] = (f32x4){0.f,0.f,0.f,0.f}; acc2[c][1] = (f32x4){0.f,0.f,0.f,0.f}; }
#pragma unroll
    for (int kc = 0; kc < 4; kc++) {
        bf16x8 a0 = *(const bf16x8*)(hls + m * 136 + kc * 32 + q * 8);
        bf16x8 a1 = *(const bf16x8*)(hls + (m + 16) * 136 + kc * 32 + q * 8);
#pragma unroll
        for (int c = 0; c < 4; c++) {
            acc2[c][0] = __builtin_amdgcn_mfma_f32_16x16x32_bf16(a0, b2[kc][c], acc2[c][0], 0, 0, 0);
            acc2[c][1] = __builtin_amdgcn_mfma_f32_16x16x32_bf16(a1, b2[kc][c], acc2[c][1], 0, 0, 0);
        }
    }
#pragma unroll
    for (int c = 0; c < 4; c++) {
        int n = (w * 4 + c) * 16 + m;
        float bv = bias2 ? bias2[n] : 0.f;
        int pj = perm256(n);
#pragma unroll
        for (int hh = 0; hh < 2; hh++) {
#pragma unroll
            for (int r = 0; r < 4; r++) {
                int row = r0 + hh * 16 + q * 4 + r;
                if (row < M) {
                    float val = acc2[c][hh][r] + bv;
                    if (OMODE2 == 1) ((unsigned short*)out2)[(size_t)row * 256 + pj] = f2bf(val);
                    else             ((unsigned char*)out2)[(size_t)row * 256 + pj] = f2fp8(val);
                }
            }
        }
    }
}

// ---------------- histograms (idx0 degree, idx1 degree, graph counts) ----------------
__global__ __launch_bounds__(256) void k_hist2(const int* __restrict__ idx0, const int* __restrict__ idx1,
                                               const int* __restrict__ batch,
                                               int* __restrict__ hist, int* __restrict__ hist1,
                                               int* __restrict__ gcount, int E, int N) {
    int i = blockIdx.x * 256 + threadIdx.x;
    if (i < E) {
        atomicAdd(&hist[idx0[i]], 1);
        atomicAdd(&hist1[idx1[i]], 1);
    }
    if (i < N) atomicAdd(&gcount[batch[i]], 1);
}

// ---------------- single-block scan ----------------
__global__ __launch_bounds__(1024) void k_scanall(const int* __restrict__ hist, int* __restrict__ rowptr,
                                                  const int* __restrict__ gcount, int* __restrict__ gptr, int N) {
    __shared__ int s[1024];
    const int t = threadIdx.x;
    const int PER = (N + 1023) >> 10;
    const int b0 = t * PER;
    const int b1 = min(b0 + PER, N);
    int sum = 0;
    for (int i = b0; i < b1; i++) sum += hist[i];
    s[t] = sum;
    __syncthreads();
    for (int ofs = 1; ofs < 1024; ofs <<= 1) {
        int v = (t >= ofs) ? s[t - ofs] : 0;
        __syncthreads();
        s[t] += v;
        __syncthreads();
    }
    int run = s[t] - sum;
    for (int i = b0; i < b1; i++) {
        run += hist[i];
        rowptr[i + 1] = run;
    }
    if (t == 0) rowptr[0] = 0;
    __syncthreads();
    int gv = (t < 128) ? gcount[t] : 0;
    s[t] = gv;
    __syncthreads();
    for (int ofs = 1; ofs < 128; ofs <<= 1) {
        int v = (t >= ofs && t < 128) ? s[t - ofs] : 0;
        __syncthreads();
        if (t < 128) s[t] += v;
        __syncthreads();
    }
    if (t < 128) gptr[t + 1] = s[t];
    if (t == 0) gptr[0] = 0;
}

// ---------------- merged scatter (sidx1 stores BYTE offsets = idx1*256) ----------------
__global__ __launch_bounds__(256) void k_scatter2(const int* __restrict__ idx0, const int* __restrict__ idx1,
                                                  const int* __restrict__ batch,
                                                  const int* __restrict__ rowptr, const int* __restrict__ gptr,
                                                  int* __restrict__ fill, int* __restrict__ gfill,
                                                  int* __restrict__ sidx1, int* __restrict__ gnodes, int E, int N) {
    int i = blockIdx.x * 256 + threadIdx.x;
    if (i < E) {
        int n = idx0[i];
        int pos = rowptr[n] + atomicAdd(&fill[n], 1);
        sidx1[pos] = idx1[i] << 8;                       // byte offset of the 256B fp8 row
    }
    if (i < N) {
        int g = batch[i];
        int pos = gptr[g] + atomicAdd(&gfill[g], 1);
        gnodes[pos] = i;
    }
}

// ---------------- slot -> node-bound table (kills per-wave binary searches) ----------------
// slots[s].x = min n with rowptr[n] >= s*per_slot   (N sentinel when s*per_slot >= E)
// slots[s].y = max n with rowptr[n] <= s*per_slot   (k_stats start node)
__global__ __launch_bounds__(256) void k_slots(const int* __restrict__ rowptr, int2* __restrict__ slots,
                                               int E, int N, int per_slot, int nslots) {
    int s = blockIdx.x * 256 + threadIdx.x;
    if (s > nslots) return;
    long base = (long)s * per_slot;
    if (base >= E) { slots[s] = (int2){N, N - 1}; return; }
    int e0 = (int)base;
    int lo = 0, hi = N;
    while (lo + 1 < hi) { int mid = (lo + hi) >> 1; if (rowptr[mid] <= e0) lo = mid; else hi = mid; }
    int nS = lo;
    int nA = 0;
    if (e0 > 0) {
        lo = 0; hi = N;
        while (lo + 1 < hi) { int mid = (lo + hi) >> 1; if (rowptr[mid] < e0) lo = mid; else hi = mid; }
        nA = hi;
    }
    slots[s] = (int2){nA, nS};
}

// ---------------- deg-weighted moments: sum(deg0*a), sum(deg0*a^2), sum(deg1*c), sum(deg1*c^2) ----------------
__global__ __launch_bounds__(256) void k_rowstats(const uint2* __restrict__ A16, const unsigned* __restrict__ Cp8,
                                                  const int* __restrict__ hist0, const int* __restrict__ hist1,
                                                  float* __restrict__ gsum, float* __restrict__ gsq,
                                                  int N, int NHE) {
    __shared__ float4 lsm4[256], lsq4[256];
    const int t = threadIdx.x;
    const int s = t >> 6, l = t & 63;
    const int w0 = blockIdx.x * 4 + s;
    const int nw = gridDim.x * 4;
    f32x2 smF = {0.f,0.f}, smC = {0.f,0.f}, sqF = {0.f,0.f}, sqC = {0.f,0.f};
    for (int n = w0; n < N; n += nw) {
        float dg = (float)hist0[n];
        uint2 a8 = A16[(size_t)n * 64 + l];
        f32x2 aF = {bflo(a8.x), bfhi(a8.x)};
        f32x2 aC = {bflo(a8.y), bfhi(a8.y)};
        f32x2 dF = aF * dg;
        f32x2 dC = aC * dg;
        smF += dF; smC += dC;
        sqF = pk_fma2(dF, aF, sqF);
        sqC = pk_fma2(dC, aC, sqC);
    }
    for (int m = w0; m < NHE; m += nw) {
        float dg = (float)hist1[m];
        unsigned p = Cp8[(size_t)m * 64 + l];
        f32x2 vf, vc;
        fp8pair(p, vf, vc);
        f32x2 dF = vf * dg;
        f32x2 dC = vc * dg;
        smF += dF; smC += dC;
        sqF = pk_fma2(dF, vf, sqF);
        sqC = pk_fma2(dC, vc, sqC);
    }
    lsm4[t] = (float4){smF.x, smF.y, smC.x, smC.y};
    lsq4[t] = (float4){sqF.x, sqF.y, sqC.x, sqC.y};
    __syncthreads();
    const float* fm = (const float*)lsm4;
    const float* fq = (const float*)lsq4;
    float vs = fm[t] + fm[256 + t] + fm[512 + t] + fm[768 + t];
    float vq = fq[t] + fq[256 + t] + fq[512 + t] + fq[768 + t];
    atomicAdd(&gsum[t], vs);
    atomicAdd(&gsq[t], vq);
}

// ---------------- BN1 cross term only: 2*sum_e a[idx0]*c[idx1] ----------------
// Per-edge body: decode + 2 pk_add (csr); cross fma amortized at run flush.
__global__ __launch_bounds__(256) void k_stats(const uint2* __restrict__ A16, const unsigned char* __restrict__ Cp8b,
                                               const int* __restrict__ rowptr, const int* __restrict__ sidx1,
                                               const int2* __restrict__ slots,
                                               float* __restrict__ gsq, int E, int N, int per_slot) {
    __shared__ float4 lsq4[256];
    const int t = threadIdx.x;
    const int s = t >> 6, l = t & 63;
    const int slot = blockIdx.x * 4 + s;
    const unsigned lo4 = (unsigned)(l << 2);
    const long base = (long)slot * per_slot;
    const int e0 = (int)min((long)E, base);
    const int e1 = (int)min((long)E, base + per_slot);
    f32x2 sqF = {0.f,0.f}, sqC = {0.f,0.f};
    f32x2 csrF = {0.f,0.f}, csrC = {0.f,0.f};
    f32x2 aF2 = {0.f,0.f}, aC2 = {0.f,0.f};        // 2*a of current node
    int cur_n = 0, bound = 0;

    auto flush = [&]() {
        sqF = pk_fma2(aF2, csrF, sqF);
        sqC = pk_fma2(aC2, csrC, sqC);
        csrF = (f32x2){0.f,0.f}; csrC = (f32x2){0.f,0.f};
    };
    auto loadA = [&](int n) {
        uint2 a8 = A16[(size_t)n * 64 + l];
        aF2 = (f32x2){bflo(a8.x) * 2.f, bfhi(a8.x) * 2.f};
        aC2 = (f32x2){bflo(a8.y) * 2.f, bfhi(a8.y) * 2.f};
    };

    if (e0 < e1) {
        cur_n = slots[slot].y;
        bound = rowptr[cur_n + 1];
        loadA(cur_n);
    }

    auto proc = [&](int e, unsigned p) {
        if (e >= bound) {                            // wave-uniform
            flush();
            do { cur_n++; bound = rowptr[cur_n + 1]; } while (bound <= e);
            loadA(cur_n);
        }
        f32x2 vf, vc;
        fp8pair(p, vf, vc);
        csrF += vf; csrC += vc;
    };

    int e = e0;
    for (; e + 8 <= e1; e += 8) {
        int4 mm0 = *(const int4*)(sidx1 + e);
        int4 mm1 = *(const int4*)(sidx1 + e + 4);
        unsigned p0 = *(const unsigned*)(Cp8b + ((unsigned)mm0.x + lo4));
        unsigned p1 = *(const unsigned*)(Cp8b + ((unsigned)mm0.y + lo4));
        unsigned p2 = *(const unsigned*)(Cp8b + ((unsigned)mm0.z + lo4));
        unsigned p3 = *(const unsigned*)(Cp8b + ((unsigned)mm0.w + lo4));
        unsigned p4 = *(const unsigned*)(Cp8b + ((unsigned)mm1.x + lo4));
        unsigned p5 = *(const unsigned*)(Cp8b + ((unsigned)mm1.y + lo4));
        unsigned p6 = *(const unsigned*)(Cp8b + ((unsigned)mm1.z + lo4));
        unsigned p7 = *(const unsigned*)(Cp8b + ((unsigned)mm1.w + lo4));
        proc(e, p0); proc(e + 1, p1); proc(e + 2, p2); proc(e + 3, p3);
        proc(e + 4, p4); proc(e + 5, p5); proc(e + 6, p6); proc(e + 7, p7);
    }
    for (; e < e1; e++) proc(e, *(const unsigned*)(Cp8b + ((unsigned)sidx1[e] + lo4)));
    flush();

    lsq4[t] = (float4){sqF.x, sqF.y, sqC.x, sqC.y};
    __syncthreads();
    const float* fq = (const float*)lsq4;
    float vq = fq[t] + fq[256 + t] + fq[512 + t] + fq[768 + t];
    atomicAdd(&gsq[t], vq);
}

// ---------------- fused BN1-finalize + msg + segment softmax ----------------
// Run-based: each wave-slot owns nodes n with rowptr[n] in [e0, e0+per_slot)
// (last real slot also owns trailing empty nodes). Contiguous edge stream
// with 8-wide aligned gather prefetch; A-row prefetched one node ahead.
__global__ __launch_bounds__(256) void k_aggr(const uint2* __restrict__ A16, const unsigned char* __restrict__ Cp8b,
                                              const int* __restrict__ rowptr, const int* __restrict__ sidx1,
                                              const int2* __restrict__ slots,
                                              const float* __restrict__ bn1_sum, const float* __restrict__ bn1_sq,
                                              const float* __restrict__ g1, const float* __restrict__ b1,
                                              const float* __restrict__ tptr, unsigned* __restrict__ out,
                                              float invE, int E, int N, int per_slot) {
    const int t = threadIdx.x;
    const int slot = blockIdx.x * 4 + (t >> 6);
    const int l = t & 63;
    const long base = (long)slot * per_slot;
    if (base >= E) return;
    const int n_first = slots[slot].x;
    const int n_last  = slots[slot + 1].x - 1;       // includes trailing empties for last real slot
    if (n_first > n_last) return;                    // spanning node covers whole slot

    const float tt = tptr[0];
    const float4 sum4 = ((const float4*)bn1_sum)[l];
    const float4 sq4  = ((const float4*)bn1_sq)[l];
    const float2 gf = ((const float2*)g1)[l];
    const float2 gc = ((const float2*)(g1 + 128))[l];
    const float2 bf2 = ((const float2*)b1)[l];
    const float2 bc2 = ((const float2*)(b1 + 128))[l];
    auto mkss = [&](float sum, float sq, float gg, float bb, float& sc, float& sh) {
        float mu = sum * invE;
        float var = sq * invE - mu * mu;
        sc = gg * rsqrtf(var + EPS_BN);
        sh = fmaf(-mu, sc, bb);
    };
    float scx, shx, scy, shy, scz, shz, scw, shw;
    mkss(sum4.x, sq4.x, gf.x, bf2.x, scx, shx);
    mkss(sum4.y, sq4.y, gf.y, bf2.y, scy, shy);
    mkss(sum4.z, sq4.z, gc.x, bc2.x, scz, shz);
    mkss(sum4.w, sq4.w, gc.y, bc2.y, scw, shw);
    const f32x2 sF  = {-scx * LOG2E, -scy * LOG2E};
    const f32x2 bsF = {-shx * LOG2E, -shy * LOG2E};
    const f32x2 sC  = { scz * LOG2E,  scw * LOG2E};
    const f32x2 bsC = { shz * LOG2E,  shw * LOG2E};
    const unsigned lo4 = (unsigned)(l << 2);

    int nc = n_first;
    uint2 aNx = A16[(size_t)nc * 64 + l];
    f32x2 bF, bC;
    auto consumeA = [&]() {
        f32x2 aF = {bflo(aNx.x), bfhi(aNx.x)};
        f32x2 aC = {bflo(aNx.y), bfhi(aNx.y)};
        bF = pk_fma2(aF, sF, bsF);
        bC = pk_fma2(aC, sC, bsC);
    };
    consumeA();
    if (nc < n_last) aNx = A16[(size_t)(nc + 1) * 64 + l];
    int bound = rowptr[nc + 1];
    f32x2 den = {0.f, 0.f}, num = {0.f, 0.f};

    auto finalize = [&]() {
        float ox = den.x != 0.f ? LN2 * num.x * __builtin_amdgcn_rcpf(den.x) : 0.f;
        float oy = den.y != 0.f ? LN2 * num.y * __builtin_amdgcn_rcpf(den.y) : 0.f;
        out[(size_t)nc * 64 + l] = pack2bf(ox, oy);
    };

    auto proc = [&](int e, unsigned p) {
        if (e >= bound) {                            // wave-uniform node switch
            finalize();
            den = (f32x2){0.f, 0.f}; num = (f32x2){0.f, 0.f};
            for (;;) {
                nc++;
                consumeA();
                if (nc < n_last) aNx = A16[(size_t)(nc + 1) * 64 + l];
                bound = rowptr[nc + 1];
                if (bound > e) break;
                out[(size_t)nc * 64 + l] = 0u;       // empty node
            }
        }
        f32x2 vf, vc;
        fp8pair(p, vf, vc);
        f32x2 argf = pk_fma2(vf, sF, bF);            // -zf_hat * log2e
        f32x2 argc = pk_fma2(vc, sC, bC);            //  zc_hat * log2e
        f32x2 ef = {fexp2(argf.x), fexp2(argf.y)};
        f32x2 uu = {fexp2(argc.x), fexp2(argc.y)};
        f32x2 d1 = ef + 1.f;
        f32x2 u1 = uu + 1.f;
        f32x2 sig = {__builtin_amdgcn_rcpf(d1.x), __builtin_amdgcn_rcpf(d1.y)};
        f32x2 lg = {flog2(u1.x), flog2(u1.y)};
        f32x2 M = sig * lg;
        f32x2 tM = M * tt;
        f32x2 w = {fexp2(tM.x), fexp2(tM.y)};
        den += w;
        num = pk_fma2(M, w, num);
    };

    const int eb0 = rowptr[n_first];
    const int eb1 = rowptr[n_last + 1];
    if (eb0 < eb1) {
        int eb = eb0 & ~7;
        int lo = eb0 - eb;
        int hi = min(eb1 - eb, 8);
        int4 m0 = *(const int4*)(sidx1 + eb);
        int4 m1 = *(const int4*)(sidx1 + eb + 4);
        unsigned g[8];
        {
            int mi[8] = {m0.x, m0.y, m0.z, m0.w, m1.x, m1.y, m1.z, m1.w};
#pragma unroll
            for (int i = 0; i < 8; i++)
                if (i >= lo && i < hi) g[i] = *(const unsigned*)(Cp8b + ((unsigned)mi[i] + lo4));
        }
        for (;;) {
            int ebn = eb + 8;
            bool more = ebn < eb1;
            unsigned gn[8];
            int nhi = 0;
            if (more) {
                int4 t0 = *(const int4*)(sidx1 + ebn);
                int4 t1 = *(const int4*)(sidx1 + ebn + 4);
                int mn[8] = {t0.x, t0.y, t0.z, t0.w, t1.x, t1.y, t1.z, t1.w};
                nhi = min(eb1 - ebn, 8);
#pragma unroll
                for (int i = 0; i < 8; i++)
                    if (i < nhi) gn[i] = *(const unsigned*)(Cp8b + ((unsigned)mn[i] + lo4));
            }
#pragma unroll
            for (int i = 0; i < 8; i++)
                if (i >= lo && i < hi) proc(eb + i, g[i]);
            if (!more) break;
#pragma unroll
            for (int i = 0; i < 8; i++) g[i] = gn[i];
            eb = ebn; lo = 0; hi = nhi;
        }
    }
    finalize();                                      // last non-empty (or lone empty) node
    while (nc < n_last) { nc++; out[(size_t)nc * 64 + l] = 0u; }   // trailing empties
}

// ---------------- BN2 stats (bf16 outbuf) ----------------
__global__ __launch_bounds__(128) void k_bn2stats(const unsigned short* __restrict__ out, float* __restrict__ sum,
                                                  float* __restrict__ sq, int N) {
    const int c = threadIdx.x;
    const int n0 = blockIdx.x * 64;
    const int nend = min(n0 + 64, N);
    float sm = 0.f, s2 = 0.f;
    for (int n = n0; n < nend; n++) {
        float v = bfu16(out[(size_t)n * 128 + c]);
        sm += v;
        s2 = fmaf(v, v, s2);
    }
    atomicAdd(&sum[c], sm);
    atomicAdd(&sq[c], s2);
}

// ---------------- fused BN2-finalize + residual+softplus + mean-pool (bf16 inputs) ----------------
template<int SPLIT>
__global__ __launch_bounds__(128) void k_h2pool(const unsigned short* __restrict__ out,
                                                const unsigned short* __restrict__ h,
                                                const int* __restrict__ gptr, const int* __restrict__ gnodes,
                                                const float* __restrict__ bn2_sum, const float* __restrict__ bn2_sq,
                                                const float* __restrict__ g2, const float* __restrict__ b2,
                                                float* __restrict__ pooled, float invN) {
    const int g = blockIdx.x & 127;
    const int sp = blockIdx.x >> 7;
    const int c = threadIdx.x;
    float mu = bn2_sum[c] * invN;
    float var = bn2_sq[c] * invN - mu * mu;
    float sc = g2[c] * rsqrtf(var + EPS_BN);
    float sh = fmaf(-mu, sc, b2[c]);
    const int i0 = gptr[g], i1 = gptr[g + 1];
    float acc = 0.f;
    for (int i = i0 + sp; i < i1; i += SPLIT) {
        int n = gnodes[i];
        float v = fmaf(bfu16(out[(size_t)n * 128 + c]), sc, sh) + bfu16(h[(size_t)n * 128 + c]);
        acc += softplus_fast(v);
    }
    if (acc != 0.f) atomicAdd(&pooled[g * 128 + c], acc);
}

// ---------------- head ----------------
__global__ __launch_bounds__(256) void k_head(const float* __restrict__ pooled, const int* __restrict__ gcount,
                                              const float* __restrict__ l1w, const float* __restrict__ l1b,
                                              const float* __restrict__ outw, const float* __restrict__ outb,
                                              float* __restrict__ dout) {
    __shared__ float p[128];
    __shared__ float red[256];
    const int g = blockIdx.x;
    const int j = threadIdx.x;
    if (j < 128) {
        float cnt = (float)max(gcount[g], 1);
        p[j] = pooled[g * 128 + j] / cnt;
    }
    __syncthreads();
    float acc = l1b[j];
    for (int k = 0; k < 128; k++) acc = fmaf(p[k], l1w[k * 256 + j], acc);
    red[j] = softplus_fast(acc) * outw[j];
    __syncthreads();
    for (int s = 128; s > 0; s >>= 1) {
        if (j < s) red[j] += red[j + s];
        __syncthreads();
    }
    if (j == 0) dout[g] = red[0] + outb[0];
}

// ---------------- launch ----------------
extern "C" void kernel_launch(void* const* d_in, const int* in_sizes, int n_in,
                              void* d_out, int out_size, void* d_ws, size_t ws_size,
                              hipStream_t stream) {
    const float* x        = (const float*)d_in[0];
    const float* hedge    = (const float*)d_in[1];
    const int*   iri      = (const int*)d_in[2];
    const int*   batch    = (const int*)d_in[3];
    const float* embed_w  = (const float*)d_in[5];
    const float* embed_b  = (const float*)d_in[6];
    const float* bembed_w = (const float*)d_in[7];
    const float* bembed_b = (const float*)d_in[8];
    const float* lin_w    = (const float*)d_in[9];
    const float* lin_b    = (const float*)d_in[10];
    const float* bn1_g    = (const float*)d_in[11];
    const float* bn1_b    = (const float*)d_in[12];
    const float* bn2_g    = (const float*)d_in[13];
    const float* bn2_b    = (const float*)d_in[14];
    const float* aggr_t   = (const float*)d_in[15];
    const float* l1_w     = (const float*)d_in[16];
    const float* l1_b     = (const float*)d_in[17];
    const float* out_w    = (const float*)d_in[18];
    const float* out_b    = (const float*)d_in[19];

    const int N   = in_sizes[0] / 92;
    const int NHE = in_sizes[1] / 40;
    const int E   = in_sizes[2] / 3;
    const int* idx0 = iri;
    const int* idx1 = iri + E;

    float* ws = (float*)d_ws;
    size_t off = 0;
    auto alloc = [&](size_t elems) -> float* {
        float* p = ws + off;
        off += (elems + 63) & ~(size_t)63;
        return p;
    };
    unsigned short* h16 = (unsigned short*)alloc((size_t)N * 64);   // N*128 bf16
    uint2* A16    = (uint2*)alloc((size_t)N * 128);                 // N*256 bf16 packed
    unsigned* Cp8 = (unsigned*)alloc((size_t)NHE * 64);             // NHE*256 fp8 packed
    unsigned short* embB  = (unsigned short*)alloc(6144);
    unsigned short* bembB = (unsigned short*)alloc(4096);
    unsigned short* waB   = (unsigned short*)alloc(16384);
    unsigned short* wcB   = (unsigned short*)alloc(16384);
    int*   rowptr = (int*)alloc((size_t)N + 1);
    int*   sidx1  = (int*)alloc((size_t)E + 8);
    int*   gptr   = (int*)alloc(129);
    int*   gnodes = (int*)alloc((size_t)N);
    unsigned* outbuf = (unsigned*)alloc((size_t)N * 64);            // N*128 bf16
    int2*  slots  = (int2*)alloc(2 * 8200);                         // slot->node bounds (+sentinel)
    // contiguous zero region
    float* zbase  = ws + off;
    int*   hist   = (int*)alloc((size_t)N);
    int*   hist1  = (int*)alloc((size_t)NHE);
    int*   fill   = (int*)alloc((size_t)N);
    int*   gfill  = (int*)alloc(128);
    float* bn1_sum = alloc(256);
    float* bn1_sq  = alloc(256);
    float* bn2_sum = alloc(128);
    float* bn2_sq  = alloc(128);
    float* pooled  = alloc(128 * 128);
    int*   gcount  = (int*)alloc(128);
    size_t zbytes = (size_t)((ws + off) - zbase) * sizeof(float);
    (void)ws_size;  // ~78MB; fit verified

    hipMemsetAsync(zbase, 0, zbytes, stream);

    // frag-major bf16 weight prep + fused MFMA GEMM chains
    k_prepw<<<320, 256, 0, stream>>>(embed_w, bembed_w, lin_w, embB, bembB, waB, wcB);
    const int mtN   = (N + 31) / 32;
    const int mtNHE = (NHE + 31) / 32;
    mfma_fused<92, 3, 1><<<mtN, 256, 0, stream>>>(x, embB, embed_b, waB, lin_b, h16, A16, N);
    mfma_fused<40, 2, 2><<<mtNHE, 256, 0, stream>>>(hedge, bembB, bembed_b, wcB, nullptr, nullptr, Cp8, NHE);

    // CSR build
    k_hist2<<<(E + 255) / 256, 256, 0, stream>>>(idx0, idx1, batch, hist, hist1, gcount, E, N);
    k_scanall<<<1, 1024, 0, stream>>>(hist, rowptr, gcount, gptr, N);
    k_scatter2<<<(E + 255) / 256, 256, 0, stream>>>(idx0, idx1, batch, rowptr, gptr,
                                                    fill, gfill, sidx1, gnodes, E, N);

    // unified slot geometry for both edge kernels (8 | per_slot)
    const int EDGE_BLOCKS = 2048;
    const int NSLOTS = EDGE_BLOCKS * 4;
    int per_slot = ((E + NSLOTS - 1) / NSLOTS + 7) & ~7;
    int nslots_used = (E + per_slot - 1) / per_slot;
    k_slots<<<(nslots_used + 1 + 255) / 256, 256, 0, stream>>>(rowptr, slots, E, N, per_slot, nslots_used);

    // BN1 stats: deg-weighted A/C moments (row streams) + cross term (edge pass)
    k_rowstats<<<256, 256, 0, stream>>>(A16, Cp8, hist, hist1, bn1_sum, bn1_sq, N, NHE);
    k_stats<<<EDGE_BLOCKS, 256, 0, stream>>>(A16, (const unsigned char*)Cp8, rowptr, sidx1, slots,
                                             bn1_sq, E, N, per_slot);

    // fused BN1-finalize + message + softmax aggregation (run-based)
    k_aggr<<<EDGE_BLOCKS, 256, 0, stream>>>(A16, (const unsigned char*)Cp8, rowptr, sidx1, slots,
                                            bn1_sum, bn1_sq, bn1_g, bn1_b, aggr_t, outbuf,
                                            1.0f / (float)E, E, N, per_slot);

    // BN2 stats + fused finalize/residual/softplus/pool
    k_bn2stats<<<(N + 63) / 64, 128, 0, stream>>>((const unsigned short*)outbuf, bn2_sum, bn2_sq, N);
    k_h2pool<16><<<128 * 16, 128, 0, stream>>>((const unsigned short*)outbuf, h16, gptr, gnodes,
                                               bn2_sum, bn2_sq, bn2_g, bn2_b, pooled, 1.0f / (float)N);

    // head
    k_head<<<128, 256, 0, stream>>>(pooled, gcount, l1_w, l1_b, out_w, out_b, (float*)d_out);
}

// Round 3
// 603.258 us; speedup vs baseline: 1.0915x; 1.0915x over previous
//
#include <hip/hip_runtime.h>
#include <hip/hip_bf16.h>

// CrystalHypergraphConv — MI355X implementation.
//
// z[e] = A[idx0[e]] + C[idx1[e]];  A [N,256] bf16-packed; C [NHE,256]
// fp8-e4m3-packed. Lane l owns channels {2l,2l+1,128+2l,129+2l}.
//
// R19 -> R20:
//  - REVERT hist1/deg1-weighted C moments (R19's k_hist2 doubled memory-side
//    atomic writeback 25->50MB, +50us; k_stats is gather-bound so the VALU
//    it saved was free anyway). k_stats again accumulates sum(c), sum(c^2)
//    and the cross term per edge-run.
//  - k_hist2 deleted: hist0 atomics folded into mfma_fused<92> prologue,
//    gcount atomics into mfma_fused<40> prologue. Fire-and-forget atomics
//    issue before the GEMM and drain under the MFMA work (overlap without
//    multi-stream, which graph capture + no-hipEvent forbids).
//  - scatter2 + slots + rowstats merged into one k_build kernel
//    (block-range dispatch): all depend only on rowptr + GEMM outputs,
//    so their latency sinks co-schedule.

#define EPS_BN 1e-5f
#define LOG2E 1.4426950408889634f
#define LN2   0.6931471805599453f

typedef __attribute__((ext_vector_type(8))) short bf16x8;
typedef __attribute__((ext_vector_type(4))) float f32x4;
typedef __attribute__((ext_vector_type(2))) float f32x2;

__device__ __forceinline__ float fexp2(float x) {
#if __has_builtin(__builtin_amdgcn_exp2f)
    return __builtin_amdgcn_exp2f(x);
#else
    return __expf(x * LN2);
#endif
}
__device__ __forceinline__ float flog2(float x) {
#if __has_builtin(__builtin_amdgcn_logf)
    return __builtin_amdgcn_logf(x);
#else
    return __logf(x) * LOG2E;
#endif
}
__device__ __forceinline__ float softplus_fast(float x) {
    return LN2 * flog2(1.f + fexp2(x * LOG2E));
}

__device__ __forceinline__ f32x2 pk_fma2(f32x2 a, f32x2 b, f32x2 c) {
#if __has_builtin(__builtin_elementwise_fma)
    return __builtin_elementwise_fma(a, b, c);
#else
    return (f32x2){fmaf(a.x, b.x, c.x), fmaf(a.y, b.y, c.y)};
#endif
}

__device__ __forceinline__ unsigned short f2bf(float f) {
    unsigned u = __float_as_uint(f);
    unsigned r = (u + 0x7fffu + ((u >> 16) & 1u)) >> 16;   // RNE
    return (unsigned short)r;
}
__device__ __forceinline__ float bflo(unsigned u) { return __uint_as_float(u << 16); }
__device__ __forceinline__ float bfhi(unsigned u) { return __uint_as_float(u & 0xffff0000u); }
__device__ __forceinline__ float bfu16(unsigned short v) { return __uint_as_float(((unsigned)v) << 16); }
__device__ __forceinline__ unsigned pack2bf(float x, float y) {
    return (unsigned)f2bf(x) | ((unsigned)f2bf(y) << 16);
}

// ---- fp8 e4m3 encode/decode (OCP; HW path on gfx950) ----
#if __has_builtin(__builtin_amdgcn_cvt_pk_f32_fp8) && __has_builtin(__builtin_amdgcn_cvt_pk_fp8_f32)
#define HW_FP8 1
#else
#define HW_FP8 0
#endif

__device__ __forceinline__ unsigned char f2fp8(float f) {
#if HW_FP8
    int r = __builtin_amdgcn_cvt_pk_fp8_f32(f, f, 0, false);
    return (unsigned char)(r & 0xff);
#else
    unsigned u = __float_as_uint(f);
    unsigned s = (u >> 24) & 0x80u;
    float af = fabsf(f);
    if (!(af >= 0.015625f)) {
        int m = (int)rintf(af * 512.f);
        if (m > 7) m = 7;
        return (unsigned char)(s | (unsigned)m);
    }
    if (af > 448.f) return (unsigned char)(s | 0x7e);
    unsigned au = __float_as_uint(af);
    unsigned r = au + 0x7ffffu + ((au >> 20) & 1u);
    int e8 = (int)(r >> 23) - 120;
    unsigned m = (r >> 20) & 7u;
    if (e8 > 15 || (e8 == 15 && m == 7)) return (unsigned char)(s | 0x7e);
    return (unsigned char)(s | ((unsigned)e8 << 3) | m);
#endif
}

// decode packed word -> lo pair (bytes 0,1 = f channels), hi pair (bytes 2,3 = c channels)
__device__ __forceinline__ void fp8pair(unsigned p, f32x2& lo, f32x2& hi) {
#if HW_FP8
    lo = __builtin_amdgcn_cvt_pk_f32_fp8((int)p, false);
    hi = __builtin_amdgcn_cvt_pk_f32_fp8((int)p, true);
#else
    auto dec = [](unsigned byte) -> float {
        unsigned s = (byte & 0x80u) << 24;
        unsigned em = byte & 0x7fu;
        float nrm = __uint_as_float(s | ((em << 20) + 0x3C000000u));
        float sub = __uint_as_float(s | 0x3F800000u) * (float)em * 0.001953125f;
        return (em >= 8) ? nrm : sub;
    };
    lo = (f32x2){dec(p & 0xff), dec((p >> 8) & 0xff)};
    hi = (f32x2){dec((p >> 16) & 0xff), dec(p >> 24)};
#endif
}

__device__ __forceinline__ int perm256(int j) {
    return (j < 128) ? ((j >> 1) * 4 + (j & 1)) : (((j - 128) >> 1) * 4 + 2 + (j & 1));
}

// ---------------- weight prep: frag-major bf16 B tables ----------------
__global__ __launch_bounds__(256) void k_prepw(const float* __restrict__ ew, const float* __restrict__ bw,
                                               const float* __restrict__ lw,
                                               unsigned short* __restrict__ embB, unsigned short* __restrict__ bembB,
                                               unsigned short* __restrict__ waB, unsigned short* __restrict__ wcB) {
    int i = blockIdx.x * 256 + threadIdx.x;          // 0..81919
    if (i >= 81920) return;
    unsigned short* dst;
    int f, NKC, CT, mode;
    if (i < 12288)      { dst = embB;  f = i;         NKC = 3; CT = 2; mode = 0; }
    else if (i < 20480) { dst = bembB; f = i - 12288; NKC = 2; CT = 2; mode = 1; }
    else if (i < 53248) { dst = waB;   f = i - 20480; NKC = 4; CT = 4; mode = 2; }
    else                { dst = wcB;   f = i - 53248; NKC = 4; CT = 4; mode = 3; }
    int j = f & 7, l = (f >> 3) & 63;
    int r2 = f >> 9;
    int c = r2 % CT;
    int r3 = r2 / CT;
    int kc = r3 % NKC, w = r3 / NKC;
    int k = kc * 32 + ((l >> 4) & 3) * 8 + j;
    int n = (w * CT + c) * 16 + (l & 15);
    float v;
    if (mode == 0)      v = (k < 92) ? ew[k * 128 + n] : 0.f;
    else if (mode == 1) v = (k < 40) ? bw[k * 128 + n] : 0.f;
    else if (mode == 2) v = lw[k * 256 + n] + lw[(k + 256) * 256 + n];
    else                v = lw[(k + 128) * 256 + n];
    dst[f] = f2bf(v);
}

// ---------------- fused 2-stage MFMA GEMM (+ histogram atomic prologue) ----------------
// OMODE2: 1 = bf16-packed A + bf16 h out; 2 = fp8-packed C out
// aux: fire-and-forget histogram atomics (hist0 for GEMM1, gcount for GEMM2);
// they issue before the GEMM and drain under the MFMA work.
template<int KIN, int NKC1, int OMODE2>
__global__ __launch_bounds__(256) void mfma_fused(
    const float* __restrict__ in, const unsigned short* __restrict__ B1, const float* __restrict__ bias1,
    const unsigned short* __restrict__ B2, const float* __restrict__ bias2,
    unsigned short* __restrict__ hout, void* __restrict__ out2, int M,
    const int* __restrict__ aux_idx, int* __restrict__ aux_hist, int aux_cnt)
{
    const int r0 = blockIdx.x * 32;
    const int t = threadIdx.x;
    const int w = t >> 6;
    const int l = t & 63;
    const int m = l & 15, q = l >> 4;

    if (aux_idx) {
        const int T = gridDim.x * 256;
        for (int i = blockIdx.x * 256 + t; i < aux_cnt; i += T)
            atomicAdd(&aux_hist[aux_idx[i]], 1);
    }

    __shared__ __align__(16) unsigned short als[32 * NKC1 * 32];
    __shared__ __align__(16) unsigned short hls[32 * 136];

    const int KP = NKC1 * 32;
    for (int i = t; i < 32 * KP; i += 256) {
        int r = i / KP, k = i - r * KP;
        int gr = r0 + r;
        float v = (gr < M && k < KIN) ? in[(size_t)gr * KIN + k] : 0.f;
        int idx = (((r >> 4) * NKC1 + (k >> 5)) * 64 + ((k >> 3) & 3) * 16 + (r & 15)) * 8 + (k & 7);
        als[idx] = f2bf(v);
    }
    bf16x8 b1[NKC1][2];
    const bf16x8* B1f = (const bf16x8*)B1;
#pragma unroll
    for (int kc = 0; kc < NKC1; kc++)
#pragma unroll
        for (int c = 0; c < 2; c++)
            b1[kc][c] = B1f[((w * NKC1 + kc) * 2 + c) * 64 + l];
    __syncthreads();

    f32x4 acc1[2][2];
#pragma unroll
    for (int c = 0; c < 2; c++) { acc1[c][0] = (f32x4){0.f,0.f,0.f,0.f}; acc1[c][1] = (f32x4){0.f,0.f,0.f,0.f}; }
    const bf16x8* af = (const bf16x8*)als;
#pragma unroll
    for (int kc = 0; kc < NKC1; kc++) {
        bf16x8 a0 = af[kc * 64 + l];
        bf16x8 a1 = af[(NKC1 + kc) * 64 + l];
#pragma unroll
        for (int c = 0; c < 2; c++) {
            acc1[c][0] = __builtin_amdgcn_mfma_f32_16x16x32_bf16(a0, b1[kc][c], acc1[c][0], 0, 0, 0);
            acc1[c][1] = __builtin_amdgcn_mfma_f32_16x16x32_bf16(a1, b1[kc][c], acc1[c][1], 0, 0, 0);
        }
    }
#pragma unroll
    for (int c = 0; c < 2; c++) {
        int n1 = (w * 2 + c) * 16 + m;
        float bv = bias1[n1];
#pragma unroll
        for (int hh = 0; hh < 2; hh++) {
#pragma unroll
            for (int r = 0; r < 4; r++) {
                int row = hh * 16 + q * 4 + r;
                float val = acc1[c][hh][r] + bv;
                unsigned short bf = f2bf(val);
                hls[row * 136 + n1] = bf;
                if (OMODE2 == 1 && r0 + row < M) hout[(size_t)(r0 + row) * 128 + n1] = bf;
            }
        }
    }
    __syncthreads();

    bf16x8 b2[4][4];
    const bf16x8* B2f = (const bf16x8*)B2;
#pragma unroll
    for (int kc = 0; kc < 4; kc++)
#pragma unroll
        for (int c = 0; c < 4; c++)
            b2[kc][c] = B2f[((w * 4 + kc) * 4 + c) * 64 + l];

    f32x4 acc2[4][2];
#pragma unroll
    for (int c = 0; c < 4; c++) { acc2[c][0] = (f32x4){0.f,0.f,0.f,0.f}; acc2[c][1] = (f32x4){0.f,0.f,0.f,0.f}; }
#pragma unroll
    for (int kc = 0; kc < 4; kc++) {
        bf16x8 a0 = *(const bf16x8*)(hls + m * 136 + kc * 32 + q * 8);
        bf16x8 a1 = *(const bf16x8*)(hls + (m + 16) * 136 + kc * 32 + q * 8);
#pragma unroll
        for (int c = 0; c < 4; c++) {
            acc2[c][0] = __builtin_amdgcn_mfma_f32_16x16x32_bf16(a0, b2[kc][c], acc2[c][0], 0, 0, 0);
            acc2[c][1] = __builtin_amdgcn_mfma_f32_16x16x32_bf16(a1, b2[kc][c], acc2[c][1], 0, 0, 0);
        }
    }
#pragma unroll
    for (int c = 0; c < 4; c++) {
        int n = (w * 4 + c) * 16 + m;
        float bv = bias2 ? bias2[n] : 0.f;
        int pj = perm256(n);
#pragma unroll
        for (int hh = 0; hh < 2; hh++) {
#pragma unroll
            for (int r = 0; r < 4; r++) {
                int row = r0 + hh * 16 + q * 4 + r;
                if (row < M) {
                    float val = acc2[c][hh][r] + bv;
                    if (OMODE2 == 1) ((unsigned short*)out2)[(size_t)row * 256 + pj] = f2bf(val);
                    else             ((unsigned char*)out2)[(size_t)row * 256 + pj] = f2fp8(val);
                }
            }
        }
    }
}

// ---------------- single-block scan ----------------
__global__ __launch_bounds__(1024) void k_scanall(const int* __restrict__ hist, int* __restrict__ rowptr,
                                                  const int* __restrict__ gcount, int* __restrict__ gptr, int N) {
    __shared__ int s[1024];
    const int t = threadIdx.x;
    const int PER = (N + 1023) >> 10;
    const int b0 = t * PER;
    const int b1 = min(b0 + PER, N);
    int sum = 0;
    for (int i = b0; i < b1; i++) sum += hist[i];
    s[t] = sum;
    __syncthreads();
    for (int ofs = 1; ofs < 1024; ofs <<= 1) {
        int v = (t >= ofs) ? s[t - ofs] : 0;
        __syncthreads();
        s[t] += v;
        __syncthreads();
    }
    int run = s[t] - sum;
    for (int i = b0; i < b1; i++) {
        run += hist[i];
        rowptr[i + 1] = run;
    }
    if (t == 0) rowptr[0] = 0;
    __syncthreads();
    int gv = (t < 128) ? gcount[t] : 0;
    s[t] = gv;
    __syncthreads();
    for (int ofs = 1; ofs < 128; ofs <<= 1) {
        int v = (t >= ofs && t < 128) ? s[t - ofs] : 0;
        __syncthreads();
        if (t < 128) s[t] += v;
        __syncthreads();
    }
    if (t < 128) gptr[t + 1] = s[t];
    if (t == 0) gptr[0] = 0;
}

// ---------------- merged build: scatter + slot table + deg0-weighted A moments ----------------
// Block ranges: [0,SC) scatter; [SC,SC+SL) slots; [SC+SL, end) rowstats.
// All depend only on {rowptr, gptr, GEMM outputs}; co-scheduling hides the
// scatter's atomic/scatter-write latency under rowstats' streaming reads.
__global__ __launch_bounds__(256) void k_build(
    const int* __restrict__ idx0, const int* __restrict__ idx1, const int* __restrict__ batch,
    const int* __restrict__ rowptr, const int* __restrict__ gptr,
    int* __restrict__ fill, int* __restrict__ gfill,
    int* __restrict__ sidx1, int* __restrict__ gnodes,
    int2* __restrict__ slots,
    const uint2* __restrict__ A16, const int* __restrict__ hist0,
    float* __restrict__ gsum, float* __restrict__ gsq,
    int E, int N, int per_slot, int nslots, int SC_BLOCKS, int SL_BLOCKS)
{
    __shared__ float4 lsm4[256], lsq4[256];
    const int t = threadIdx.x;
    const int bid = blockIdx.x;

    if (bid < SC_BLOCKS) {                           // ---- scatter ----
        int i = bid * 256 + t;
        if (i < E) {
            int n = idx0[i];
            int pos = rowptr[n] + atomicAdd(&fill[n], 1);
            sidx1[pos] = idx1[i] << 8;               // byte offset of the 256B fp8 row
        }
        if (i < N) {
            int g = batch[i];
            int pos = gptr[g] + atomicAdd(&gfill[g], 1);
            gnodes[pos] = i;
        }
        return;
    }
    if (bid < SC_BLOCKS + SL_BLOCKS) {               // ---- slot->node bounds ----
        int s = (bid - SC_BLOCKS) * 256 + t;
        if (s > nslots) return;
        long base = (long)s * per_slot;
        if (base >= E) { slots[s] = (int2){N, N - 1}; return; }
        int e0 = (int)base;
        int lo = 0, hi = N;
        while (lo + 1 < hi) { int mid = (lo + hi) >> 1; if (rowptr[mid] <= e0) lo = mid; else hi = mid; }
        int nS = lo;
        int nA = 0;
        if (e0 > 0) {
            lo = 0; hi = N;
            while (lo + 1 < hi) { int mid = (lo + hi) >> 1; if (rowptr[mid] < e0) lo = mid; else hi = mid; }
            nA = hi;
        }
        slots[s] = (int2){nA, nS};
        return;
    }
    // ---- rowstats: sum(deg0*a), sum(deg0*a^2) ----
    const int s = t >> 6, l = t & 63;
    const int rb = bid - SC_BLOCKS - SL_BLOCKS;
    const int w0 = rb * 4 + s;
    const int nw = (gridDim.x - SC_BLOCKS - SL_BLOCKS) * 4;
    f32x2 smF = {0.f,0.f}, smC = {0.f,0.f}, sqF = {0.f,0.f}, sqC = {0.f,0.f};
    for (int n = w0; n < N; n += nw) {
        float dg = (float)hist0[n];
        uint2 a8 = A16[(size_t)n * 64 + l];
        f32x2 aF = {bflo(a8.x), bfhi(a8.x)};
        f32x2 aC = {bflo(a8.y), bfhi(a8.y)};
        f32x2 dF = aF * dg;
        f32x2 dC = aC * dg;
        smF += dF; smC += dC;
        sqF = pk_fma2(dF, aF, sqF);
        sqC = pk_fma2(dC, aC, sqC);
    }
    lsm4[t] = (float4){smF.x, smF.y, smC.x, smC.y};
    lsq4[t] = (float4){sqF.x, sqF.y, sqC.x, sqC.y};
    __syncthreads();
    const float* fm = (const float*)lsm4;
    const float* fq = (const float*)lsq4;
    float vs = fm[t] + fm[256 + t] + fm[512 + t] + fm[768 + t];
    float vq = fq[t] + fq[256 + t] + fq[512 + t] + fq[768 + t];
    atomicAdd(&gsum[t], vs);
    atomicAdd(&gsq[t], vq);
}

// ---------------- BN1 edge stats: sum(c), sum(c^2), cross 2*sum(a*csr) ----------------
// Gather-bound (91MB stream); per-edge VALU rides along. Slot-start (no
// per-wave binary search), 8-wide aligned gather prefetch.
__global__ __launch_bounds__(256) void k_stats(const uint2* __restrict__ A16, const unsigned char* __restrict__ Cp8b,
                                               const int* __restrict__ rowptr, const int* __restrict__ sidx1,
                                               const int2* __restrict__ slots,
                                               float* __restrict__ gsum, float* __restrict__ gsq,
                                               int E, int N, int per_slot) {
    __shared__ float4 lsm4[256], lsq4[256];
    const int t = threadIdx.x;
    const int s = t >> 6, l = t & 63;
    const int slot = blockIdx.x * 4 + s;
    const unsigned lo4 = (unsigned)(l << 2);
    const long base = (long)slot * per_slot;
    const int e0 = (int)min((long)E, base);
    const int e1 = (int)min((long)E, base + per_slot);
    f32x2 smF = {0.f,0.f}, smC = {0.f,0.f};
    f32x2 sqF = {0.f,0.f}, sqC = {0.f,0.f};        // accumulates c^2 AND 2*a*csr
    f32x2 csrF = {0.f,0.f}, csrC = {0.f,0.f};
    f32x2 aF2 = {0.f,0.f}, aC2 = {0.f,0.f};        // 2*a of current node
    int cur_n = 0, bound = 0;

    auto flush = [&]() {
        smF += csrF; smC += csrC;
        sqF = pk_fma2(aF2, csrF, sqF);
        sqC = pk_fma2(aC2, csrC, sqC);
        csrF = (f32x2){0.f,0.f}; csrC = (f32x2){0.f,0.f};
    };
    auto loadA = [&](int n) {
        uint2 a8 = A16[(size_t)n * 64 + l];
        aF2 = (f32x2){bflo(a8.x) * 2.f, bfhi(a8.x) * 2.f};
        aC2 = (f32x2){bflo(a8.y) * 2.f, bfhi(a8.y) * 2.f};
    };

    if (e0 < e1) {
        cur_n = slots[slot].y;
        bound = rowptr[cur_n + 1];
        loadA(cur_n);
    }

    auto proc = [&](int e, unsigned p) {
        if (e >= bound) {                            // wave-uniform
            flush();
            do { cur_n++; bound = rowptr[cur_n + 1]; } while (bound <= e);
            loadA(cur_n);
        }
        f32x2 vf, vc;
        fp8pair(p, vf, vc);
        csrF += vf; csrC += vc;
        sqF = pk_fma2(vf, vf, sqF);
        sqC = pk_fma2(vc, vc, sqC);
    };

    int e = e0;
    for (; e + 8 <= e1; e += 8) {
        int4 mm0 = *(const int4*)(sidx1 + e);
        int4 mm1 = *(const int4*)(sidx1 + e + 4);
        unsigned p0 = *(const unsigned*)(Cp8b + ((unsigned)mm0.x + lo4));
        unsigned p1 = *(const unsigned*)(Cp8b + ((unsigned)mm0.y + lo4));
        unsigned p2 = *(const unsigned*)(Cp8b + ((unsigned)mm0.z + lo4));
        unsigned p3 = *(const unsigned*)(Cp8b + ((unsigned)mm0.w + lo4));
        unsigned p4 = *(const unsigned*)(Cp8b + ((unsigned)mm1.x + lo4));
        unsigned p5 = *(const unsigned*)(Cp8b + ((unsigned)mm1.y + lo4));
        unsigned p6 = *(const unsigned*)(Cp8b + ((unsigned)mm1.z + lo4));
        unsigned p7 = *(const unsigned*)(Cp8b + ((unsigned)mm1.w + lo4));
        proc(e, p0); proc(e + 1, p1); proc(e + 2, p2); proc(e + 3, p3);
        proc(e + 4, p4); proc(e + 5, p5); proc(e + 6, p6); proc(e + 7, p7);
    }
    for (; e < e1; e++) proc(e, *(const unsigned*)(Cp8b + ((unsigned)sidx1[e] + lo4)));
    flush();

    lsm4[t] = (float4){smF.x, smF.y, smC.x, smC.y};
    lsq4[t] = (float4){sqF.x, sqF.y, sqC.x, sqC.y};
    __syncthreads();
    const float* fm = (const float*)lsm4;
    const float* fq = (const float*)lsq4;
    float vs = fm[t] + fm[256 + t] + fm[512 + t] + fm[768 + t];
    float vq = fq[t] + fq[256 + t] + fq[512 + t] + fq[768 + t];
    atomicAdd(&gsum[t], vs);
    atomicAdd(&gsq[t], vq);
}

// ---------------- fused BN1-finalize + msg + segment softmax ----------------
// Run-based: each wave-slot owns nodes n with rowptr[n] in [e0, e0+per_slot)
// (last real slot also owns trailing empty nodes). Contiguous edge stream
// with 8-wide aligned gather prefetch; A-row prefetched one node ahead.
__global__ __launch_bounds__(256) void k_aggr(const uint2* __restrict__ A16, const unsigned char* __restrict__ Cp8b,
                                              const int* __restrict__ rowptr, const int* __restrict__ sidx1,
                                              const int2* __restrict__ slots,
                                              const float* __restrict__ bn1_sum, const float* __restrict__ bn1_sq,
                                              const float* __restrict__ g1, const float* __restrict__ b1,
                                              const float* __restrict__ tptr, unsigned* __restrict__ out,
                                              float invE, int E, int N, int per_slot) {
    const int t = threadIdx.x;
    const int slot = blockIdx.x * 4 + (t >> 6);
    const int l = t & 63;
    const long base = (long)slot * per_slot;
    if (base >= E) return;
    const int n_first = slots[slot].x;
    const int n_last  = slots[slot + 1].x - 1;       // includes trailing empties for last real slot
    if (n_first > n_last) return;                    // spanning node covers whole slot

    const float tt = tptr[0];
    const float4 sum4 = ((const float4*)bn1_sum)[l];
    const float4 sq4  = ((const float4*)bn1_sq)[l];
    const float2 gf = ((const float2*)g1)[l];
    const float2 gc = ((const float2*)(g1 + 128))[l];
    const float2 bf2 = ((const float2*)b1)[l];
    const float2 bc2 = ((const float2*)(b1 + 128))[l];
    auto mkss = [&](float sum, float sq, float gg, float bb, float& sc, float& sh) {
        float mu = sum * invE;
        float var = sq * invE - mu * mu;
        sc = gg * rsqrtf(var + EPS_BN);
        sh = fmaf(-mu, sc, bb);
    };
    float scx, shx, scy, shy, scz, shz, scw, shw;
    mkss(sum4.x, sq4.x, gf.x, bf2.x, scx, shx);
    mkss(sum4.y, sq4.y, gf.y, bf2.y, scy, shy);
    mkss(sum4.z, sq4.z, gc.x, bc2.x, scz, shz);
    mkss(sum4.w, sq4.w, gc.y, bc2.y, scw, shw);
    const f32x2 sF  = {-scx * LOG2E, -scy * LOG2E};
    const f32x2 bsF = {-shx * LOG2E, -shy * LOG2E};
    const f32x2 sC  = { scz * LOG2E,  scw * LOG2E};
    const f32x2 bsC = { shz * LOG2E,  shw * LOG2E};
    const unsigned lo4 = (unsigned)(l << 2);

    int nc = n_first;
    uint2 aNx = A16[(size_t)nc * 64 + l];
    f32x2 bF, bC;
    auto consumeA = [&]() {
        f32x2 aF = {bflo(aNx.x), bfhi(aNx.x)};
        f32x2 aC = {bflo(aNx.y), bfhi(aNx.y)};
        bF = pk_fma2(aF, sF, bsF);
        bC = pk_fma2(aC, sC, bsC);
    };
    consumeA();
    if (nc < n_last) aNx = A16[(size_t)(nc + 1) * 64 + l];
    int bound = rowptr[nc + 1];
    f32x2 den = {0.f, 0.f}, num = {0.f, 0.f};

    auto finalize = [&]() {
        float ox = den.x != 0.f ? LN2 * num.x * __builtin_amdgcn_rcpf(den.x) : 0.f;
        float oy = den.y != 0.f ? LN2 * num.y * __builtin_amdgcn_rcpf(den.y) : 0.f;
        out[(size_t)nc * 64 + l] = pack2bf(ox, oy);
    };

    auto proc = [&](int e, unsigned p) {
        if (e >= bound) {                            // wave-uniform node switch
            finalize();
            den = (f32x2){0.f, 0.f}; num = (f32x2){0.f, 0.f};
            for (;;) {
                nc++;
                consumeA();
                if (nc < n_last) aNx = A16[(size_t)(nc + 1) * 64 + l];
                bound = rowptr[nc + 1];
                if (bound > e) break;
                out[(size_t)nc * 64 + l] = 0u;       // empty node
            }
        }
        f32x2 vf, vc;
        fp8pair(p, vf, vc);
        f32x2 argf = pk_fma2(vf, sF, bF);            // -zf_hat * log2e
        f32x2 argc = pk_fma2(vc, sC, bC);            //  zc_hat * log2e
        f32x2 ef = {fexp2(argf.x), fexp2(argf.y)};
        f32x2 uu = {fexp2(argc.x), fexp2(argc.y)};
        f32x2 d1 = ef + 1.f;
        f32x2 u1 = uu + 1.f;
        f32x2 sig = {__builtin_amdgcn_rcpf(d1.x), __builtin_amdgcn_rcpf(d1.y)};
        f32x2 lg = {flog2(u1.x), flog2(u1.y)};
        f32x2 M = sig * lg;
        f32x2 tM = M * tt;
        f32x2 w = {fexp2(tM.x), fexp2(tM.y)};
        den += w;
        num = pk_fma2(M, w, num);
    };

    const int eb0 = rowptr[n_first];
    const int eb1 = rowptr[n_last + 1];
    if (eb0 < eb1) {
        int eb = eb0 & ~7;
        int lo = eb0 - eb;
        int hi = min(eb1 - eb, 8);
        int4 m0 = *(const int4*)(sidx1 + eb);
        int4 m1 = *(const int4*)(sidx1 + eb + 4);
        unsigned g[8];
        {
            int mi[8] = {m0.x, m0.y, m0.z, m0.w, m1.x, m1.y, m1.z, m1.w};
#pragma unroll
            for (int i = 0; i < 8; i++)
                if (i >= lo && i < hi) g[i] = *(const unsigned*)(Cp8b + ((unsigned)mi[i] + lo4));
        }
        for (;;) {
            int ebn = eb + 8;
            bool more = ebn < eb1;
            unsigned gn[8];
            int nhi = 0;
            if (more) {
                int4 t0 = *(const int4*)(sidx1 + ebn);
                int4 t1 = *(const int4*)(sidx1 + ebn + 4);
                int mn[8] = {t0.x, t0.y, t0.z, t0.w, t1.x, t1.y, t1.z, t1.w};
                nhi = min(eb1 - ebn, 8);
#pragma unroll
                for (int i = 0; i < 8; i++)
                    if (i < nhi) gn[i] = *(const unsigned*)(Cp8b + ((unsigned)mn[i] + lo4));
            }
#pragma unroll
            for (int i = 0; i < 8; i++)
                if (i >= lo && i < hi) proc(eb + i, g[i]);
            if (!more) break;
#pragma unroll
            for (int i = 0; i < 8; i++) g[i] = gn[i];
            eb = ebn; lo = 0; hi = nhi;
        }
    }
    finalize();                                      // last non-empty (or lone empty) node
    while (nc < n_last) { nc++; out[(size_t)nc * 64 + l] = 0u; }   // trailing empties
}

// ---------------- BN2 stats (bf16 outbuf) ----------------
__global__ __launch_bounds__(128) void k_bn2stats(const unsigned short* __restrict__ out, float* __restrict__ sum,
                                                  float* __restrict__ sq, int N) {
    const int c = threadIdx.x;
    const int n0 = blockIdx.x * 64;
    const int nend = min(n0 + 64, N);
    float sm = 0.f, s2 = 0.f;
    for (int n = n0; n < nend; n++) {
        float v = bfu16(out[(size_t)n * 128 + c]);
        sm += v;
        s2 = fmaf(v, v, s2);
    }
    atomicAdd(&sum[c], sm);
    atomicAdd(&sq[c], s2);
}

// ---------------- fused BN2-finalize + residual+softplus + mean-pool (bf16 inputs) ----------------
template<int SPLIT>
__global__ __launch_bounds__(128) void k_h2pool(const unsigned short* __restrict__ out,
                                                const unsigned short* __restrict__ h,
                                                const int* __restrict__ gptr, const int* __restrict__ gnodes,
                                                const float* __restrict__ bn2_sum, const float* __restrict__ bn2_sq,
                                                const float* __restrict__ g2, const float* __restrict__ b2,
                                                float* __restrict__ pooled, float invN) {
    const int g = blockIdx.x & 127;
    const int sp = blockIdx.x >> 7;
    const int c = threadIdx.x;
    float mu = bn2_sum[c] * invN;
    float var = bn2_sq[c] * invN - mu * mu;
    float sc = g2[c] * rsqrtf(var + EPS_BN);
    float sh = fmaf(-mu, sc, b2[c]);
    const int i0 = gptr[g], i1 = gptr[g + 1];
    float acc = 0.f;
    for (int i = i0 + sp; i < i1; i += SPLIT) {
        int n = gnodes[i];
        float v = fmaf(bfu16(out[(size_t)n * 128 + c]), sc, sh) + bfu16(h[(size_t)n * 128 + c]);
        acc += softplus_fast(v);
    }
    if (acc != 0.f) atomicAdd(&pooled[g * 128 + c], acc);
}

// ---------------- head ----------------
__global__ __launch_bounds__(256) void k_head(const float* __restrict__ pooled, const int* __restrict__ gcount,
                                              const float* __restrict__ l1w, const float* __restrict__ l1b,
                                              const float* __restrict__ outw, const float* __restrict__ outb,
                                              float* __restrict__ dout) {
    __shared__ float p[128];
    __shared__ float red[256];
    const int g = blockIdx.x;
    const int j = threadIdx.x;
    if (j < 128) {
        float cnt = (float)max(gcount[g], 1);
        p[j] = pooled[g * 128 + j] / cnt;
    }
    __syncthreads();
    float acc = l1b[j];
    for (int k = 0; k < 128; k++) acc = fmaf(p[k], l1w[k * 256 + j], acc);
    red[j] = softplus_fast(acc) * outw[j];
    __syncthreads();
    for (int s = 128; s > 0; s >>= 1) {
        if (j < s) red[j] += red[j + s];
        __syncthreads();
    }
    if (j == 0) dout[g] = red[0] + outb[0];
}

// ---------------- launch ----------------
extern "C" void kernel_launch(void* const* d_in, const int* in_sizes, int n_in,
                              void* d_out, int out_size, void* d_ws, size_t ws_size,
                              hipStream_t stream) {
    const float* x        = (const float*)d_in[0];
    const float* hedge    = (const float*)d_in[1];
    const int*   iri      = (const int*)d_in[2];
    const int*   batch    = (const int*)d_in[3];
    const float* embed_w  = (const float*)d_in[5];
    const float* embed_b  = (const float*)d_in[6];
    const float* bembed_w = (const float*)d_in[7];
    const float* bembed_b = (const float*)d_in[8];
    const float* lin_w    = (const float*)d_in[9];
    const float* lin_b    = (const float*)d_in[10];
    const float* bn1_g    = (const float*)d_in[11];
    const float* bn1_b    = (const float*)d_in[12];
    const float* bn2_g    = (const float*)d_in[13];
    const float* bn2_b    = (const float*)d_in[14];
    const float* aggr_t   = (const float*)d_in[15];
    const float* l1_w     = (const float*)d_in[16];
    const float* l1_b     = (const float*)d_in[17];
    const float* out_w    = (const float*)d_in[18];
    const float* out_b    = (const float*)d_in[19];

    const int N   = in_sizes[0] / 92;
    const int NHE = in_sizes[1] / 40;
    const int E   = in_sizes[2] / 3;
    const int* idx0 = iri;
    const int* idx1 = iri + E;

    float* ws = (float*)d_ws;
    size_t off = 0;
    auto alloc = [&](size_t elems) -> float* {
        float* p = ws + off;
        off += (elems + 63) & ~(size_t)63;
        return p;
    };
    unsigned short* h16 = (unsigned short*)alloc((size_t)N * 64);   // N*128 bf16
    uint2* A16    = (uint2*)alloc((size_t)N * 128);                 // N*256 bf16 packed
    unsigned* Cp8 = (unsigned*)alloc((size_t)NHE * 64);             // NHE*256 fp8 packed
    unsigned short* embB  = (unsigned short*)alloc(6144);
    unsigned short* bembB = (unsigned short*)alloc(4096);
    unsigned short* waB   = (unsigned short*)alloc(16384);
    unsigned short* wcB   = (unsigned short*)alloc(16384);
    int*   rowptr = (int*)alloc((size_t)N + 1);
    int*   sidx1  = (int*)alloc((size_t)E + 8);
    int*   gptr   = (int*)alloc(129);
    int*   gnodes = (int*)alloc((size_t)N);
    unsigned* outbuf = (unsigned*)alloc((size_t)N * 64);            // N*128 bf16
    int2*  slots  = (int2*)alloc(2 * 8200);                         // slot->node bounds (+sentinel)
    // contiguous zero region
    float* zbase  = ws + off;
    int*   hist   = (int*)alloc((size_t)N);
    int*   fill   = (int*)alloc((size_t)N);
    int*   gfill  = (int*)alloc(128);
    float* bn1_sum = alloc(256);
    float* bn1_sq  = alloc(256);
    float* bn2_sum = alloc(128);
    float* bn2_sq  = alloc(128);
    float* pooled  = alloc(128 * 128);
    int*   gcount  = (int*)alloc(128);
    size_t zbytes = (size_t)((ws + off) - zbase) * sizeof(float);
    (void)ws_size;  // ~78MB; fit verified

    hipMemsetAsync(zbase, 0, zbytes, stream);

    // frag-major bf16 weight prep + fused MFMA GEMM chains.
    // GEMM1 also builds hist0 (idx0 degree); GEMM2 builds gcount. The
    // fire-and-forget atomics drain under the MFMA work.
    k_prepw<<<320, 256, 0, stream>>>(embed_w, bembed_w, lin_w, embB, bembB, waB, wcB);
    const int mtN   = (N + 31) / 32;
    const int mtNHE = (NHE + 31) / 32;
    mfma_fused<92, 3, 1><<<mtN, 256, 0, stream>>>(x, embB, embed_b, waB, lin_b, h16, A16, N,
                                                  idx0, hist, E);
    mfma_fused<40, 2, 2><<<mtNHE, 256, 0, stream>>>(hedge, bembB, bembed_b, wcB, nullptr, nullptr, Cp8, NHE,
                                                    batch, gcount, N);

    // prefix sums
    k_scanall<<<1, 1024, 0, stream>>>(hist, rowptr, gcount, gptr, N);

    // unified slot geometry for both edge kernels (8 | per_slot)
    const int EDGE_BLOCKS = 2048;
    const int NSLOTS = EDGE_BLOCKS * 4;
    int per_slot = ((E + NSLOTS - 1) / NSLOTS + 7) & ~7;
    int nslots_used = (E + per_slot - 1) / per_slot;

    // merged scatter + slot table + deg0-weighted A moments
    const int SC_BLOCKS = ((E > N ? E : N) + 255) / 256;
    const int SL_BLOCKS = (nslots_used + 1 + 255) / 256;
    const int RS_BLOCKS = 256;
    k_build<<<SC_BLOCKS + SL_BLOCKS + RS_BLOCKS, 256, 0, stream>>>(
        idx0, idx1, batch, rowptr, gptr, fill, gfill, sidx1, gnodes, slots,
        A16, hist, bn1_sum, bn1_sq, E, N, per_slot, nslots_used, SC_BLOCKS, SL_BLOCKS);

    // BN1 edge stats (C moments + cross term)
    k_stats<<<EDGE_BLOCKS, 256, 0, stream>>>(A16, (const unsigned char*)Cp8, rowptr, sidx1, slots,
                                             bn1_sum, bn1_sq, E, N, per_slot);

    // fused BN1-finalize + message + softmax aggregation (run-based)
    k_aggr<<<EDGE_BLOCKS, 256, 0, stream>>>(A16, (const unsigned char*)Cp8, rowptr, sidx1, slots,
                                            bn1_sum, bn1_sq, bn1_g, bn1_b, aggr_t, outbuf,
                                            1.0f / (float)E, E, N, per_slot);

    // BN2 stats + fused finalize/residual/softplus/pool
    k_bn2stats<<<(N + 63) / 64, 128, 0, stream>>>((const unsigned short*)outbuf, bn2_sum, bn2_sq, N);
    k_h2pool<16><<<128 * 16, 128, 0, stream>>>((const unsigned short*)outbuf, h16, gptr, gnodes,
                                               bn2_sum, bn2_sq, bn2_g, bn2_b, pooled, 1.0f / (float)N);

    // head
    k_head<<<128, 256, 0, stream>>>(pooled, gcount, l1_w, l1_b, out_w, out_b, (float*)d_out);
}

// Round 4
// 589.609 us; speedup vs baseline: 1.1168x; 1.0232x over previous
//
#include <hip/hip_runtime.h>
#include <hip/hip_bf16.h>

// CrystalHypergraphConv — MI355X implementation.
//
// z[e] = A[idx0[e]] + C[idx1[e]];  A [N,256] bf16-packed; C [NHE,256]
// fp8-e4m3-packed. Lane l owns channels {2l,2l+1,128+2l,129+2l}.
//
// R20 -> R21:
//  - k_aggr: revert run-based slots (95us, occupancy 53%) to node-per-wave,
//    upgraded to TWO adjacent nodes per wave with interleaved dual streams:
//    shared prologue (adjacent rowptr/A-rows), two independent accumulator
//    chains, 2x4-deep gather prefetch (8 loads in flight). Stream B's proc
//    hides stream A's node-switch latency. 25k waves restores
//    over-subscription (24/SIMD queued).
//  - k_bn2stats: scalar 2B loads -> packed-word loads (4B/lane coalesced)
//    + LDS cross-wave reduce; grid-stride 256 blocks.

#define EPS_BN 1e-5f
#define LOG2E 1.4426950408889634f
#define LN2   0.6931471805599453f

typedef __attribute__((ext_vector_type(8))) short bf16x8;
typedef __attribute__((ext_vector_type(4))) float f32x4;
typedef __attribute__((ext_vector_type(2))) float f32x2;

__device__ __forceinline__ float fexp2(float x) {
#if __has_builtin(__builtin_amdgcn_exp2f)
    return __builtin_amdgcn_exp2f(x);
#else
    return __expf(x * LN2);
#endif
}
__device__ __forceinline__ float flog2(float x) {
#if __has_builtin(__builtin_amdgcn_logf)
    return __builtin_amdgcn_logf(x);
#else
    return __logf(x) * LOG2E;
#endif
}
__device__ __forceinline__ float softplus_fast(float x) {
    return LN2 * flog2(1.f + fexp2(x * LOG2E));
}

__device__ __forceinline__ f32x2 pk_fma2(f32x2 a, f32x2 b, f32x2 c) {
#if __has_builtin(__builtin_elementwise_fma)
    return __builtin_elementwise_fma(a, b, c);
#else
    return (f32x2){fmaf(a.x, b.x, c.x), fmaf(a.y, b.y, c.y)};
#endif
}

__device__ __forceinline__ unsigned short f2bf(float f) {
    unsigned u = __float_as_uint(f);
    unsigned r = (u + 0x7fffu + ((u >> 16) & 1u)) >> 16;   // RNE
    return (unsigned short)r;
}
__device__ __forceinline__ float bflo(unsigned u) { return __uint_as_float(u << 16); }
__device__ __forceinline__ float bfhi(unsigned u) { return __uint_as_float(u & 0xffff0000u); }
__device__ __forceinline__ float bfu16(unsigned short v) { return __uint_as_float(((unsigned)v) << 16); }
__device__ __forceinline__ unsigned pack2bf(float x, float y) {
    return (unsigned)f2bf(x) | ((unsigned)f2bf(y) << 16);
}

// ---- fp8 e4m3 encode/decode (OCP; HW path on gfx950) ----
#if __has_builtin(__builtin_amdgcn_cvt_pk_f32_fp8) && __has_builtin(__builtin_amdgcn_cvt_pk_fp8_f32)
#define HW_FP8 1
#else
#define HW_FP8 0
#endif

__device__ __forceinline__ unsigned char f2fp8(float f) {
#if HW_FP8
    int r = __builtin_amdgcn_cvt_pk_fp8_f32(f, f, 0, false);
    return (unsigned char)(r & 0xff);
#else
    unsigned u = __float_as_uint(f);
    unsigned s = (u >> 24) & 0x80u;
    float af = fabsf(f);
    if (!(af >= 0.015625f)) {
        int m = (int)rintf(af * 512.f);
        if (m > 7) m = 7;
        return (unsigned char)(s | (unsigned)m);
    }
    if (af > 448.f) return (unsigned char)(s | 0x7e);
    unsigned au = __float_as_uint(af);
    unsigned r = au + 0x7ffffu + ((au >> 20) & 1u);
    int e8 = (int)(r >> 23) - 120;
    unsigned m = (r >> 20) & 7u;
    if (e8 > 15 || (e8 == 15 && m == 7)) return (unsigned char)(s | 0x7e);
    return (unsigned char)(s | ((unsigned)e8 << 3) | m);
#endif
}

// decode packed word -> lo pair (bytes 0,1 = f channels), hi pair (bytes 2,3 = c channels)
__device__ __forceinline__ void fp8pair(unsigned p, f32x2& lo, f32x2& hi) {
#if HW_FP8
    lo = __builtin_amdgcn_cvt_pk_f32_fp8((int)p, false);
    hi = __builtin_amdgcn_cvt_pk_f32_fp8((int)p, true);
#else
    auto dec = [](unsigned byte) -> float {
        unsigned s = (byte & 0x80u) << 24;
        unsigned em = byte & 0x7fu;
        float nrm = __uint_as_float(s | ((em << 20) + 0x3C000000u));
        float sub = __uint_as_float(s | 0x3F800000u) * (float)em * 0.001953125f;
        return (em >= 8) ? nrm : sub;
    };
    lo = (f32x2){dec(p & 0xff), dec((p >> 8) & 0xff)};
    hi = (f32x2){dec((p >> 16) & 0xff), dec(p >> 24)};
#endif
}

__device__ __forceinline__ int perm256(int j) {
    return (j < 128) ? ((j >> 1) * 4 + (j & 1)) : (((j - 128) >> 1) * 4 + 2 + (j & 1));
}

// ---------------- weight prep: frag-major bf16 B tables ----------------
__global__ __launch_bounds__(256) void k_prepw(const float* __restrict__ ew, const float* __restrict__ bw,
                                               const float* __restrict__ lw,
                                               unsigned short* __restrict__ embB, unsigned short* __restrict__ bembB,
                                               unsigned short* __restrict__ waB, unsigned short* __restrict__ wcB) {
    int i = blockIdx.x * 256 + threadIdx.x;          // 0..81919
    if (i >= 81920) return;
    unsigned short* dst;
    int f, NKC, CT, mode;
    if (i < 12288)      { dst = embB;  f = i;         NKC = 3; CT = 2; mode = 0; }
    else if (i < 20480) { dst = bembB; f = i - 12288; NKC = 2; CT = 2; mode = 1; }
    else if (i < 53248) { dst = waB;   f = i - 20480; NKC = 4; CT = 4; mode = 2; }
    else                { dst = wcB;   f = i - 53248; NKC = 4; CT = 4; mode = 3; }
    int j = f & 7, l = (f >> 3) & 63;
    int r2 = f >> 9;
    int c = r2 % CT;
    int r3 = r2 / CT;
    int kc = r3 % NKC, w = r3 / NKC;
    int k = kc * 32 + ((l >> 4) & 3) * 8 + j;
    int n = (w * CT + c) * 16 + (l & 15);
    float v;
    if (mode == 0)      v = (k < 92) ? ew[k * 128 + n] : 0.f;
    else if (mode == 1) v = (k < 40) ? bw[k * 128 + n] : 0.f;
    else if (mode == 2) v = lw[k * 256 + n] + lw[(k + 256) * 256 + n];
    else                v = lw[(k + 128) * 256 + n];
    dst[f] = f2bf(v);
}

// ---------------- fused 2-stage MFMA GEMM (+ histogram atomic prologue) ----------------
// OMODE2: 1 = bf16-packed A + bf16 h out; 2 = fp8-packed C out
template<int KIN, int NKC1, int OMODE2>
__global__ __launch_bounds__(256) void mfma_fused(
    const float* __restrict__ in, const unsigned short* __restrict__ B1, const float* __restrict__ bias1,
    const unsigned short* __restrict__ B2, const float* __restrict__ bias2,
    unsigned short* __restrict__ hout, void* __restrict__ out2, int M,
    const int* __restrict__ aux_idx, int* __restrict__ aux_hist, int aux_cnt)
{
    const int r0 = blockIdx.x * 32;
    const int t = threadIdx.x;
    const int w = t >> 6;
    const int l = t & 63;
    const int m = l & 15, q = l >> 4;

    if (aux_idx) {
        const int T = gridDim.x * 256;
        for (int i = blockIdx.x * 256 + t; i < aux_cnt; i += T)
            atomicAdd(&aux_hist[aux_idx[i]], 1);
    }

    __shared__ __align__(16) unsigned short als[32 * NKC1 * 32];
    __shared__ __align__(16) unsigned short hls[32 * 136];

    const int KP = NKC1 * 32;
    for (int i = t; i < 32 * KP; i += 256) {
        int r = i / KP, k = i - r * KP;
        int gr = r0 + r;
        float v = (gr < M && k < KIN) ? in[(size_t)gr * KIN + k] : 0.f;
        int idx = (((r >> 4) * NKC1 + (k >> 5)) * 64 + ((k >> 3) & 3) * 16 + (r & 15)) * 8 + (k & 7);
        als[idx] = f2bf(v);
    }
    bf16x8 b1[NKC1][2];
    const bf16x8* B1f = (const bf16x8*)B1;
#pragma unroll
    for (int kc = 0; kc < NKC1; kc++)
#pragma unroll
        for (int c = 0; c < 2; c++)
            b1[kc][c] = B1f[((w * NKC1 + kc) * 2 + c) * 64 + l];
    __syncthreads();

    f32x4 acc1[2][2];
#pragma unroll
    for (int c = 0; c < 2; c++) { acc1[c][0] = (f32x4){0.f,0.f,0.f,0.f}; acc1[c][1] = (f32x4){0.f,0.f,0.f,0.f}; }
    const bf16x8* af = (const bf16x8*)als;
#pragma unroll
    for (int kc = 0; kc < NKC1; kc++) {
        bf16x8 a0 = af[kc * 64 + l];
        bf16x8 a1 = af[(NKC1 + kc) * 64 + l];
#pragma unroll
        for (int c = 0; c < 2; c++) {
            acc1[c][0] = __builtin_amdgcn_mfma_f32_16x16x32_bf16(a0, b1[kc][c], acc1[c][0], 0, 0, 0);
            acc1[c][1] = __builtin_amdgcn_mfma_f32_16x16x32_bf16(a1, b1[kc][c], acc1[c][1], 0, 0, 0);
        }
    }
#pragma unroll
    for (int c = 0; c < 2; c++) {
        int n1 = (w * 2 + c) * 16 + m;
        float bv = bias1[n1];
#pragma unroll
        for (int hh = 0; hh < 2; hh++) {
#pragma unroll
            for (int r = 0; r < 4; r++) {
                int row = hh * 16 + q * 4 + r;
                float val = acc1[c][hh][r] + bv;
                unsigned short bf = f2bf(val);
                hls[row * 136 + n1] = bf;
                if (OMODE2 == 1 && r0 + row < M) hout[(size_t)(r0 + row) * 128 + n1] = bf;
            }
        }
    }
    __syncthreads();

    bf16x8 b2[4][4];
    const bf16x8* B2f = (const bf16x8*)B2;
#pragma unroll
    for (int kc = 0; kc < 4; kc++)
#pragma unroll
        for (int c = 0; c < 4; c++)
            b2[kc][c] = B2f[((w * 4 + kc) * 4 + c) * 64 + l];

    f32x4 acc2[4][2];
#pragma unroll
    for (int c = 0; c < 4; c++) { acc2[c][0] = (f32x4){0.f,0.f,0.f,0.f}; acc2[c][1] = (f32x4){0.f,0.f,0.f,0.f}; }
#pragma unroll
    for (int kc = 0; kc < 4; kc++) {
        bf16x8 a0 = *(const bf16x8*)(hls + m * 136 + kc * 32 + q * 8);
        bf16x8 a1 = *(const bf16x8*)(hls + (m + 16) * 136 + kc * 32 + q * 8);
#pragma unroll
        for (int c = 0; c < 4; c++) {
            acc2[c][0] = __builtin_amdgcn_mfma_f32_16x16x32_bf16(a0, b2[kc][c], acc2[c][0], 0, 0, 0);
            acc2[c][1] = __builtin_amdgcn_mfma_f32_16x16x32_bf16(a1, b2[kc][c], acc2[c][1], 0, 0, 0);
        }
    }
#pragma unroll
    for (int c = 0; c < 4; c++) {
        int n = (w * 4 + c) * 16 + m;
        float bv = bias2 ? bias2[n] : 0.f;
        int pj = perm256(n);
#pragma unroll
        for (int hh = 0; hh < 2; hh++) {
#pragma unroll
            for (int r = 0; r < 4; r++) {
                int row = r0 + hh * 16 + q * 4 + r;
                if (row < M) {
                    float val = acc2[c][hh][r] + bv;
                    if (OMODE2 == 1) ((unsigned short*)out2)[(size_t)row * 256 + pj] = f2bf(val);
                    else             ((unsigned char*)out2)[(size_t)row * 256 + pj] = f2fp8(val);
                }
            }
        }
    }
}

// ---------------- single-block scan ----------------
__global__ __launch_bounds__(1024) void k_scanall(const int* __restrict__ hist, int* __restrict__ rowptr,
                                                  const int* __restrict__ gcount, int* __restrict__ gptr, int N) {
    __shared__ int s[1024];
    const int t = threadIdx.x;
    const int PER = (N + 1023) >> 10;
    const int b0 = t * PER;
    const int b1 = min(b0 + PER, N);
    int sum = 0;
    for (int i = b0; i < b1; i++) sum += hist[i];
    s[t] = sum;
    __syncthreads();
    for (int ofs = 1; ofs < 1024; ofs <<= 1) {
        int v = (t >= ofs) ? s[t - ofs] : 0;
        __syncthreads();
        s[t] += v;
        __syncthreads();
    }
    int run = s[t] - sum;
    for (int i = b0; i < b1; i++) {
        run += hist[i];
        rowptr[i + 1] = run;
    }
    if (t == 0) rowptr[0] = 0;
    __syncthreads();
    int gv = (t < 128) ? gcount[t] : 0;
    s[t] = gv;
    __syncthreads();
    for (int ofs = 1; ofs < 128; ofs <<= 1) {
        int v = (t >= ofs && t < 128) ? s[t - ofs] : 0;
        __syncthreads();
        if (t < 128) s[t] += v;
        __syncthreads();
    }
    if (t < 128) gptr[t + 1] = s[t];
    if (t == 0) gptr[0] = 0;
}

// ---------------- merged build: scatter + slot table + deg0-weighted A moments ----------------
__global__ __launch_bounds__(256) void k_build(
    const int* __restrict__ idx0, const int* __restrict__ idx1, const int* __restrict__ batch,
    const int* __restrict__ rowptr, const int* __restrict__ gptr,
    int* __restrict__ fill, int* __restrict__ gfill,
    int* __restrict__ sidx1, int* __restrict__ gnodes,
    int2* __restrict__ slots,
    const uint2* __restrict__ A16, const int* __restrict__ hist0,
    float* __restrict__ gsum, float* __restrict__ gsq,
    int E, int N, int per_slot, int nslots, int SC_BLOCKS, int SL_BLOCKS)
{
    __shared__ float4 lsm4[256], lsq4[256];
    const int t = threadIdx.x;
    const int bid = blockIdx.x;

    if (bid < SC_BLOCKS) {                           // ---- scatter ----
        int i = bid * 256 + t;
        if (i < E) {
            int n = idx0[i];
            int pos = rowptr[n] + atomicAdd(&fill[n], 1);
            sidx1[pos] = idx1[i] << 8;               // byte offset of the 256B fp8 row
        }
        if (i < N) {
            int g = batch[i];
            int pos = gptr[g] + atomicAdd(&gfill[g], 1);
            gnodes[pos] = i;
        }
        return;
    }
    if (bid < SC_BLOCKS + SL_BLOCKS) {               // ---- slot->node bounds ----
        int s = (bid - SC_BLOCKS) * 256 + t;
        if (s > nslots) return;
        long base = (long)s * per_slot;
        if (base >= E) { slots[s] = (int2){N, N - 1}; return; }
        int e0 = (int)base;
        int lo = 0, hi = N;
        while (lo + 1 < hi) { int mid = (lo + hi) >> 1; if (rowptr[mid] <= e0) lo = mid; else hi = mid; }
        int nS = lo;
        int nA = 0;
        if (e0 > 0) {
            lo = 0; hi = N;
            while (lo + 1 < hi) { int mid = (lo + hi) >> 1; if (rowptr[mid] < e0) lo = mid; else hi = mid; }
            nA = hi;
        }
        slots[s] = (int2){nA, nS};
        return;
    }
    // ---- rowstats: sum(deg0*a), sum(deg0*a^2) ----
    const int s = t >> 6, l = t & 63;
    const int rb = bid - SC_BLOCKS - SL_BLOCKS;
    const int w0 = rb * 4 + s;
    const int nw = (gridDim.x - SC_BLOCKS - SL_BLOCKS) * 4;
    f32x2 smF = {0.f,0.f}, smC = {0.f,0.f}, sqF = {0.f,0.f}, sqC = {0.f,0.f};
    for (int n = w0; n < N; n += nw) {
        float dg = (float)hist0[n];
        uint2 a8 = A16[(size_t)n * 64 + l];
        f32x2 aF = {bflo(a8.x), bfhi(a8.x)};
        f32x2 aC = {bflo(a8.y), bfhi(a8.y)};
        f32x2 dF = aF * dg;
        f32x2 dC = aC * dg;
        smF += dF; smC += dC;
        sqF = pk_fma2(dF, aF, sqF);
        sqC = pk_fma2(dC, aC, sqC);
    }
    lsm4[t] = (float4){smF.x, smF.y, smC.x, smC.y};
    lsq4[t] = (float4){sqF.x, sqF.y, sqC.x, sqC.y};
    __syncthreads();
    const float* fm = (const float*)lsm4;
    const float* fq = (const float*)lsq4;
    float vs = fm[t] + fm[256 + t] + fm[512 + t] + fm[768 + t];
    float vq = fq[t] + fq[256 + t] + fq[512 + t] + fq[768 + t];
    atomicAdd(&gsum[t], vs);
    atomicAdd(&gsq[t], vq);
}

// ---------------- BN1 edge stats: sum(c), sum(c^2), cross 2*sum(a*csr) ----------------
__global__ __launch_bounds__(256) void k_stats(const uint2* __restrict__ A16, const unsigned char* __restrict__ Cp8b,
                                               const int* __restrict__ rowptr, const int* __restrict__ sidx1,
                                               const int2* __restrict__ slots,
                                               float* __restrict__ gsum, float* __restrict__ gsq,
                                               int E, int N, int per_slot) {
    __shared__ float4 lsm4[256], lsq4[256];
    const int t = threadIdx.x;
    const int s = t >> 6, l = t & 63;
    const int slot = blockIdx.x * 4 + s;
    const unsigned lo4 = (unsigned)(l << 2);
    const long base = (long)slot * per_slot;
    const int e0 = (int)min((long)E, base);
    const int e1 = (int)min((long)E, base + per_slot);
    f32x2 smF = {0.f,0.f}, smC = {0.f,0.f};
    f32x2 sqF = {0.f,0.f}, sqC = {0.f,0.f};        // accumulates c^2 AND 2*a*csr
    f32x2 csrF = {0.f,0.f}, csrC = {0.f,0.f};
    f32x2 aF2 = {0.f,0.f}, aC2 = {0.f,0.f};        // 2*a of current node
    int cur_n = 0, bound = 0;

    auto flush = [&]() {
        smF += csrF; smC += csrC;
        sqF = pk_fma2(aF2, csrF, sqF);
        sqC = pk_fma2(aC2, csrC, sqC);
        csrF = (f32x2){0.f,0.f}; csrC = (f32x2){0.f,0.f};
    };
    auto loadA = [&](int n) {
        uint2 a8 = A16[(size_t)n * 64 + l];
        aF2 = (f32x2){bflo(a8.x) * 2.f, bfhi(a8.x) * 2.f};
        aC2 = (f32x2){bflo(a8.y) * 2.f, bfhi(a8.y) * 2.f};
    };

    if (e0 < e1) {
        cur_n = slots[slot].y;
        bound = rowptr[cur_n + 1];
        loadA(cur_n);
    }

    auto proc = [&](int e, unsigned p) {
        if (e >= bound) {                            // wave-uniform
            flush();
            do { cur_n++; bound = rowptr[cur_n + 1]; } while (bound <= e);
            loadA(cur_n);
        }
        f32x2 vf, vc;
        fp8pair(p, vf, vc);
        csrF += vf; csrC += vc;
        sqF = pk_fma2(vf, vf, sqF);
        sqC = pk_fma2(vc, vc, sqC);
    };

    int e = e0;
    for (; e + 8 <= e1; e += 8) {
        int4 mm0 = *(const int4*)(sidx1 + e);
        int4 mm1 = *(const int4*)(sidx1 + e + 4);
        unsigned p0 = *(const unsigned*)(Cp8b + ((unsigned)mm0.x + lo4));
        unsigned p1 = *(const unsigned*)(Cp8b + ((unsigned)mm0.y + lo4));
        unsigned p2 = *(const unsigned*)(Cp8b + ((unsigned)mm0.z + lo4));
        unsigned p3 = *(const unsigned*)(Cp8b + ((unsigned)mm0.w + lo4));
        unsigned p4 = *(const unsigned*)(Cp8b + ((unsigned)mm1.x + lo4));
        unsigned p5 = *(const unsigned*)(Cp8b + ((unsigned)mm1.y + lo4));
        unsigned p6 = *(const unsigned*)(Cp8b + ((unsigned)mm1.z + lo4));
        unsigned p7 = *(const unsigned*)(Cp8b + ((unsigned)mm1.w + lo4));
        proc(e, p0); proc(e + 1, p1); proc(e + 2, p2); proc(e + 3, p3);
        proc(e + 4, p4); proc(e + 5, p5); proc(e + 6, p6); proc(e + 7, p7);
    }
    for (; e < e1; e++) proc(e, *(const unsigned*)(Cp8b + ((unsigned)sidx1[e] + lo4)));
    flush();

    lsm4[t] = (float4){smF.x, smF.y, smC.x, smC.y};
    lsq4[t] = (float4){sqF.x, sqF.y, sqC.x, sqC.y};
    __syncthreads();
    const float* fm = (const float*)lsm4;
    const float* fq = (const float*)lsq4;
    float vs = fm[t] + fm[256 + t] + fm[512 + t] + fm[768 + t];
    float vq = fq[t] + fq[256 + t] + fq[512 + t] + fq[768 + t];
    atomicAdd(&gsum[t], vs);
    atomicAdd(&gsq[t], vq);
}

// ---------------- fused BN1-finalize + msg + segment softmax ----------------
// Two adjacent nodes per wave, interleaved dual streams: shared prologue,
// independent accumulators, 2x4-deep gather prefetch (8 loads in flight).
__global__ __launch_bounds__(256) void k_aggr(const uint2* __restrict__ A16, const unsigned char* __restrict__ Cp8b,
                                              const int* __restrict__ rowptr, const int* __restrict__ sidx1,
                                              const float* __restrict__ bn1_sum, const float* __restrict__ bn1_sq,
                                              const float* __restrict__ g1, const float* __restrict__ b1,
                                              const float* __restrict__ tptr, unsigned* __restrict__ out,
                                              float invE, int N) {
    const int t = threadIdx.x;
    const int l = t & 63;
    const int n1 = blockIdx.x * 8 + (t >> 6) * 2;
    if (n1 >= N) return;
    const int has2 = (n1 + 1) < N ? 1 : 0;

    const float tt = tptr[0];
    const float4 sum4 = ((const float4*)bn1_sum)[l];
    const float4 sq4  = ((const float4*)bn1_sq)[l];
    const float2 gf = ((const float2*)g1)[l];
    const float2 gc = ((const float2*)(g1 + 128))[l];
    const float2 bf2 = ((const float2*)b1)[l];
    const float2 bc2 = ((const float2*)(b1 + 128))[l];
    auto mkss = [&](float sum, float sq, float gg, float bb, float& sc, float& sh) {
        float mu = sum * invE;
        float var = sq * invE - mu * mu;
        sc = gg * rsqrtf(var + EPS_BN);
        sh = fmaf(-mu, sc, bb);
    };
    float scx, shx, scy, shy, scz, shz, scw, shw;
    mkss(sum4.x, sq4.x, gf.x, bf2.x, scx, shx);
    mkss(sum4.y, sq4.y, gf.y, bf2.y, scy, shy);
    mkss(sum4.z, sq4.z, gc.x, bc2.x, scz, shz);
    mkss(sum4.w, sq4.w, gc.y, bc2.y, scw, shw);
    const f32x2 sF  = {-scx * LOG2E, -scy * LOG2E};
    const f32x2 bsF = {-shx * LOG2E, -shy * LOG2E};
    const f32x2 sC  = { scz * LOG2E,  scw * LOG2E};
    const f32x2 bsC = { shz * LOG2E,  shw * LOG2E};
    const unsigned lo4 = (unsigned)(l << 2);

    uint2 a1 = A16[(size_t)n1 * 64 + l];
    uint2 a2 = A16[(size_t)(n1 + has2) * 64 + l];
    const int e0 = rowptr[n1];
    const int e1 = rowptr[n1 + 1];
    const int e2 = has2 ? rowptr[n1 + 2] : e1;

    f32x2 aF1 = {bflo(a1.x), bfhi(a1.x)}, aC1 = {bflo(a1.y), bfhi(a1.y)};
    f32x2 aF2 = {bflo(a2.x), bfhi(a2.x)}, aC2 = {bflo(a2.y), bfhi(a2.y)};
    const f32x2 bF1 = pk_fma2(aF1, sF, bsF), bC1 = pk_fma2(aC1, sC, bsC);
    const f32x2 bF2 = pk_fma2(aF2, sF, bsF), bC2 = pk_fma2(aC2, sC, bsC);

    f32x2 den1 = {0.f,0.f}, num1 = {0.f,0.f}, den2 = {0.f,0.f}, num2 = {0.f,0.f};

    auto G = [&](int e) -> unsigned {
        return *(const unsigned*)(Cp8b + ((unsigned)sidx1[e] + lo4));
    };
    auto procg = [&](unsigned p, const f32x2& bF, const f32x2& bC, f32x2& den, f32x2& num) {
        f32x2 vf, vc;
        fp8pair(p, vf, vc);
        f32x2 argf = pk_fma2(vf, sF, bF);            // -zf_hat * log2e
        f32x2 argc = pk_fma2(vc, sC, bC);            //  zc_hat * log2e
        f32x2 ef = {fexp2(argf.x), fexp2(argf.y)};
        f32x2 uu = {fexp2(argc.x), fexp2(argc.y)};
        f32x2 d1 = ef + 1.f;
        f32x2 u1 = uu + 1.f;
        f32x2 sig = {__builtin_amdgcn_rcpf(d1.x), __builtin_amdgcn_rcpf(d1.y)};
        f32x2 lg = {flog2(u1.x), flog2(u1.y)};
        f32x2 M = sig * lg;
        f32x2 tM = M * tt;
        f32x2 w = {fexp2(tM.x), fexp2(tM.y)};
        den += w;
        num = pk_fma2(M, w, num);
    };

    unsigned cur1[4], cur2[4];
    int cl1 = min(e1 - e0, 4);
    int cl2 = min(e2 - e1, 4);
#pragma unroll
    for (int i = 0; i < 4; i++) if (i < cl1) cur1[i] = G(e0 + i);
#pragma unroll
    for (int i = 0; i < 4; i++) if (i < cl2) cur2[i] = G(e1 + i);
    int pl1 = e0 + cl1;
    int pl2 = e1 + cl2;
    while ((cl1 | cl2) != 0) {
        unsigned nxt1[4], nxt2[4];
        int nl1 = min(max(e1 - pl1, 0), 4);
        int nl2 = min(max(e2 - pl2, 0), 4);
#pragma unroll
        for (int i = 0; i < 4; i++) if (i < nl1) nxt1[i] = G(pl1 + i);
#pragma unroll
        for (int i = 0; i < 4; i++) if (i < nl2) nxt2[i] = G(pl2 + i);
#pragma unroll
        for (int i = 0; i < 4; i++) if (i < cl1) procg(cur1[i], bF1, bC1, den1, num1);
#pragma unroll
        for (int i = 0; i < 4; i++) if (i < cl2) procg(cur2[i], bF2, bC2, den2, num2);
#pragma unroll
        for (int i = 0; i < 4; i++) { cur1[i] = nxt1[i]; cur2[i] = nxt2[i]; }
        pl1 += nl1; pl2 += nl2;
        cl1 = nl1; cl2 = nl2;
    }
    float ox1 = den1.x != 0.f ? LN2 * num1.x * __builtin_amdgcn_rcpf(den1.x) : 0.f;
    float oy1 = den1.y != 0.f ? LN2 * num1.y * __builtin_amdgcn_rcpf(den1.y) : 0.f;
    out[(size_t)n1 * 64 + l] = pack2bf(ox1, oy1);
    if (has2) {
        float ox2 = den2.x != 0.f ? LN2 * num2.x * __builtin_amdgcn_rcpf(den2.x) : 0.f;
        float oy2 = den2.y != 0.f ? LN2 * num2.y * __builtin_amdgcn_rcpf(den2.y) : 0.f;
        out[(size_t)(n1 + 1) * 64 + l] = pack2bf(ox2, oy2);
    }
}

// ---------------- BN2 stats (packed-word loads + LDS reduce) ----------------
__global__ __launch_bounds__(256) void k_bn2stats(const unsigned* __restrict__ outw, float* __restrict__ sum,
                                                  float* __restrict__ sq, int N) {
    __shared__ float4 ls[256];
    const int t = threadIdx.x;
    const int w = t & 63;
    const int rg = t >> 6;
    f32x2 sm = {0.f,0.f}, s2 = {0.f,0.f};
    for (int n = blockIdx.x * 4 + rg; n < N; n += gridDim.x * 4) {
        unsigned v = outw[(size_t)n * 64 + w];
        f32x2 x = {bflo(v), bfhi(v)};
        sm += x;
        s2 = pk_fma2(x, x, s2);
    }
    ls[t] = (float4){sm.x, sm.y, s2.x, s2.y};
    __syncthreads();
    if (t < 64) {
        float4 a = ls[t], b = ls[t + 64], c = ls[t + 128], d = ls[t + 192];
        atomicAdd(&sum[2 * w],     a.x + b.x + c.x + d.x);
        atomicAdd(&sum[2 * w + 1], a.y + b.y + c.y + d.y);
        atomicAdd(&sq[2 * w],      a.z + b.z + c.z + d.z);
        atomicAdd(&sq[2 * w + 1],  a.w + b.w + c.w + d.w);
    }
}

// ---------------- fused BN2-finalize + residual+softplus + mean-pool (bf16 inputs) ----------------
template<int SPLIT>
__global__ __launch_bounds__(128) void k_h2pool(const unsigned short* __restrict__ out,
                                                const unsigned short* __restrict__ h,
                                                const int* __restrict__ gptr, const int* __restrict__ gnodes,
                                                const float* __restrict__ bn2_sum, const float* __restrict__ bn2_sq,
                                                const float* __restrict__ g2, const float* __restrict__ b2,
                                                float* __restrict__ pooled, float invN) {
    const int g = blockIdx.x & 127;
    const int sp = blockIdx.x >> 7;
    const int c = threadIdx.x;
    float mu = bn2_sum[c] * invN;
    float var = bn2_sq[c] * invN - mu * mu;
    float sc = g2[c] * rsqrtf(var + EPS_BN);
    float sh = fmaf(-mu, sc, b2[c]);
    const int i0 = gptr[g], i1 = gptr[g + 1];
    float acc = 0.f;
    for (int i = i0 + sp; i < i1; i += SPLIT) {
        int n = gnodes[i];
        float v = fmaf(bfu16(out[(size_t)n * 128 + c]), sc, sh) + bfu16(h[(size_t)n * 128 + c]);
        acc += softplus_fast(v);
    }
    if (acc != 0.f) atomicAdd(&pooled[g * 128 + c], acc);
}

// ---------------- head ----------------
__global__ __launch_bounds__(256) void k_head(const float* __restrict__ pooled, const int* __restrict__ gcount,
                                              const float* __restrict__ l1w, const float* __restrict__ l1b,
                                              const float* __restrict__ outw, const float* __restrict__ outb,
                                              float* __restrict__ dout) {
    __shared__ float p[128];
    __shared__ float red[256];
    const int g = blockIdx.x;
    const int j = threadIdx.x;
    if (j < 128) {
        float cnt = (float)max(gcount[g], 1);
        p[j] = pooled[g * 128 + j] / cnt;
    }
    __syncthreads();
    float acc = l1b[j];
    for (int k = 0; k < 128; k++) acc = fmaf(p[k], l1w[k * 256 + j], acc);
    red[j] = softplus_fast(acc) * outw[j];
    __syncthreads();
    for (int s = 128; s > 0; s >>= 1) {
        if (j < s) red[j] += red[j + s];
        __syncthreads();
    }
    if (j == 0) dout[g] = red[0] + outb[0];
}

// ---------------- launch ----------------
extern "C" void kernel_launch(void* const* d_in, const int* in_sizes, int n_in,
                              void* d_out, int out_size, void* d_ws, size_t ws_size,
                              hipStream_t stream) {
    const float* x        = (const float*)d_in[0];
    const float* hedge    = (const float*)d_in[1];
    const int*   iri      = (const int*)d_in[2];
    const int*   batch    = (const int*)d_in[3];
    const float* embed_w  = (const float*)d_in[5];
    const float* embed_b  = (const float*)d_in[6];
    const float* bembed_w = (const float*)d_in[7];
    const float* bembed_b = (const float*)d_in[8];
    const float* lin_w    = (const float*)d_in[9];
    const float* lin_b    = (const float*)d_in[10];
    const float* bn1_g    = (const float*)d_in[11];
    const float* bn1_b    = (const float*)d_in[12];
    const float* bn2_g    = (const float*)d_in[13];
    const float* bn2_b    = (const float*)d_in[14];
    const float* aggr_t   = (const float*)d_in[15];
    const float* l1_w     = (const float*)d_in[16];
    const float* l1_b     = (const float*)d_in[17];
    const float* out_w    = (const float*)d_in[18];
    const float* out_b    = (const float*)d_in[19];

    const int N   = in_sizes[0] / 92;
    const int NHE = in_sizes[1] / 40;
    const int E   = in_sizes[2] / 3;
    const int* idx0 = iri;
    const int* idx1 = iri + E;

    float* ws = (float*)d_ws;
    size_t off = 0;
    auto alloc = [&](size_t elems) -> float* {
        float* p = ws + off;
        off += (elems + 63) & ~(size_t)63;
        return p;
    };
    unsigned short* h16 = (unsigned short*)alloc((size_t)N * 64);   // N*128 bf16
    uint2* A16    = (uint2*)alloc((size_t)N * 128);                 // N*256 bf16 packed
    unsigned* Cp8 = (unsigned*)alloc((size_t)NHE * 64);             // NHE*256 fp8 packed
    unsigned short* embB  = (unsigned short*)alloc(6144);
    unsigned short* bembB = (unsigned short*)alloc(4096);
    unsigned short* waB   = (unsigned short*)alloc(16384);
    unsigned short* wcB   = (unsigned short*)alloc(16384);
    int*   rowptr = (int*)alloc((size_t)N + 1);
    int*   sidx1  = (int*)alloc((size_t)E + 8);
    int*   gptr   = (int*)alloc(129);
    int*   gnodes = (int*)alloc((size_t)N);
    unsigned* outbuf = (unsigned*)alloc((size_t)N * 64);            // N*128 bf16
    int2*  slots  = (int2*)alloc(2 * 8200);                         // slot->node bounds (+sentinel)
    // contiguous zero region
    float* zbase  = ws + off;
    int*   hist   = (int*)alloc((size_t)N);
    int*   fill   = (int*)alloc((size_t)N);
    int*   gfill  = (int*)alloc(128);
    float* bn1_sum = alloc(256);
    float* bn1_sq  = alloc(256);
    float* bn2_sum = alloc(128);
    float* bn2_sq  = alloc(128);
    float* pooled  = alloc(128 * 128);
    int*   gcount  = (int*)alloc(128);
    size_t zbytes = (size_t)((ws + off) - zbase) * sizeof(float);
    (void)ws_size;  // ~78MB; fit verified

    hipMemsetAsync(zbase, 0, zbytes, stream);

    // frag-major bf16 weight prep + fused MFMA GEMM chains.
    // GEMM1 also builds hist0 (idx0 degree); GEMM2 builds gcount.
    k_prepw<<<320, 256, 0, stream>>>(embed_w, bembed_w, lin_w, embB, bembB, waB, wcB);
    const int mtN   = (N + 31) / 32;
    const int mtNHE = (NHE + 31) / 32;
    mfma_fused<92, 3, 1><<<mtN, 256, 0, stream>>>(x, embB, embed_b, waB, lin_b, h16, A16, N,
                                                  idx0, hist, E);
    mfma_fused<40, 2, 2><<<mtNHE, 256, 0, stream>>>(hedge, bembB, bembed_b, wcB, nullptr, nullptr, Cp8, NHE,
                                                    batch, gcount, N);

    // prefix sums
    k_scanall<<<1, 1024, 0, stream>>>(hist, rowptr, gcount, gptr, N);

    // unified slot geometry for k_stats (8 | per_slot)
    const int EDGE_BLOCKS = 2048;
    const int NSLOTS = EDGE_BLOCKS * 4;
    int per_slot = ((E + NSLOTS - 1) / NSLOTS + 7) & ~7;
    int nslots_used = (E + per_slot - 1) / per_slot;

    // merged scatter + slot table + deg0-weighted A moments
    const int SC_BLOCKS = ((E > N ? E : N) + 255) / 256;
    const int SL_BLOCKS = (nslots_used + 1 + 255) / 256;
    const int RS_BLOCKS = 256;
    k_build<<<SC_BLOCKS + SL_BLOCKS + RS_BLOCKS, 256, 0, stream>>>(
        idx0, idx1, batch, rowptr, gptr, fill, gfill, sidx1, gnodes, slots,
        A16, hist, bn1_sum, bn1_sq, E, N, per_slot, nslots_used, SC_BLOCKS, SL_BLOCKS);

    // BN1 edge stats (C moments + cross term)
    k_stats<<<EDGE_BLOCKS, 256, 0, stream>>>(A16, (const unsigned char*)Cp8, rowptr, sidx1, slots,
                                             bn1_sum, bn1_sq, E, N, per_slot);

    // fused BN1-finalize + message + softmax aggregation (2 nodes/wave, dual stream)
    k_aggr<<<(N + 7) / 8, 256, 0, stream>>>(A16, (const unsigned char*)Cp8, rowptr, sidx1,
                                            bn1_sum, bn1_sq, bn1_g, bn1_b, aggr_t, outbuf,
                                            1.0f / (float)E, N);

    // BN2 stats + fused finalize/residual/softplus/pool
    k_bn2stats<<<256, 256, 0, stream>>>((const unsigned*)outbuf, bn2_sum, bn2_sq, N);
    k_h2pool<16><<<128 * 16, 128, 0, stream>>>((const unsigned short*)outbuf, h16, gptr, gnodes,
                                               bn2_sum, bn2_sq, bn2_g, bn2_b, pooled, 1.0f / (float)N);

    // head
    k_head<<<128, 256, 0, stream>>>(pooled, gcount, l1_w, l1_b, out_w, out_b, (float*)d_out);
}

// Round 5
// 572.911 us; speedup vs baseline: 1.1494x; 1.0291x over previous
//
#include <hip/hip_runtime.h>
#include <hip/hip_bf16.h>

// CrystalHypergraphConv — MI355X implementation.
//
// z[e] = A[idx0[e]] + C[idx1[e]];  A [N,256] bf16-packed; C [NHE,256]
// fp8-e4m3-packed. Lane l owns channels {2l,2l+1,128+2l,129+2l}.
//
// R21 -> R22: CSR scatter de-randomized (was 94us at 57MB partial-line
// writeback, VALU 1.6%). Two-level bucket sort, bucket = idx0>>8:
//  - k_binA: LDS bucket histogram -> one global atomic per (block,bucket)
//    reserves contiguous staging segments -> packed (idx1<<8|idx0_low)
//    writes in ~10-edge runs. 800k fill[] atomics -> ~40k bfill atomics;
//    51MB scattered writeback -> 3.2MB dense.
//  - k_binB (in k_build2): per-bucket LDS node ranks, writes sidx1 into
//    the bucket's contiguous CSR region (hot 8KB -> full-line writeback).
//  slots + rowstats stay co-scheduled in k_build2 (no read of sidx1 there).

#define EPS_BN 1e-5f
#define LOG2E 1.4426950408889634f
#define LN2   0.6931471805599453f

#define BIN_SH 8
#define BIN_CHUNK 4096

typedef __attribute__((ext_vector_type(8))) short bf16x8;
typedef __attribute__((ext_vector_type(4))) float f32x4;
typedef __attribute__((ext_vector_type(2))) float f32x2;

__device__ __forceinline__ float fexp2(float x) {
#if __has_builtin(__builtin_amdgcn_exp2f)
    return __builtin_amdgcn_exp2f(x);
#else
    return __expf(x * LN2);
#endif
}
__device__ __forceinline__ float flog2(float x) {
#if __has_builtin(__builtin_amdgcn_logf)
    return __builtin_amdgcn_logf(x);
#else
    return __logf(x) * LOG2E;
#endif
}
__device__ __forceinline__ float softplus_fast(float x) {
    return LN2 * flog2(1.f + fexp2(x * LOG2E));
}

__device__ __forceinline__ f32x2 pk_fma2(f32x2 a, f32x2 b, f32x2 c) {
#if __has_builtin(__builtin_elementwise_fma)
    return __builtin_elementwise_fma(a, b, c);
#else
    return (f32x2){fmaf(a.x, b.x, c.x), fmaf(a.y, b.y, c.y)};
#endif
}

__device__ __forceinline__ unsigned short f2bf(float f) {
    unsigned u = __float_as_uint(f);
    unsigned r = (u + 0x7fffu + ((u >> 16) & 1u)) >> 16;   // RNE
    return (unsigned short)r;
}
__device__ __forceinline__ float bflo(unsigned u) { return __uint_as_float(u << 16); }
__device__ __forceinline__ float bfhi(unsigned u) { return __uint_as_float(u & 0xffff0000u); }
__device__ __forceinline__ float bfu16(unsigned short v) { return __uint_as_float(((unsigned)v) << 16); }
__device__ __forceinline__ unsigned pack2bf(float x, float y) {
    return (unsigned)f2bf(x) | ((unsigned)f2bf(y) << 16);
}

// ---- fp8 e4m3 encode/decode (OCP; HW path on gfx950) ----
#if __has_builtin(__builtin_amdgcn_cvt_pk_f32_fp8) && __has_builtin(__builtin_amdgcn_cvt_pk_fp8_f32)
#define HW_FP8 1
#else
#define HW_FP8 0
#endif

__device__ __forceinline__ unsigned char f2fp8(float f) {
#if HW_FP8
    int r = __builtin_amdgcn_cvt_pk_fp8_f32(f, f, 0, false);
    return (unsigned char)(r & 0xff);
#else
    unsigned u = __float_as_uint(f);
    unsigned s = (u >> 24) & 0x80u;
    float af = fabsf(f);
    if (!(af >= 0.015625f)) {
        int m = (int)rintf(af * 512.f);
        if (m > 7) m = 7;
        return (unsigned char)(s | (unsigned)m);
    }
    if (af > 448.f) return (unsigned char)(s | 0x7e);
    unsigned au = __float_as_uint(af);
    unsigned r = au + 0x7ffffu + ((au >> 20) & 1u);
    int e8 = (int)(r >> 23) - 120;
    unsigned m = (r >> 20) & 7u;
    if (e8 > 15 || (e8 == 15 && m == 7)) return (unsigned char)(s | 0x7e);
    return (unsigned char)(s | ((unsigned)e8 << 3) | m);
#endif
}

// decode packed word -> lo pair (bytes 0,1 = f channels), hi pair (bytes 2,3 = c channels)
__device__ __forceinline__ void fp8pair(unsigned p, f32x2& lo, f32x2& hi) {
#if HW_FP8
    lo = __builtin_amdgcn_cvt_pk_f32_fp8((int)p, false);
    hi = __builtin_amdgcn_cvt_pk_f32_fp8((int)p, true);
#else
    auto dec = [](unsigned byte) -> float {
        unsigned s = (byte & 0x80u) << 24;
        unsigned em = byte & 0x7fu;
        float nrm = __uint_as_float(s | ((em << 20) + 0x3C000000u));
        float sub = __uint_as_float(s | 0x3F800000u) * (float)em * 0.001953125f;
        return (em >= 8) ? nrm : sub;
    };
    lo = (f32x2){dec(p & 0xff), dec((p >> 8) & 0xff)};
    hi = (f32x2){dec((p >> 16) & 0xff), dec(p >> 24)};
#endif
}

__device__ __forceinline__ int perm256(int j) {
    return (j < 128) ? ((j >> 1) * 4 + (j & 1)) : (((j - 128) >> 1) * 4 + 2 + (j & 1));
}

// ---------------- weight prep: frag-major bf16 B tables ----------------
__global__ __launch_bounds__(256) void k_prepw(const float* __restrict__ ew, const float* __restrict__ bw,
                                               const float* __restrict__ lw,
                                               unsigned short* __restrict__ embB, unsigned short* __restrict__ bembB,
                                               unsigned short* __restrict__ waB, unsigned short* __restrict__ wcB) {
    int i = blockIdx.x * 256 + threadIdx.x;          // 0..81919
    if (i >= 81920) return;
    unsigned short* dst;
    int f, NKC, CT, mode;
    if (i < 12288)      { dst = embB;  f = i;         NKC = 3; CT = 2; mode = 0; }
    else if (i < 20480) { dst = bembB; f = i - 12288; NKC = 2; CT = 2; mode = 1; }
    else if (i < 53248) { dst = waB;   f = i - 20480; NKC = 4; CT = 4; mode = 2; }
    else                { dst = wcB;   f = i - 53248; NKC = 4; CT = 4; mode = 3; }
    int j = f & 7, l = (f >> 3) & 63;
    int r2 = f >> 9;
    int c = r2 % CT;
    int r3 = r2 / CT;
    int kc = r3 % NKC, w = r3 / NKC;
    int k = kc * 32 + ((l >> 4) & 3) * 8 + j;
    int n = (w * CT + c) * 16 + (l & 15);
    float v;
    if (mode == 0)      v = (k < 92) ? ew[k * 128 + n] : 0.f;
    else if (mode == 1) v = (k < 40) ? bw[k * 128 + n] : 0.f;
    else if (mode == 2) v = lw[k * 256 + n] + lw[(k + 256) * 256 + n];
    else                v = lw[(k + 128) * 256 + n];
    dst[f] = f2bf(v);
}

// ---------------- fused 2-stage MFMA GEMM (+ histogram atomic prologue) ----------------
// OMODE2: 1 = bf16-packed A + bf16 h out; 2 = fp8-packed C out
template<int KIN, int NKC1, int OMODE2>
__global__ __launch_bounds__(256) void mfma_fused(
    const float* __restrict__ in, const unsigned short* __restrict__ B1, const float* __restrict__ bias1,
    const unsigned short* __restrict__ B2, const float* __restrict__ bias2,
    unsigned short* __restrict__ hout, void* __restrict__ out2, int M,
    const int* __restrict__ aux_idx, int* __restrict__ aux_hist, int aux_cnt)
{
    const int r0 = blockIdx.x * 32;
    const int t = threadIdx.x;
    const int w = t >> 6;
    const int l = t & 63;
    const int m = l & 15, q = l >> 4;

    if (aux_idx) {
        const int T = gridDim.x * 256;
        for (int i = blockIdx.x * 256 + t; i < aux_cnt; i += T)
            atomicAdd(&aux_hist[aux_idx[i]], 1);
    }

    __shared__ __align__(16) unsigned short als[32 * NKC1 * 32];
    __shared__ __align__(16) unsigned short hls[32 * 136];

    const int KP = NKC1 * 32;
    for (int i = t; i < 32 * KP; i += 256) {
        int r = i / KP, k = i - r * KP;
        int gr = r0 + r;
        float v = (gr < M && k < KIN) ? in[(size_t)gr * KIN + k] : 0.f;
        int idx = (((r >> 4) * NKC1 + (k >> 5)) * 64 + ((k >> 3) & 3) * 16 + (r & 15)) * 8 + (k & 7);
        als[idx] = f2bf(v);
    }
    bf16x8 b1[NKC1][2];
    const bf16x8* B1f = (const bf16x8*)B1;
#pragma unroll
    for (int kc = 0; kc < NKC1; kc++)
#pragma unroll
        for (int c = 0; c < 2; c++)
            b1[kc][c] = B1f[((w * NKC1 + kc) * 2 + c) * 64 + l];
    __syncthreads();

    f32x4 acc1[2][2];
#pragma unroll
    for (int c = 0; c < 2; c++) { acc1[c][0] = (f32x4){0.f,0.f,0.f,0.f}; acc1[c][1] = (f32x4){0.f,0.f,0.f,0.f}; }
    const bf16x8* af = (const bf16x8*)als;
#pragma unroll
    for (int kc = 0; kc < NKC1; kc++) {
        bf16x8 a0 = af[kc * 64 + l];
        bf16x8 a1 = af[(NKC1 + kc) * 64 + l];
#pragma unroll
        for (int c = 0; c < 2; c++) {
            acc1[c][0] = __builtin_amdgcn_mfma_f32_16x16x32_bf16(a0, b1[kc][c], acc1[c][0], 0, 0, 0);
            acc1[c][1] = __builtin_amdgcn_mfma_f32_16x16x32_bf16(a1, b1[kc][c], acc1[c][1], 0, 0, 0);
        }
    }
#pragma unroll
    for (int c = 0; c < 2; c++) {
        int n1 = (w * 2 + c) * 16 + m;
        float bv = bias1[n1];
#pragma unroll
        for (int hh = 0; hh < 2; hh++) {
#pragma unroll
            for (int r = 0; r < 4; r++) {
                int row = hh * 16 + q * 4 + r;
                float val = acc1[c][hh][r] + bv;
                unsigned short bf = f2bf(val);
                hls[row * 136 + n1] = bf;
                if (OMODE2 == 1 && r0 + row < M) hout[(size_t)(r0 + row) * 128 + n1] = bf;
            }
        }
    }
    __syncthreads();

    bf16x8 b2[4][4];
    const bf16x8* B2f = (const bf16x8*)B2;
#pragma unroll
    for (int kc = 0; kc < 4; kc++)
#pragma unroll
        for (int c = 0; c < 4; c++)
            b2[kc][c] = B2f[((w * 4 + kc) * 4 + c) * 64 + l];

    f32x4 acc2[4][2];
#pragma unroll
    for (int c = 0; c < 4; c++) { acc2[c][0] = (f32x4){0.f,0.f,0.f,0.f}; acc2[c][1] = (f32x4){0.f,0.f,0.f,0.f}; }
#pragma unroll
    for (int kc = 0; kc < 4; kc++) {
        bf16x8 a0 = *(const bf16x8*)(hls + m * 136 + kc * 32 + q * 8);
        bf16x8 a1 = *(const bf16x8*)(hls + (m + 16) * 136 + kc * 32 + q * 8);
#pragma unroll
        for (int c = 0; c < 4; c++) {
            acc2[c][0] = __builtin_amdgcn_mfma_f32_16x16x32_bf16(a0, b2[kc][c], acc2[c][0], 0, 0, 0);
            acc2[c][1] = __builtin_amdgcn_mfma_f32_16x16x32_bf16(a1, b2[kc][c], acc2[c][1], 0, 0, 0);
        }
    }
#pragma unroll
    for (int c = 0; c < 4; c++) {
        int n = (w * 4 + c) * 16 + m;
        float bv = bias2 ? bias2[n] : 0.f;
        int pj = perm256(n);
#pragma unroll
        for (int hh = 0; hh < 2; hh++) {
#pragma unroll
            for (int r = 0; r < 4; r++) {
                int row = r0 + hh * 16 + q * 4 + r;
                if (row < M) {
                    float val = acc2[c][hh][r] + bv;
                    if (OMODE2 == 1) ((unsigned short*)out2)[(size_t)row * 256 + pj] = f2bf(val);
                    else             ((unsigned char*)out2)[(size_t)row * 256 + pj] = f2fp8(val);
                }
            }
        }
    }
}

// ---------------- single-block scan ----------------
__global__ __launch_bounds__(1024) void k_scanall(const int* __restrict__ hist, int* __restrict__ rowptr,
                                                  const int* __restrict__ gcount, int* __restrict__ gptr, int N) {
    __shared__ int s[1024];
    const int t = threadIdx.x;
    const int PER = (N + 1023) >> 10;
    const int b0 = t * PER;
    const int b1 = min(b0 + PER, N);
    int sum = 0;
    for (int i = b0; i < b1; i++) sum += hist[i];
    s[t] = sum;
    __syncthreads();
    for (int ofs = 1; ofs < 1024; ofs <<= 1) {
        int v = (t >= ofs) ? s[t - ofs] : 0;
        __syncthreads();
        s[t] += v;
        __syncthreads();
    }
    int run = s[t] - sum;
    for (int i = b0; i < b1; i++) {
        run += hist[i];
        rowptr[i + 1] = run;
    }
    if (t == 0) rowptr[0] = 0;
    __syncthreads();
    int gv = (t < 128) ? gcount[t] : 0;
    s[t] = gv;
    __syncthreads();
    for (int ofs = 1; ofs < 128; ofs <<= 1) {
        int v = (t >= ofs && t < 128) ? s[t - ofs] : 0;
        __syncthreads();
        if (t < 128) s[t] += v;
        __syncthreads();
    }
    if (t < 128) gptr[t + 1] = s[t];
    if (t == 0) gptr[0] = 0;
}

// ---------------- pass A: bucket edges by idx0>>8 into staging (+ gnodes scatter tail) ----------------
// staging value: (idx1 << 8) | (idx0 & 255); bucket b's staging region is
// [rowptr[b<<8], rowptr[(b+1)<<8]) — same geometry as the final CSR.
__global__ __launch_bounds__(256) void k_binA(
    const int* __restrict__ idx0, const int* __restrict__ idx1,
    const int* __restrict__ rowptr, int* __restrict__ bfill,
    int* __restrict__ staging,
    const int* __restrict__ batch, const int* __restrict__ gptr,
    int* __restrict__ gfill, int* __restrict__ gnodes,
    int E, int N, int NB, int EB)
{
    const int t = threadIdx.x;
    const int bid = blockIdx.x;
    if (bid >= EB) {                                 // ---- gnodes scatter ----
        int i = (bid - EB) * 256 + t;
        if (i < N) {
            int g = batch[i];
            int pos = gptr[g] + atomicAdd(&gfill[g], 1);
            gnodes[pos] = i;
        }
        return;
    }
    __shared__ int svals[BIN_CHUNK];
    __shared__ unsigned char sbk[BIN_CHUNK];
    __shared__ int lhist[256], lbase[256];
    const int e0 = bid * BIN_CHUNK;
    const int cnt = min(E - e0, BIN_CHUNK);
    for (int b = t; b < NB; b += 256) lhist[b] = 0;
    __syncthreads();
    for (int i = t; i < cnt; i += 256) {
        int n = idx0[e0 + i];
        int m = idx1[e0 + i];
        int bk = n >> BIN_SH;
        sbk[i] = (unsigned char)bk;
        svals[i] = (m << BIN_SH) | (n & ((1 << BIN_SH) - 1));
        atomicAdd(&lhist[bk], 1);
    }
    __syncthreads();
    for (int b = t; b < NB; b += 256) {
        int h = lhist[b];
        int base = h ? atomicAdd(&bfill[b], h) : 0;
        lbase[b] = rowptr[b << BIN_SH] + base;
        lhist[b] = 0;
    }
    __syncthreads();
    for (int i = t; i < cnt; i += 256) {
        int bk = sbk[i];
        int r = atomicAdd(&lhist[bk], 1);
        staging[lbase[bk] + r] = svals[i];
    }
}

// ---------------- merged: binB (staging->CSR) + slot table + deg0-weighted A moments ----------------
// Block ranges: [0,NB) binB; [NB,NB+SL) slots; rest rowstats. binB writes
// only sidx1, which nothing else here reads — safe co-schedule.
__global__ __launch_bounds__(256) void k_build2(
    const int* __restrict__ rowptr, const int* __restrict__ staging,
    int* __restrict__ sidx1, int2* __restrict__ slots,
    const uint2* __restrict__ A16, const int* __restrict__ hist0,
    float* __restrict__ gsum, float* __restrict__ gsq,
    int E, int N, int per_slot, int nslots, int NB, int SL_BLOCKS)
{
    __shared__ float4 lsm4[256], lsq4[256];
    __shared__ int rp[257];
    __shared__ int lcnt[256];
    const int t = threadIdx.x;
    const int bid = blockIdx.x;

    if (bid < NB) {                                  // ---- binB: bucket -> CSR ----
        const int n0 = bid << BIN_SH;
        const int nn = min(N - n0, 256);
        for (int j = t; j <= nn; j += 256) rp[j] = rowptr[n0 + j];
        lcnt[t] = 0;
        __syncthreads();
        const int s0 = rp[0], s1 = rp[nn];
        for (int i = s0 + t; i < s1; i += 256) {
            int v = staging[i];
            int nl = v & 255;
            int r = atomicAdd(&lcnt[nl], 1);
            sidx1[rp[nl] + r] = v & 0xffffff00;      // == idx1 << 8 (byte offset)
        }
        return;
    }
    if (bid < NB + SL_BLOCKS) {                      // ---- slot->node bounds ----
        int s = (bid - NB) * 256 + t;
        if (s > nslots) return;
        long base = (long)s * per_slot;
        if (base >= E) { slots[s] = (int2){N, N - 1}; return; }
        int e0 = (int)base;
        int lo = 0, hi = N;
        while (lo + 1 < hi) { int mid = (lo + hi) >> 1; if (rowptr[mid] <= e0) lo = mid; else hi = mid; }
        int nS = lo;
        int nA = 0;
        if (e0 > 0) {
            lo = 0; hi = N;
            while (lo + 1 < hi) { int mid = (lo + hi) >> 1; if (rowptr[mid] < e0) lo = mid; else hi = mid; }
            nA = hi;
        }
        slots[s] = (int2){nA, nS};
        return;
    }
    // ---- rowstats: sum(deg0*a), sum(deg0*a^2) ----
    const int s = t >> 6, l = t & 63;
    const int rb = bid - NB - SL_BLOCKS;
    const int w0 = rb * 4 + s;
    const int nw = (gridDim.x - NB - SL_BLOCKS) * 4;
    f32x2 smF = {0.f,0.f}, smC = {0.f,0.f}, sqF = {0.f,0.f}, sqC = {0.f,0.f};
    for (int n = w0; n < N; n += nw) {
        float dg = (float)hist0[n];
        uint2 a8 = A16[(size_t)n * 64 + l];
        f32x2 aF = {bflo(a8.x), bfhi(a8.x)};
        f32x2 aC = {bflo(a8.y), bfhi(a8.y)};
        f32x2 dF = aF * dg;
        f32x2 dC = aC * dg;
        smF += dF; smC += dC;
        sqF = pk_fma2(dF, aF, sqF);
        sqC = pk_fma2(dC, aC, sqC);
    }
    lsm4[t] = (float4){smF.x, smF.y, smC.x, smC.y};
    lsq4[t] = (float4){sqF.x, sqF.y, sqC.x, sqC.y};
    __syncthreads();
    const float* fm = (const float*)lsm4;
    const float* fq = (const float*)lsq4;
    float vs = fm[t] + fm[256 + t] + fm[512 + t] + fm[768 + t];
    float vq = fq[t] + fq[256 + t] + fq[512 + t] + fq[768 + t];
    atomicAdd(&gsum[t], vs);
    atomicAdd(&gsq[t], vq);
}

// ---------------- BN1 edge stats: sum(c), sum(c^2), cross 2*sum(a*csr) ----------------
__global__ __launch_bounds__(256) void k_stats(const uint2* __restrict__ A16, const unsigned char* __restrict__ Cp8b,
                                               const int* __restrict__ rowptr, const int* __restrict__ sidx1,
                                               const int2* __restrict__ slots,
                                               float* __restrict__ gsum, float* __restrict__ gsq,
                                               int E, int N, int per_slot) {
    __shared__ float4 lsm4[256], lsq4[256];
    const int t = threadIdx.x;
    const int s = t >> 6, l = t & 63;
    const int slot = blockIdx.x * 4 + s;
    const unsigned lo4 = (unsigned)(l << 2);
    const long base = (long)slot * per_slot;
    const int e0 = (int)min((long)E, base);
    const int e1 = (int)min((long)E, base + per_slot);
    f32x2 smF = {0.f,0.f}, smC = {0.f,0.f};
    f32x2 sqF = {0.f,0.f}, sqC = {0.f,0.f};        // accumulates c^2 AND 2*a*csr
    f32x2 csrF = {0.f,0.f}, csrC = {0.f,0.f};
    f32x2 aF2 = {0.f,0.f}, aC2 = {0.f,0.f};        // 2*a of current node
    int cur_n = 0, bound = 0;

    auto flush = [&]() {
        smF += csrF; smC += csrC;
        sqF = pk_fma2(aF2, csrF, sqF);
        sqC = pk_fma2(aC2, csrC, sqC);
        csrF = (f32x2){0.f,0.f}; csrC = (f32x2){0.f,0.f};
    };
    auto loadA = [&](int n) {
        uint2 a8 = A16[(size_t)n * 64 + l];
        aF2 = (f32x2){bflo(a8.x) * 2.f, bfhi(a8.x) * 2.f};
        aC2 = (f32x2){bflo(a8.y) * 2.f, bfhi(a8.y) * 2.f};
    };

    if (e0 < e1) {
        cur_n = slots[slot].y;
        bound = rowptr[cur_n + 1];
        loadA(cur_n);
    }

    auto proc = [&](int e, unsigned p) {
        if (e >= bound) {                            // wave-uniform
            flush();
            do { cur_n++; bound = rowptr[cur_n + 1]; } while (bound <= e);
            loadA(cur_n);
        }
        f32x2 vf, vc;
        fp8pair(p, vf, vc);
        csrF += vf; csrC += vc;
        sqF = pk_fma2(vf, vf, sqF);
        sqC = pk_fma2(vc, vc, sqC);
    };

    int e = e0;
    for (; e + 8 <= e1; e += 8) {
        int4 mm0 = *(const int4*)(sidx1 + e);
        int4 mm1 = *(const int4*)(sidx1 + e + 4);
        unsigned p0 = *(const unsigned*)(Cp8b + ((unsigned)mm0.x + lo4));
        unsigned p1 = *(const unsigned*)(Cp8b + ((unsigned)mm0.y + lo4));
        unsigned p2 = *(const unsigned*)(Cp8b + ((unsigned)mm0.z + lo4));
        unsigned p3 = *(const unsigned*)(Cp8b + ((unsigned)mm0.w + lo4));
        unsigned p4 = *(const unsigned*)(Cp8b + ((unsigned)mm1.x + lo4));
        unsigned p5 = *(const unsigned*)(Cp8b + ((unsigned)mm1.y + lo4));
        unsigned p6 = *(const unsigned*)(Cp8b + ((unsigned)mm1.z + lo4));
        unsigned p7 = *(const unsigned*)(Cp8b + ((unsigned)mm1.w + lo4));
        proc(e, p0); proc(e + 1, p1); proc(e + 2, p2); proc(e + 3, p3);
        proc(e + 4, p4); proc(e + 5, p5); proc(e + 6, p6); proc(e + 7, p7);
    }
    for (; e < e1; e++) proc(e, *(const unsigned*)(Cp8b + ((unsigned)sidx1[e] + lo4)));
    flush();

    lsm4[t] = (float4){smF.x, smF.y, smC.x, smC.y};
    lsq4[t] = (float4){sqF.x, sqF.y, sqC.x, sqC.y};
    __syncthreads();
    const float* fm = (const float*)lsm4;
    const float* fq = (const float*)lsq4;
    float vs = fm[t] + fm[256 + t] + fm[512 + t] + fm[768 + t];
    float vq = fq[t] + fq[256 + t] + fq[512 + t] + fq[768 + t];
    atomicAdd(&gsum[t], vs);
    atomicAdd(&gsq[t], vq);
}

// ---------------- fused BN1-finalize + msg + segment softmax ----------------
// Two adjacent nodes per wave, interleaved dual streams: shared prologue,
// independent accumulators, 2x4-deep gather prefetch (8 loads in flight).
__global__ __launch_bounds__(256) void k_aggr(const uint2* __restrict__ A16, const unsigned char* __restrict__ Cp8b,
                                              const int* __restrict__ rowptr, const int* __restrict__ sidx1,
                                              const float* __restrict__ bn1_sum, const float* __restrict__ bn1_sq,
                                              const float* __restrict__ g1, const float* __restrict__ b1,
                                              const float* __restrict__ tptr, unsigned* __restrict__ out,
                                              float invE, int N) {
    const int t = threadIdx.x;
    const int l = t & 63;
    const int n1 = blockIdx.x * 8 + (t >> 6) * 2;
    if (n1 >= N) return;
    const int has2 = (n1 + 1) < N ? 1 : 0;

    const float tt = tptr[0];
    const float4 sum4 = ((const float4*)bn1_sum)[l];
    const float4 sq4  = ((const float4*)bn1_sq)[l];
    const float2 gf = ((const float2*)g1)[l];
    const float2 gc = ((const float2*)(g1 + 128))[l];
    const float2 bf2 = ((const float2*)b1)[l];
    const float2 bc2 = ((const float2*)(b1 + 128))[l];
    auto mkss = [&](float sum, float sq, float gg, float bb, float& sc, float& sh) {
        float mu = sum * invE;
        float var = sq * invE - mu * mu;
        sc = gg * rsqrtf(var + EPS_BN);
        sh = fmaf(-mu, sc, bb);
    };
    float scx, shx, scy, shy, scz, shz, scw, shw;
    mkss(sum4.x, sq4.x, gf.x, bf2.x, scx, shx);
    mkss(sum4.y, sq4.y, gf.y, bf2.y, scy, shy);
    mkss(sum4.z, sq4.z, gc.x, bc2.x, scz, shz);
    mkss(sum4.w, sq4.w, gc.y, bc2.y, scw, shw);
    const f32x2 sF  = {-scx * LOG2E, -scy * LOG2E};
    const f32x2 bsF = {-shx * LOG2E, -shy * LOG2E};
    const f32x2 sC  = { scz * LOG2E,  scw * LOG2E};
    const f32x2 bsC = { shz * LOG2E,  shw * LOG2E};
    const unsigned lo4 = (unsigned)(l << 2);

    uint2 a1 = A16[(size_t)n1 * 64 + l];
    uint2 a2 = A16[(size_t)(n1 + has2) * 64 + l];
    const int e0 = rowptr[n1];
    const int e1 = rowptr[n1 + 1];
    const int e2 = has2 ? rowptr[n1 + 2] : e1;

    f32x2 aF1 = {bflo(a1.x), bfhi(a1.x)}, aC1 = {bflo(a1.y), bfhi(a1.y)};
    f32x2 aF2 = {bflo(a2.x), bfhi(a2.x)}, aC2 = {bflo(a2.y), bfhi(a2.y)};
    const f32x2 bF1 = pk_fma2(aF1, sF, bsF), bC1 = pk_fma2(aC1, sC, bsC);
    const f32x2 bF2 = pk_fma2(aF2, sF, bsF), bC2 = pk_fma2(aC2, sC, bsC);

    f32x2 den1 = {0.f,0.f}, num1 = {0.f,0.f}, den2 = {0.f,0.f}, num2 = {0.f,0.f};

    auto G = [&](int e) -> unsigned {
        return *(const unsigned*)(Cp8b + ((unsigned)sidx1[e] + lo4));
    };
    auto procg = [&](unsigned p, const f32x2& bF, const f32x2& bC, f32x2& den, f32x2& num) {
        f32x2 vf, vc;
        fp8pair(p, vf, vc);
        f32x2 argf = pk_fma2(vf, sF, bF);            // -zf_hat * log2e
        f32x2 argc = pk_fma2(vc, sC, bC);            //  zc_hat * log2e
        f32x2 ef = {fexp2(argf.x), fexp2(argf.y)};
        f32x2 uu = {fexp2(argc.x), fexp2(argc.y)};
        f32x2 d1 = ef + 1.f;
        f32x2 u1 = uu + 1.f;
        f32x2 sig = {__builtin_amdgcn_rcpf(d1.x), __builtin_amdgcn_rcpf(d1.y)};
        f32x2 lg = {flog2(u1.x), flog2(u1.y)};
        f32x2 M = sig * lg;
        f32x2 tM = M * tt;
        f32x2 w = {fexp2(tM.x), fexp2(tM.y)};
        den += w;
        num = pk_fma2(M, w, num);
    };

    unsigned cur1[4], cur2[4];
    int cl1 = min(e1 - e0, 4);
    int cl2 = min(e2 - e1, 4);
#pragma unroll
    for (int i = 0; i < 4; i++) if (i < cl1) cur1[i] = G(e0 + i);
#pragma unroll
    for (int i = 0; i < 4; i++) if (i < cl2) cur2[i] = G(e1 + i);
    int pl1 = e0 + cl1;
    int pl2 = e1 + cl2;
    while ((cl1 | cl2) != 0) {
        unsigned nxt1[4], nxt2[4];
        int nl1 = min(max(e1 - pl1, 0), 4);
        int nl2 = min(max(e2 - pl2, 0), 4);
#pragma unroll
        for (int i = 0; i < 4; i++) if (i < nl1) nxt1[i] = G(pl1 + i);
#pragma unroll
        for (int i = 0; i < 4; i++) if (i < nl2) nxt2[i] = G(pl2 + i);
#pragma unroll
        for (int i = 0; i < 4; i++) if (i < cl1) procg(cur1[i], bF1, bC1, den1, num1);
#pragma unroll
        for (int i = 0; i < 4; i++) if (i < cl2) procg(cur2[i], bF2, bC2, den2, num2);
#pragma unroll
        for (int i = 0; i < 4; i++) { cur1[i] = nxt1[i]; cur2[i] = nxt2[i]; }
        pl1 += nl1; pl2 += nl2;
        cl1 = nl1; cl2 = nl2;
    }
    float ox1 = den1.x != 0.f ? LN2 * num1.x * __builtin_amdgcn_rcpf(den1.x) : 0.f;
    float oy1 = den1.y != 0.f ? LN2 * num1.y * __builtin_amdgcn_rcpf(den1.y) : 0.f;
    out[(size_t)n1 * 64 + l] = pack2bf(ox1, oy1);
    if (has2) {
        float ox2 = den2.x != 0.f ? LN2 * num2.x * __builtin_amdgcn_rcpf(den2.x) : 0.f;
        float oy2 = den2.y != 0.f ? LN2 * num2.y * __builtin_amdgcn_rcpf(den2.y) : 0.f;
        out[(size_t)(n1 + 1) * 64 + l] = pack2bf(ox2, oy2);
    }
}

// ---------------- BN2 stats (packed-word loads + LDS reduce) ----------------
__global__ __launch_bounds__(256) void k_bn2stats(const unsigned* __restrict__ outw, float* __restrict__ sum,
                                                  float* __restrict__ sq, int N) {
    __shared__ float4 ls[256];
    const int t = threadIdx.x;
    const int w = t & 63;
    const int rg = t >> 6;
    f32x2 sm = {0.f,0.f}, s2 = {0.f,0.f};
    for (int n = blockIdx.x * 4 + rg; n < N; n += gridDim.x * 4) {
        unsigned v = outw[(size_t)n * 64 + w];
        f32x2 x = {bflo(v), bfhi(v)};
        sm += x;
        s2 = pk_fma2(x, x, s2);
    }
    ls[t] = (float4){sm.x, sm.y, s2.x, s2.y};
    __syncthreads();
    if (t < 64) {
        float4 a = ls[t], b = ls[t + 64], c = ls[t + 128], d = ls[t + 192];
        atomicAdd(&sum[2 * w],     a.x + b.x + c.x + d.x);
        atomicAdd(&sum[2 * w + 1], a.y + b.y + c.y + d.y);
        atomicAdd(&sq[2 * w],      a.z + b.z + c.z + d.z);
        atomicAdd(&sq[2 * w + 1],  a.w + b.w + c.w + d.w);
    }
}

// ---------------- fused BN2-finalize + residual+softplus + mean-pool (bf16 inputs) ----------------
template<int SPLIT>
__global__ __launch_bounds__(128) void k_h2pool(const unsigned short* __restrict__ out,
                                                const unsigned short* __restrict__ h,
                                                const int* __restrict__ gptr, const int* __restrict__ gnodes,
                                                const float* __restrict__ bn2_sum, const float* __restrict__ bn2_sq,
                                                const float* __restrict__ g2, const float* __restrict__ b2,
                                                float* __restrict__ pooled, float invN) {
    const int g = blockIdx.x & 127;
    const int sp = blockIdx.x >> 7;
    const int c = threadIdx.x;
    float mu = bn2_sum[c] * invN;
    float var = bn2_sq[c] * invN - mu * mu;
    float sc = g2[c] * rsqrtf(var + EPS_BN);
    float sh = fmaf(-mu, sc, b2[c]);
    const int i0 = gptr[g], i1 = gptr[g + 1];
    float acc = 0.f;
    for (int i = i0 + sp; i < i1; i += SPLIT) {
        int n = gnodes[i];
        float v = fmaf(bfu16(out[(size_t)n * 128 + c]), sc, sh) + bfu16(h[(size_t)n * 128 + c]);
        acc += softplus_fast(v);
    }
    if (acc != 0.f) atomicAdd(&pooled[g * 128 + c], acc);
}

// ---------------- head ----------------
__global__ __launch_bounds__(256) void k_head(const float* __restrict__ pooled, const int* __restrict__ gcount,
                                              const float* __restrict__ l1w, const float* __restrict__ l1b,
                                              const float* __restrict__ outw, const float* __restrict__ outb,
                                              float* __restrict__ dout) {
    __shared__ float p[128];
    __shared__ float red[256];
    const int g = blockIdx.x;
    const int j = threadIdx.x;
    if (j < 128) {
        float cnt = (float)max(gcount[g], 1);
        p[j] = pooled[g * 128 + j] / cnt;
    }
    __syncthreads();
    float acc = l1b[j];
    for (int k = 0; k < 128; k++) acc = fmaf(p[k], l1w[k * 256 + j], acc);
    red[j] = softplus_fast(acc) * outw[j];
    __syncthreads();
    for (int s = 128; s > 0; s >>= 1) {
        if (j < s) red[j] += red[j + s];
        __syncthreads();
    }
    if (j == 0) dout[g] = red[0] + outb[0];
}

// ---------------- launch ----------------
extern "C" void kernel_launch(void* const* d_in, const int* in_sizes, int n_in,
                              void* d_out, int out_size, void* d_ws, size_t ws_size,
                              hipStream_t stream) {
    const float* x        = (const float*)d_in[0];
    const float* hedge    = (const float*)d_in[1];
    const int*   iri      = (const int*)d_in[2];
    const int*   batch    = (const int*)d_in[3];
    const float* embed_w  = (const float*)d_in[5];
    const float* embed_b  = (const float*)d_in[6];
    const float* bembed_w = (const float*)d_in[7];
    const float* bembed_b = (const float*)d_in[8];
    const float* lin_w    = (const float*)d_in[9];
    const float* lin_b    = (const float*)d_in[10];
    const float* bn1_g    = (const float*)d_in[11];
    const float* bn1_b    = (const float*)d_in[12];
    const float* bn2_g    = (const float*)d_in[13];
    const float* bn2_b    = (const float*)d_in[14];
    const float* aggr_t   = (const float*)d_in[15];
    const float* l1_w     = (const float*)d_in[16];
    const float* l1_b     = (const float*)d_in[17];
    const float* out_w    = (const float*)d_in[18];
    const float* out_b    = (const float*)d_in[19];

    const int N   = in_sizes[0] / 92;
    const int NHE = in_sizes[1] / 40;
    const int E   = in_sizes[2] / 3;
    const int* idx0 = iri;
    const int* idx1 = iri + E;

    float* ws = (float*)d_ws;
    size_t off = 0;
    auto alloc = [&](size_t elems) -> float* {
        float* p = ws + off;
        off += (elems + 63) & ~(size_t)63;
        return p;
    };
    unsigned short* h16 = (unsigned short*)alloc((size_t)N * 64);   // N*128 bf16
    uint2* A16    = (uint2*)alloc((size_t)N * 128);                 // N*256 bf16 packed
    unsigned* Cp8 = (unsigned*)alloc((size_t)NHE * 64);             // NHE*256 fp8 packed
    unsigned short* embB  = (unsigned short*)alloc(6144);
    unsigned short* bembB = (unsigned short*)alloc(4096);
    unsigned short* waB   = (unsigned short*)alloc(16384);
    unsigned short* wcB   = (unsigned short*)alloc(16384);
    int*   rowptr = (int*)alloc((size_t)N + 1);
    int*   sidx1  = (int*)alloc((size_t)E + 8);
    int*   staging = (int*)alloc((size_t)E + 8);
    int*   gptr   = (int*)alloc(129);
    int*   gnodes = (int*)alloc((size_t)N);
    unsigned* outbuf = (unsigned*)alloc((size_t)N * 64);            // N*128 bf16
    int2*  slots  = (int2*)alloc(2 * 8200);                         // slot->node bounds (+sentinel)
    // contiguous zero region
    float* zbase  = ws + off;
    int*   hist   = (int*)alloc((size_t)N);
    int*   bfill  = (int*)alloc(256);
    int*   gfill  = (int*)alloc(128);
    float* bn1_sum = alloc(256);
    float* bn1_sq  = alloc(256);
    float* bn2_sum = alloc(128);
    float* bn2_sq  = alloc(128);
    float* pooled  = alloc(128 * 128);
    int*   gcount  = (int*)alloc(128);
    size_t zbytes = (size_t)((ws + off) - zbase) * sizeof(float);
    (void)ws_size;  // ~81MB; fit verified

    hipMemsetAsync(zbase, 0, zbytes, stream);

    // frag-major bf16 weight prep + fused MFMA GEMM chains.
    // GEMM1 also builds hist0 (idx0 degree); GEMM2 builds gcount.
    k_prepw<<<320, 256, 0, stream>>>(embed_w, bembed_w, lin_w, embB, bembB, waB, wcB);
    const int mtN   = (N + 31) / 32;
    const int mtNHE = (NHE + 31) / 32;
    mfma_fused<92, 3, 1><<<mtN, 256, 0, stream>>>(x, embB, embed_b, waB, lin_b, h16, A16, N,
                                                  idx0, hist, E);
    mfma_fused<40, 2, 2><<<mtNHE, 256, 0, stream>>>(hedge, bembB, bembed_b, wcB, nullptr, nullptr, Cp8, NHE,
                                                    batch, gcount, N);

    // prefix sums
    k_scanall<<<1, 1024, 0, stream>>>(hist, rowptr, gcount, gptr, N);

    // bucket pass A (+ gnodes scatter tail)
    const int NB = (N + 255) >> BIN_SH;
    const int EB = (E + BIN_CHUNK - 1) / BIN_CHUNK;
    const int GB = (N + 255) / 256;
    k_binA<<<EB + GB, 256, 0, stream>>>(idx0, idx1, rowptr, bfill, staging,
                                        batch, gptr, gfill, gnodes, E, N, NB, EB);

    // unified slot geometry for k_stats (8 | per_slot)
    const int EDGE_BLOCKS = 2048;
    const int NSLOTS = EDGE_BLOCKS * 4;
    int per_slot = ((E + NSLOTS - 1) / NSLOTS + 7) & ~7;
    int nslots_used = (E + per_slot - 1) / per_slot;

    // merged binB + slot table + deg0-weighted A moments
    const int SL_BLOCKS = (nslots_used + 1 + 255) / 256;
    const int RS_BLOCKS = 256;
    k_build2<<<NB + SL_BLOCKS + RS_BLOCKS, 256, 0, stream>>>(
        rowptr, staging, sidx1, slots, A16, hist, bn1_sum, bn1_sq,
        E, N, per_slot, nslots_used, NB, SL_BLOCKS);

    // BN1 edge stats (C moments + cross term)
    k_stats<<<EDGE_BLOCKS, 256, 0, stream>>>(A16, (const unsigned char*)Cp8, rowptr, sidx1, slots,
                                             bn1_sum, bn1_sq, E, N, per_slot);

    // fused BN1-finalize + message + softmax aggregation (2 nodes/wave, dual stream)
    k_aggr<<<(N + 7) / 8, 256, 0, stream>>>(A16, (const unsigned char*)Cp8, rowptr, sidx1,
                                            bn1_sum, bn1_sq, bn1_g, bn1_b, aggr_t, outbuf,
                                            1.0f / (float)E, N);

    // BN2 stats + fused finalize/residual/softplus/pool
    k_bn2stats<<<256, 256, 0, stream>>>((const unsigned*)outbuf, bn2_sum, bn2_sq, N);
    k_h2pool<16><<<128 * 16, 128, 0, stream>>>((const unsigned short*)outbuf, h16, gptr, gnodes,
                                               bn2_sum, bn2_sq, bn2_g, bn2_b, pooled, 1.0f / (float)N);

    // head
    k_head<<<128, 256, 0, stream>>>(pooled, gcount, l1_w, l1_b, out_w, out_b, (float*)d_out);
}

// Round 6
// 553.840 us; speedup vs baseline: 1.1889x; 1.0344x over previous
//
#include <hip/hip_runtime.h>
#include <hip/hip_bf16.h>

// CrystalHypergraphConv — MI355X implementation.
//
// z[e] = A[idx0[e]] + C[idx1[e]];  A [N,256] bf16-packed; C [NHE,256]
// fp8-e4m3-packed. Lane l owns channels {2l,2l+1,128+2l,129+2l}.
//
// R22 -> R23: edge-kernel scalarization. Evidence: k_aggr duration pinned
// 83-90us across VALU 55-78% -> ~76us stream floor (91MB at ~1.2TB/s).
// Dual-stream regressed vs R18 (88 vs 83.5) because per-element vector
// guards ate the gains. Now: single node/wave (R18 shape) with ALL bounds
// readfirstlane'd to SGPRs -> guards are s_cbranch (no VALU, no exec
// churn), sidx1[e] at scalar index -> s_load, gathers are
// global_load_dword v,v_lo4,s[base] with zero VALU address math.
// 8-deep scalar-guarded prefetch. k_stats: same scalarization of
// slot/cur_n/bound; int4 sidx reads -> s_load_dwordx4.

#define EPS_BN 1e-5f
#define LOG2E 1.4426950408889634f
#define LN2   0.6931471805599453f

#define BIN_SH 8
#define BIN_CHUNK 4096

typedef __attribute__((ext_vector_type(8))) short bf16x8;
typedef __attribute__((ext_vector_type(4))) float f32x4;
typedef __attribute__((ext_vector_type(2))) float f32x2;

__device__ __forceinline__ float fexp2(float x) {
#if __has_builtin(__builtin_amdgcn_exp2f)
    return __builtin_amdgcn_exp2f(x);
#else
    return __expf(x * LN2);
#endif
}
__device__ __forceinline__ float flog2(float x) {
#if __has_builtin(__builtin_amdgcn_logf)
    return __builtin_amdgcn_logf(x);
#else
    return __logf(x) * LOG2E;
#endif
}
__device__ __forceinline__ float softplus_fast(float x) {
    return LN2 * flog2(1.f + fexp2(x * LOG2E));
}

__device__ __forceinline__ f32x2 pk_fma2(f32x2 a, f32x2 b, f32x2 c) {
#if __has_builtin(__builtin_elementwise_fma)
    return __builtin_elementwise_fma(a, b, c);
#else
    return (f32x2){fmaf(a.x, b.x, c.x), fmaf(a.y, b.y, c.y)};
#endif
}

__device__ __forceinline__ unsigned short f2bf(float f) {
    unsigned u = __float_as_uint(f);
    unsigned r = (u + 0x7fffu + ((u >> 16) & 1u)) >> 16;   // RNE
    return (unsigned short)r;
}
__device__ __forceinline__ float bflo(unsigned u) { return __uint_as_float(u << 16); }
__device__ __forceinline__ float bfhi(unsigned u) { return __uint_as_float(u & 0xffff0000u); }
__device__ __forceinline__ float bfu16(unsigned short v) { return __uint_as_float(((unsigned)v) << 16); }
__device__ __forceinline__ unsigned pack2bf(float x, float y) {
    return (unsigned)f2bf(x) | ((unsigned)f2bf(y) << 16);
}

// ---- fp8 e4m3 encode/decode (OCP; HW path on gfx950) ----
#if __has_builtin(__builtin_amdgcn_cvt_pk_f32_fp8) && __has_builtin(__builtin_amdgcn_cvt_pk_fp8_f32)
#define HW_FP8 1
#else
#define HW_FP8 0
#endif

__device__ __forceinline__ unsigned char f2fp8(float f) {
#if HW_FP8
    int r = __builtin_amdgcn_cvt_pk_fp8_f32(f, f, 0, false);
    return (unsigned char)(r & 0xff);
#else
    unsigned u = __float_as_uint(f);
    unsigned s = (u >> 24) & 0x80u;
    float af = fabsf(f);
    if (!(af >= 0.015625f)) {
        int m = (int)rintf(af * 512.f);
        if (m > 7) m = 7;
        return (unsigned char)(s | (unsigned)m);
    }
    if (af > 448.f) return (unsigned char)(s | 0x7e);
    unsigned au = __float_as_uint(af);
    unsigned r = au + 0x7ffffu + ((au >> 20) & 1u);
    int e8 = (int)(r >> 23) - 120;
    unsigned m = (r >> 20) & 7u;
    if (e8 > 15 || (e8 == 15 && m == 7)) return (unsigned char)(s | 0x7e);
    return (unsigned char)(s | ((unsigned)e8 << 3) | m);
#endif
}

// decode packed word -> lo pair (bytes 0,1 = f channels), hi pair (bytes 2,3 = c channels)
__device__ __forceinline__ void fp8pair(unsigned p, f32x2& lo, f32x2& hi) {
#if HW_FP8
    lo = __builtin_amdgcn_cvt_pk_f32_fp8((int)p, false);
    hi = __builtin_amdgcn_cvt_pk_f32_fp8((int)p, true);
#else
    auto dec = [](unsigned byte) -> float {
        unsigned s = (byte & 0x80u) << 24;
        unsigned em = byte & 0x7fu;
        float nrm = __uint_as_float(s | ((em << 20) + 0x3C000000u));
        float sub = __uint_as_float(s | 0x3F800000u) * (float)em * 0.001953125f;
        return (em >= 8) ? nrm : sub;
    };
    lo = (f32x2){dec(p & 0xff), dec((p >> 8) & 0xff)};
    hi = (f32x2){dec((p >> 16) & 0xff), dec(p >> 24)};
#endif
}

__device__ __forceinline__ int perm256(int j) {
    return (j < 128) ? ((j >> 1) * 4 + (j & 1)) : (((j - 128) >> 1) * 4 + 2 + (j & 1));
}

// ---------------- weight prep: frag-major bf16 B tables ----------------
__global__ __launch_bounds__(256) void k_prepw(const float* __restrict__ ew, const float* __restrict__ bw,
                                               const float* __restrict__ lw,
                                               unsigned short* __restrict__ embB, unsigned short* __restrict__ bembB,
                                               unsigned short* __restrict__ waB, unsigned short* __restrict__ wcB) {
    int i = blockIdx.x * 256 + threadIdx.x;          // 0..81919
    if (i >= 81920) return;
    unsigned short* dst;
    int f, NKC, CT, mode;
    if (i < 12288)      { dst = embB;  f = i;         NKC = 3; CT = 2; mode = 0; }
    else if (i < 20480) { dst = bembB; f = i - 12288; NKC = 2; CT = 2; mode = 1; }
    else if (i < 53248) { dst = waB;   f = i - 20480; NKC = 4; CT = 4; mode = 2; }
    else                { dst = wcB;   f = i - 53248; NKC = 4; CT = 4; mode = 3; }
    int j = f & 7, l = (f >> 3) & 63;
    int r2 = f >> 9;
    int c = r2 % CT;
    int r3 = r2 / CT;
    int kc = r3 % NKC, w = r3 / NKC;
    int k = kc * 32 + ((l >> 4) & 3) * 8 + j;
    int n = (w * CT + c) * 16 + (l & 15);
    float v;
    if (mode == 0)      v = (k < 92) ? ew[k * 128 + n] : 0.f;
    else if (mode == 1) v = (k < 40) ? bw[k * 128 + n] : 0.f;
    else if (mode == 2) v = lw[k * 256 + n] + lw[(k + 256) * 256 + n];
    else                v = lw[(k + 128) * 256 + n];
    dst[f] = f2bf(v);
}

// ---------------- fused 2-stage MFMA GEMM (+ histogram atomic prologue) ----------------
// OMODE2: 1 = bf16-packed A + bf16 h out; 2 = fp8-packed C out
template<int KIN, int NKC1, int OMODE2>
__global__ __launch_bounds__(256) void mfma_fused(
    const float* __restrict__ in, const unsigned short* __restrict__ B1, const float* __restrict__ bias1,
    const unsigned short* __restrict__ B2, const float* __restrict__ bias2,
    unsigned short* __restrict__ hout, void* __restrict__ out2, int M,
    const int* __restrict__ aux_idx, int* __restrict__ aux_hist, int aux_cnt)
{
    const int r0 = blockIdx.x * 32;
    const int t = threadIdx.x;
    const int w = t >> 6;
    const int l = t & 63;
    const int m = l & 15, q = l >> 4;

    if (aux_idx) {
        const int T = gridDim.x * 256;
        for (int i = blockIdx.x * 256 + t; i < aux_cnt; i += T)
            atomicAdd(&aux_hist[aux_idx[i]], 1);
    }

    __shared__ __align__(16) unsigned short als[32 * NKC1 * 32];
    __shared__ __align__(16) unsigned short hls[32 * 136];

    const int KP = NKC1 * 32;
    for (int i = t; i < 32 * KP; i += 256) {
        int r = i / KP, k = i - r * KP;
        int gr = r0 + r;
        float v = (gr < M && k < KIN) ? in[(size_t)gr * KIN + k] : 0.f;
        int idx = (((r >> 4) * NKC1 + (k >> 5)) * 64 + ((k >> 3) & 3) * 16 + (r & 15)) * 8 + (k & 7);
        als[idx] = f2bf(v);
    }
    bf16x8 b1[NKC1][2];
    const bf16x8* B1f = (const bf16x8*)B1;
#pragma unroll
    for (int kc = 0; kc < NKC1; kc++)
#pragma unroll
        for (int c = 0; c < 2; c++)
            b1[kc][c] = B1f[((w * NKC1 + kc) * 2 + c) * 64 + l];
    __syncthreads();

    f32x4 acc1[2][2];
#pragma unroll
    for (int c = 0; c < 2; c++) { acc1[c][0] = (f32x4){0.f,0.f,0.f,0.f}; acc1[c][1] = (f32x4){0.f,0.f,0.f,0.f}; }
    const bf16x8* af = (const bf16x8*)als;
#pragma unroll
    for (int kc = 0; kc < NKC1; kc++) {
        bf16x8 a0 = af[kc * 64 + l];
        bf16x8 a1 = af[(NKC1 + kc) * 64 + l];
#pragma unroll
        for (int c = 0; c < 2; c++) {
            acc1[c][0] = __builtin_amdgcn_mfma_f32_16x16x32_bf16(a0, b1[kc][c], acc1[c][0], 0, 0, 0);
            acc1[c][1] = __builtin_amdgcn_mfma_f32_16x16x32_bf16(a1, b1[kc][c], acc1[c][1], 0, 0, 0);
        }
    }
#pragma unroll
    for (int c = 0; c < 2; c++) {
        int n1 = (w * 2 + c) * 16 + m;
        float bv = bias1[n1];
#pragma unroll
        for (int hh = 0; hh < 2; hh++) {
#pragma unroll
            for (int r = 0; r < 4; r++) {
                int row = hh * 16 + q * 4 + r;
                float val = acc1[c][hh][r] + bv;
                unsigned short bf = f2bf(val);
                hls[row * 136 + n1] = bf;
                if (OMODE2 == 1 && r0 + row < M) hout[(size_t)(r0 + row) * 128 + n1] = bf;
            }
        }
    }
    __syncthreads();

    bf16x8 b2[4][4];
    const bf16x8* B2f = (const bf16x8*)B2;
#pragma unroll
    for (int kc = 0; kc < 4; kc++)
#pragma unroll
        for (int c = 0; c < 4; c++)
            b2[kc][c] = B2f[((w * 4 + kc) * 4 + c) * 64 + l];

    f32x4 acc2[4][2];
#pragma unroll
    for (int c = 0; c < 4; c++) { acc2[c][0] = (f32x4){0.f,0.f,0.f,0.f}; acc2[c][1] = (f32x4){0.f,0.f,0.f,0.f}; }
#pragma unroll
    for (int kc = 0; kc < 4; kc++) {
        bf16x8 a0 = *(const bf16x8*)(hls + m * 136 + kc * 32 + q * 8);
        bf16x8 a1 = *(const bf16x8*)(hls + (m + 16) * 136 + kc * 32 + q * 8);
#pragma unroll
        for (int c = 0; c < 4; c++) {
            acc2[c][0] = __builtin_amdgcn_mfma_f32_16x16x32_bf16(a0, b2[kc][c], acc2[c][0], 0, 0, 0);
            acc2[c][1] = __builtin_amdgcn_mfma_f32_16x16x32_bf16(a1, b2[kc][c], acc2[c][1], 0, 0, 0);
        }
    }
#pragma unroll
    for (int c = 0; c < 4; c++) {
        int n = (w * 4 + c) * 16 + m;
        float bv = bias2 ? bias2[n] : 0.f;
        int pj = perm256(n);
#pragma unroll
        for (int hh = 0; hh < 2; hh++) {
#pragma unroll
            for (int r = 0; r < 4; r++) {
                int row = r0 + hh * 16 + q * 4 + r;
                if (row < M) {
                    float val = acc2[c][hh][r] + bv;
                    if (OMODE2 == 1) ((unsigned short*)out2)[(size_t)row * 256 + pj] = f2bf(val);
                    else             ((unsigned char*)out2)[(size_t)row * 256 + pj] = f2fp8(val);
                }
            }
        }
    }
}

// ---------------- single-block scan ----------------
__global__ __launch_bounds__(1024) void k_scanall(const int* __restrict__ hist, int* __restrict__ rowptr,
                                                  const int* __restrict__ gcount, int* __restrict__ gptr, int N) {
    __shared__ int s[1024];
    const int t = threadIdx.x;
    const int PER = (N + 1023) >> 10;
    const int b0 = t * PER;
    const int b1 = min(b0 + PER, N);
    int sum = 0;
    for (int i = b0; i < b1; i++) sum += hist[i];
    s[t] = sum;
    __syncthreads();
    for (int ofs = 1; ofs < 1024; ofs <<= 1) {
        int v = (t >= ofs) ? s[t - ofs] : 0;
        __syncthreads();
        s[t] += v;
        __syncthreads();
    }
    int run = s[t] - sum;
    for (int i = b0; i < b1; i++) {
        run += hist[i];
        rowptr[i + 1] = run;
    }
    if (t == 0) rowptr[0] = 0;
    __syncthreads();
    int gv = (t < 128) ? gcount[t] : 0;
    s[t] = gv;
    __syncthreads();
    for (int ofs = 1; ofs < 128; ofs <<= 1) {
        int v = (t >= ofs && t < 128) ? s[t - ofs] : 0;
        __syncthreads();
        if (t < 128) s[t] += v;
        __syncthreads();
    }
    if (t < 128) gptr[t + 1] = s[t];
    if (t == 0) gptr[0] = 0;
}

// ---------------- pass A: bucket edges by idx0>>8 into staging (+ gnodes scatter tail) ----------------
__global__ __launch_bounds__(256) void k_binA(
    const int* __restrict__ idx0, const int* __restrict__ idx1,
    const int* __restrict__ rowptr, int* __restrict__ bfill,
    int* __restrict__ staging,
    const int* __restrict__ batch, const int* __restrict__ gptr,
    int* __restrict__ gfill, int* __restrict__ gnodes,
    int E, int N, int NB, int EB)
{
    const int t = threadIdx.x;
    const int bid = blockIdx.x;
    if (bid >= EB) {                                 // ---- gnodes scatter ----
        int i = (bid - EB) * 256 + t;
        if (i < N) {
            int g = batch[i];
            int pos = gptr[g] + atomicAdd(&gfill[g], 1);
            gnodes[pos] = i;
        }
        return;
    }
    __shared__ int svals[BIN_CHUNK];
    __shared__ unsigned char sbk[BIN_CHUNK];
    __shared__ int lhist[256], lbase[256];
    const int e0 = bid * BIN_CHUNK;
    const int cnt = min(E - e0, BIN_CHUNK);
    for (int b = t; b < NB; b += 256) lhist[b] = 0;
    __syncthreads();
    for (int i = t; i < cnt; i += 256) {
        int n = idx0[e0 + i];
        int m = idx1[e0 + i];
        int bk = n >> BIN_SH;
        sbk[i] = (unsigned char)bk;
        svals[i] = (m << BIN_SH) | (n & ((1 << BIN_SH) - 1));
        atomicAdd(&lhist[bk], 1);
    }
    __syncthreads();
    for (int b = t; b < NB; b += 256) {
        int h = lhist[b];
        int base = h ? atomicAdd(&bfill[b], h) : 0;
        lbase[b] = rowptr[b << BIN_SH] + base;
        lhist[b] = 0;
    }
    __syncthreads();
    for (int i = t; i < cnt; i += 256) {
        int bk = sbk[i];
        int r = atomicAdd(&lhist[bk], 1);
        staging[lbase[bk] + r] = svals[i];
    }
}

// ---------------- merged: binB (staging->CSR) + slot table + deg0-weighted A moments ----------------
__global__ __launch_bounds__(256) void k_build2(
    const int* __restrict__ rowptr, const int* __restrict__ staging,
    int* __restrict__ sidx1, int2* __restrict__ slots,
    const uint2* __restrict__ A16, const int* __restrict__ hist0,
    float* __restrict__ gsum, float* __restrict__ gsq,
    int E, int N, int per_slot, int nslots, int NB, int SL_BLOCKS)
{
    __shared__ float4 lsm4[256], lsq4[256];
    __shared__ int rp[257];
    __shared__ int lcnt[256];
    const int t = threadIdx.x;
    const int bid = blockIdx.x;

    if (bid < NB) {                                  // ---- binB: bucket -> CSR ----
        const int n0 = bid << BIN_SH;
        const int nn = min(N - n0, 256);
        for (int j = t; j <= nn; j += 256) rp[j] = rowptr[n0 + j];
        lcnt[t] = 0;
        __syncthreads();
        const int s0 = rp[0], s1 = rp[nn];
        for (int i = s0 + t; i < s1; i += 256) {
            int v = staging[i];
            int nl = v & 255;
            int r = atomicAdd(&lcnt[nl], 1);
            sidx1[rp[nl] + r] = v & 0xffffff00;      // == idx1 << 8 (byte offset)
        }
        return;
    }
    if (bid < NB + SL_BLOCKS) {                      // ---- slot->node bounds ----
        int s = (bid - NB) * 256 + t;
        if (s > nslots) return;
        long base = (long)s * per_slot;
        if (base >= E) { slots[s] = (int2){N, N - 1}; return; }
        int e0 = (int)base;
        int lo = 0, hi = N;
        while (lo + 1 < hi) { int mid = (lo + hi) >> 1; if (rowptr[mid] <= e0) lo = mid; else hi = mid; }
        int nS = lo;
        int nA = 0;
        if (e0 > 0) {
            lo = 0; hi = N;
            while (lo + 1 < hi) { int mid = (lo + hi) >> 1; if (rowptr[mid] < e0) lo = mid; else hi = mid; }
            nA = hi;
        }
        slots[s] = (int2){nA, nS};
        return;
    }
    // ---- rowstats: sum(deg0*a), sum(deg0*a^2) ----
    const int s = t >> 6, l = t & 63;
    const int rb = bid - NB - SL_BLOCKS;
    const int w0 = rb * 4 + s;
    const int nw = (gridDim.x - NB - SL_BLOCKS) * 4;
    f32x2 smF = {0.f,0.f}, smC = {0.f,0.f}, sqF = {0.f,0.f}, sqC = {0.f,0.f};
    for (int n = w0; n < N; n += nw) {
        float dg = (float)hist0[n];
        uint2 a8 = A16[(size_t)n * 64 + l];
        f32x2 aF = {bflo(a8.x), bfhi(a8.x)};
        f32x2 aC = {bflo(a8.y), bfhi(a8.y)};
        f32x2 dF = aF * dg;
        f32x2 dC = aC * dg;
        smF += dF; smC += dC;
        sqF = pk_fma2(dF, aF, sqF);
        sqC = pk_fma2(dC, aC, sqC);
    }
    lsm4[t] = (float4){smF.x, smF.y, smC.x, smC.y};
    lsq4[t] = (float4){sqF.x, sqF.y, sqC.x, sqC.y};
    __syncthreads();
    const float* fm = (const float*)lsm4;
    const float* fq = (const float*)lsq4;
    float vs = fm[t] + fm[256 + t] + fm[512 + t] + fm[768 + t];
    float vq = fq[t] + fq[256 + t] + fq[512 + t] + fq[768 + t];
    atomicAdd(&gsum[t], vs);
    atomicAdd(&gsq[t], vq);
}

// ---------------- BN1 edge stats: sum(c), sum(c^2), cross 2*sum(a*csr) ----------------
// Scalarized: slot/e0/e1/cur_n/bound live in SGPRs (readfirstlane); node-switch
// guard is a scalar branch; sidx1 int4 reads at scalar addresses -> s_load.
__global__ __launch_bounds__(256) void k_stats(const uint2* __restrict__ A16, const unsigned char* __restrict__ Cp8b,
                                               const int* __restrict__ rowptr, const int* __restrict__ sidx1,
                                               const int2* __restrict__ slots,
                                               float* __restrict__ gsum, float* __restrict__ gsq,
                                               int E, int N, int per_slot) {
    __shared__ float4 lsm4[256], lsq4[256];
    const int t = threadIdx.x;
    const int l = t & 63;
    const int wid = __builtin_amdgcn_readfirstlane(t >> 6);
    const int slot = blockIdx.x * 4 + wid;
    const unsigned lo4 = (unsigned)(l << 2);
    const long base = (long)slot * per_slot;
    const int e0 = (int)min((long)E, base);
    const int e1 = (int)min((long)E, base + per_slot);
    f32x2 smF = {0.f,0.f}, smC = {0.f,0.f};
    f32x2 sqF = {0.f,0.f}, sqC = {0.f,0.f};        // accumulates c^2 AND 2*a*csr
    f32x2 csrF = {0.f,0.f}, csrC = {0.f,0.f};
    f32x2 aF2 = {0.f,0.f}, aC2 = {0.f,0.f};        // 2*a of current node
    int cur_n = 0, bound = 0;

    auto flush = [&]() {
        smF += csrF; smC += csrC;
        sqF = pk_fma2(aF2, csrF, sqF);
        sqC = pk_fma2(aC2, csrC, sqC);
        csrF = (f32x2){0.f,0.f}; csrC = (f32x2){0.f,0.f};
    };
    auto loadA = [&](int n) {
        uint2 a8 = A16[(size_t)n * 64 + l];
        aF2 = (f32x2){bflo(a8.x) * 2.f, bfhi(a8.x) * 2.f};
        aC2 = (f32x2){bflo(a8.y) * 2.f, bfhi(a8.y) * 2.f};
    };

    if (e0 < e1) {
        cur_n = __builtin_amdgcn_readfirstlane(slots[slot].y);
        bound = __builtin_amdgcn_readfirstlane(rowptr[cur_n + 1]);
        loadA(cur_n);
    }

    auto proc = [&](int e, unsigned p) {
        if (e >= bound) {                            // scalar branch (e, bound in SGPR)
            flush();
            do { cur_n++; bound = __builtin_amdgcn_readfirstlane(rowptr[cur_n + 1]); } while (bound <= e);
            loadA(cur_n);
        }
        f32x2 vf, vc;
        fp8pair(p, vf, vc);
        csrF += vf; csrC += vc;
        sqF = pk_fma2(vf, vf, sqF);
        sqC = pk_fma2(vc, vc, sqC);
    };

    int e = e0;
    for (; e + 8 <= e1; e += 8) {
        int4 mm0 = *(const int4*)(sidx1 + e);
        int4 mm1 = *(const int4*)(sidx1 + e + 4);
        unsigned p0 = *(const unsigned*)(Cp8b + ((unsigned)mm0.x + lo4));
        unsigned p1 = *(const unsigned*)(Cp8b + ((unsigned)mm0.y + lo4));
        unsigned p2 = *(const unsigned*)(Cp8b + ((unsigned)mm0.z + lo4));
        unsigned p3 = *(const unsigned*)(Cp8b + ((unsigned)mm0.w + lo4));
        unsigned p4 = *(const unsigned*)(Cp8b + ((unsigned)mm1.x + lo4));
        unsigned p5 = *(const unsigned*)(Cp8b + ((unsigned)mm1.y + lo4));
        unsigned p6 = *(const unsigned*)(Cp8b + ((unsigned)mm1.z + lo4));
        unsigned p7 = *(const unsigned*)(Cp8b + ((unsigned)mm1.w + lo4));
        proc(e, p0); proc(e + 1, p1); proc(e + 2, p2); proc(e + 3, p3);
        proc(e + 4, p4); proc(e + 5, p5); proc(e + 6, p6); proc(e + 7, p7);
    }
    for (; e < e1; e++) proc(e, *(const unsigned*)(Cp8b + ((unsigned)sidx1[e] + lo4)));
    flush();

    lsm4[t] = (float4){smF.x, smF.y, smC.x, smC.y};
    lsq4[t] = (float4){sqF.x, sqF.y, sqC.x, sqC.y};
    __syncthreads();
    const float* fm = (const float*)lsm4;
    const float* fq = (const float*)lsq4;
    float vs = fm[t] + fm[256 + t] + fm[512 + t] + fm[768 + t];
    float vq = fq[t] + fq[256 + t] + fq[512 + t] + fq[768 + t];
    atomicAdd(&gsum[t], vs);
    atomicAdd(&gsq[t], vq);
}

// ---------------- fused BN1-finalize + msg + segment softmax ----------------
// One node per wave (R18 shape), fully scalarized: e0/e1 via readfirstlane,
// 8-deep prefetch with SCALAR-branch guards (no VALU, no exec churn),
// sidx1[e] at scalar index -> s_load; gather = global_load v,v_lo4,s[base].
__global__ __launch_bounds__(256) void k_aggr(const uint2* __restrict__ A16, const unsigned char* __restrict__ Cp8b,
                                              const int* __restrict__ rowptr, const int* __restrict__ sidx1,
                                              const float* __restrict__ bn1_sum, const float* __restrict__ bn1_sq,
                                              const float* __restrict__ g1, const float* __restrict__ b1,
                                              const float* __restrict__ tptr, unsigned* __restrict__ out,
                                              float invE, int N) {
    const int t = threadIdx.x;
    const int l = t & 63;
    const int wid = __builtin_amdgcn_readfirstlane(t >> 6);
    const int n = blockIdx.x * 4 + wid;
    if (n >= N) return;

    const int e0 = __builtin_amdgcn_readfirstlane(rowptr[n]);
    const int e1 = __builtin_amdgcn_readfirstlane(rowptr[n + 1]);

    const float tt = tptr[0];
    const float4 sum4 = ((const float4*)bn1_sum)[l];
    const float4 sq4  = ((const float4*)bn1_sq)[l];
    const float2 gf = ((const float2*)g1)[l];
    const float2 gc = ((const float2*)(g1 + 128))[l];
    const float2 bf2 = ((const float2*)b1)[l];
    const float2 bc2 = ((const float2*)(b1 + 128))[l];
    auto mkss = [&](float sum, float sq, float gg, float bb, float& sc, float& sh) {
        float mu = sum * invE;
        float var = sq * invE - mu * mu;
        sc = gg * rsqrtf(var + EPS_BN);
        sh = fmaf(-mu, sc, bb);
    };
    float scx, shx, scy, shy, scz, shz, scw, shw;
    mkss(sum4.x, sq4.x, gf.x, bf2.x, scx, shx);
    mkss(sum4.y, sq4.y, gf.y, bf2.y, scy, shy);
    mkss(sum4.z, sq4.z, gc.x, bc2.x, scz, shz);
    mkss(sum4.w, sq4.w, gc.y, bc2.y, scw, shw);
    const f32x2 sF  = {-scx * LOG2E, -scy * LOG2E};
    const f32x2 sC  = { scz * LOG2E,  scw * LOG2E};

    uint2 a8 = A16[(size_t)n * 64 + l];
    f32x2 aF = {bflo(a8.x), bfhi(a8.x)}, aC = {bflo(a8.y), bfhi(a8.y)};
    const f32x2 bF = pk_fma2(aF, sF, (f32x2){-shx * LOG2E, -shy * LOG2E});
    const f32x2 bC = pk_fma2(aC, sC, (f32x2){ shz * LOG2E,  shw * LOG2E});

    if (e0 >= e1) { out[(size_t)n * 64 + l] = 0u; return; }

    const unsigned lo4 = (unsigned)(l << 2);
    f32x2 den = {0.f,0.f}, num = {0.f,0.f};

    auto G = [&](int e) -> unsigned {
        return *(const unsigned*)(Cp8b + ((unsigned)sidx1[e] + lo4));
    };
    auto procg = [&](unsigned p) {
        f32x2 vf, vc;
        fp8pair(p, vf, vc);
        f32x2 argf = pk_fma2(vf, sF, bF);            // -zf_hat * log2e
        f32x2 argc = pk_fma2(vc, sC, bC);            //  zc_hat * log2e
        f32x2 ef = {fexp2(argf.x), fexp2(argf.y)};
        f32x2 uu = {fexp2(argc.x), fexp2(argc.y)};
        f32x2 d1 = ef + 1.f;
        f32x2 u1 = uu + 1.f;
        f32x2 sig = {__builtin_amdgcn_rcpf(d1.x), __builtin_amdgcn_rcpf(d1.y)};
        f32x2 lg = {flog2(u1.x), flog2(u1.y)};
        f32x2 M = sig * lg;
        f32x2 tM = M * tt;
        f32x2 w = {fexp2(tM.x), fexp2(tM.y)};
        den += w;
        num = pk_fma2(M, w, num);
    };

    const int cnt = e1 - e0;                         // scalar
    unsigned cur[8];
#pragma unroll
    for (int i = 0; i < 8; i++)
        if (i < cnt) cur[i] = G(e0 + i);             // scalar-guarded loads

    int e = e0;
    while (e + 8 < e1) {                             // full group of 8 present
        unsigned nxt[8];
#pragma unroll
        for (int i = 0; i < 8; i++)
            if (e + 8 + i < e1) nxt[i] = G(e + 8 + i);   // scalar-guarded prefetch
#pragma unroll
        for (int i = 0; i < 8; i++) procg(cur[i]);
#pragma unroll
        for (int i = 0; i < 8; i++) cur[i] = nxt[i];
        e += 8;
    }
    const int rem = e1 - e;                          // 1..8, scalar
#pragma unroll
    for (int i = 0; i < 8; i++)
        if (i < rem) procg(cur[i]);                  // scalar-branch tail

    float ox = LN2 * num.x * __builtin_amdgcn_rcpf(den.x);
    float oy = LN2 * num.y * __builtin_amdgcn_rcpf(den.y);
    out[(size_t)n * 64 + l] = pack2bf(ox, oy);
}

// ---------------- BN2 stats (packed-word loads + LDS reduce) ----------------
__global__ __launch_bounds__(256) void k_bn2stats(const unsigned* __restrict__ outw, float* __restrict__ sum,
                                                  float* __restrict__ sq, int N) {
    __shared__ float4 ls[256];
    const int t = threadIdx.x;
    const int w = t & 63;
    const int rg = t >> 6;
    f32x2 sm = {0.f,0.f}, s2 = {0.f,0.f};
    for (int n = blockIdx.x * 4 + rg; n < N; n += gridDim.x * 4) {
        unsigned v = outw[(size_t)n * 64 + w];
        f32x2 x = {bflo(v), bfhi(v)};
        sm += x;
        s2 = pk_fma2(x, x, s2);
    }
    ls[t] = (float4){sm.x, sm.y, s2.x, s2.y};
    __syncthreads();
    if (t < 64) {
        float4 a = ls[t], b = ls[t + 64], c = ls[t + 128], d = ls[t + 192];
        atomicAdd(&sum[2 * w],     a.x + b.x + c.x + d.x);
        atomicAdd(&sum[2 * w + 1], a.y + b.y + c.y + d.y);
        atomicAdd(&sq[2 * w],      a.z + b.z + c.z + d.z);
        atomicAdd(&sq[2 * w + 1],  a.w + b.w + c.w + d.w);
    }
}

// ---------------- fused BN2-finalize + residual+softplus + mean-pool (bf16 inputs) ----------------
template<int SPLIT>
__global__ __launch_bounds__(128) void k_h2pool(const unsigned short* __restrict__ out,
                                                const unsigned short* __restrict__ h,
                                                const int* __restrict__ gptr, const int* __restrict__ gnodes,
                                                const float* __restrict__ bn2_sum, const float* __restrict__ bn2_sq,
                                                const float* __restrict__ g2, const float* __restrict__ b2,
                                                float* __restrict__ pooled, float invN) {
    const int g = blockIdx.x & 127;
    const int sp = blockIdx.x >> 7;
    const int c = threadIdx.x;
    float mu = bn2_sum[c] * invN;
    float var = bn2_sq[c] * invN - mu * mu;
    float sc = g2[c] * rsqrtf(var + EPS_BN);
    float sh = fmaf(-mu, sc, b2[c]);
    const int i0 = gptr[g], i1 = gptr[g + 1];
    float acc = 0.f;
    for (int i = i0 + sp; i < i1; i += SPLIT) {
        int n = gnodes[i];
        float v = fmaf(bfu16(out[(size_t)n * 128 + c]), sc, sh) + bfu16(h[(size_t)n * 128 + c]);
        acc += softplus_fast(v);
    }
    if (acc != 0.f) atomicAdd(&pooled[g * 128 + c], acc);
}

// ---------------- head ----------------
__global__ __launch_bounds__(256) void k_head(const float* __restrict__ pooled, const int* __restrict__ gcount,
                                              const float* __restrict__ l1w, const float* __restrict__ l1b,
                                              const float* __restrict__ outw, const float* __restrict__ outb,
                                              float* __restrict__ dout) {
    __shared__ float p[128];
    __shared__ float red[256];
    const int g = blockIdx.x;
    const int j = threadIdx.x;
    if (j < 128) {
        float cnt = (float)max(gcount[g], 1);
        p[j] = pooled[g * 128 + j] / cnt;
    }
    __syncthreads();
    float acc = l1b[j];
    for (int k = 0; k < 128; k++) acc = fmaf(p[k], l1w[k * 256 + j], acc);
    red[j] = softplus_fast(acc) * outw[j];
    __syncthreads();
    for (int s = 128; s > 0; s >>= 1) {
        if (j < s) red[j] += red[j + s];
        __syncthreads();
    }
    if (j == 0) dout[g] = red[0] + outb[0];
}

// ---------------- launch ----------------
extern "C" void kernel_launch(void* const* d_in, const int* in_sizes, int n_in,
                              void* d_out, int out_size, void* d_ws, size_t ws_size,
                              hipStream_t stream) {
    const float* x        = (const float*)d_in[0];
    const float* hedge    = (const float*)d_in[1];
    const int*   iri      = (const int*)d_in[2];
    const int*   batch    = (const int*)d_in[3];
    const float* embed_w  = (const float*)d_in[5];
    const float* embed_b  = (const float*)d_in[6];
    const float* bembed_w = (const float*)d_in[7];
    const float* bembed_b = (const float*)d_in[8];
    const float* lin_w    = (const float*)d_in[9];
    const float* lin_b    = (const float*)d_in[10];
    const float* bn1_g    = (const float*)d_in[11];
    const float* bn1_b    = (const float*)d_in[12];
    const float* bn2_g    = (const float*)d_in[13];
    const float* bn2_b    = (const float*)d_in[14];
    const float* aggr_t   = (const float*)d_in[15];
    const float* l1_w     = (const float*)d_in[16];
    const float* l1_b     = (const float*)d_in[17];
    const float* out_w    = (const float*)d_in[18];
    const float* out_b    = (const float*)d_in[19];

    const int N   = in_sizes[0] / 92;
    const int NHE = in_sizes[1] / 40;
    const int E   = in_sizes[2] / 3;
    const int* idx0 = iri;
    const int* idx1 = iri + E;

    float* ws = (float*)d_ws;
    size_t off = 0;
    auto alloc = [&](size_t elems) -> float* {
        float* p = ws + off;
        off += (elems + 63) & ~(size_t)63;
        return p;
    };
    unsigned short* h16 = (unsigned short*)alloc((size_t)N * 64);   // N*128 bf16
    uint2* A16    = (uint2*)alloc((size_t)N * 128);                 // N*256 bf16 packed
    unsigned* Cp8 = (unsigned*)alloc((size_t)NHE * 64);             // NHE*256 fp8 packed
    unsigned short* embB  = (unsigned short*)alloc(6144);
    unsigned short* bembB = (unsigned short*)alloc(4096);
    unsigned short* waB   = (unsigned short*)alloc(16384);
    unsigned short* wcB   = (unsigned short*)alloc(16384);
    int*   rowptr = (int*)alloc((size_t)N + 1);
    int*   sidx1  = (int*)alloc((size_t)E + 8);
    int*   staging = (int*)alloc((size_t)E + 8);
    int*   gptr   = (int*)alloc(129);
    int*   gnodes = (int*)alloc((size_t)N);
    unsigned* outbuf = (unsigned*)alloc((size_t)N * 64);            // N*128 bf16
    int2*  slots  = (int2*)alloc(2 * 8200);                         // slot->node bounds (+sentinel)
    // contiguous zero region
    float* zbase  = ws + off;
    int*   hist   = (int*)alloc((size_t)N);
    int*   bfill  = (int*)alloc(256);
    int*   gfill  = (int*)alloc(128);
    float* bn1_sum = alloc(256);
    float* bn1_sq  = alloc(256);
    float* bn2_sum = alloc(128);
    float* bn2_sq  = alloc(128);
    float* pooled  = alloc(128 * 128);
    int*   gcount  = (int*)alloc(128);
    size_t zbytes = (size_t)((ws + off) - zbase) * sizeof(float);
    (void)ws_size;  // ~81MB; fit verified

    hipMemsetAsync(zbase, 0, zbytes, stream);

    // frag-major bf16 weight prep + fused MFMA GEMM chains.
    // GEMM1 also builds hist0 (idx0 degree); GEMM2 builds gcount.
    k_prepw<<<320, 256, 0, stream>>>(embed_w, bembed_w, lin_w, embB, bembB, waB, wcB);
    const int mtN   = (N + 31) / 32;
    const int mtNHE = (NHE + 31) / 32;
    mfma_fused<92, 3, 1><<<mtN, 256, 0, stream>>>(x, embB, embed_b, waB, lin_b, h16, A16, N,
                                                  idx0, hist, E);
    mfma_fused<40, 2, 2><<<mtNHE, 256, 0, stream>>>(hedge, bembB, bembed_b, wcB, nullptr, nullptr, Cp8, NHE,
                                                    batch, gcount, N);

    // prefix sums
    k_scanall<<<1, 1024, 0, stream>>>(hist, rowptr, gcount, gptr, N);

    // bucket pass A (+ gnodes scatter tail)
    const int NB = (N + 255) >> BIN_SH;
    const int EB = (E + BIN_CHUNK - 1) / BIN_CHUNK;
    const int GB = (N + 255) / 256;
    k_binA<<<EB + GB, 256, 0, stream>>>(idx0, idx1, rowptr, bfill, staging,
                                        batch, gptr, gfill, gnodes, E, N, NB, EB);

    // unified slot geometry for k_stats (8 | per_slot)
    const int EDGE_BLOCKS = 2048;
    const int NSLOTS = EDGE_BLOCKS * 4;
    int per_slot = ((E + NSLOTS - 1) / NSLOTS + 7) & ~7;
    int nslots_used = (E + per_slot - 1) / per_slot;

    // merged binB + slot table + deg0-weighted A moments
    const int SL_BLOCKS = (nslots_used + 1 + 255) / 256;
    const int RS_BLOCKS = 256;
    k_build2<<<NB + SL_BLOCKS + RS_BLOCKS, 256, 0, stream>>>(
        rowptr, staging, sidx1, slots, A16, hist, bn1_sum, bn1_sq,
        E, N, per_slot, nslots_used, NB, SL_BLOCKS);

    // BN1 edge stats (C moments + cross term)
    k_stats<<<EDGE_BLOCKS, 256, 0, stream>>>(A16, (const unsigned char*)Cp8, rowptr, sidx1, slots,
                                             bn1_sum, bn1_sq, E, N, per_slot);

    // fused BN1-finalize + message + softmax aggregation (1 node/wave, scalarized)
    k_aggr<<<(N + 3) / 4, 256, 0, stream>>>(A16, (const unsigned char*)Cp8, rowptr, sidx1,
                                            bn1_sum, bn1_sq, bn1_g, bn1_b, aggr_t, outbuf,
                                            1.0f / (float)E, N);

    // BN2 stats + fused finalize/residual/softplus/pool
    k_bn2stats<<<256, 256, 0, stream>>>((const unsigned*)outbuf, bn2_sum, bn2_sq, N);
    k_h2pool<16><<<128 * 16, 128, 0, stream>>>((const unsigned short*)outbuf, h16, gptr, gnodes,
                                               bn2_sum, bn2_sq, bn2_g, bn2_b, pooled, 1.0f / (float)N);

    // head
    k_head<<<128, 256, 0, stream>>>(pooled, gcount, l1_w, l1_b, out_w, out_b, (float*)d_out);
}

// Round 7
// 478.264 us; speedup vs baseline: 1.3768x; 1.1580x over previous
//
#include <hip/hip_runtime.h>
#include <hip/hip_bf16.h>

// CrystalHypergraphConv — MI355X implementation.
//
// z[e] = A[idx0[e]] + C[idx1[e]];  A [N,256] bf16-packed; C [NHE,256]
// fp8-e4m3-packed. Lane l owns channels {2l,2l+1,128+2l,129+2l}.
//
// R23 -> R24: k_scanall (81us, VALU 0.015% — single-block serial scan,
// 1/256th of the machine pointer-chasing) replaced by a hierarchical scan
// on the bucket geometry:
//   k_scanA (196 blocks): LDS scan per 256-node bucket -> rloc + bsum
//   k_scanB (1 block):    scan 196 bucket totals -> boff; gptr scan
//   rowptr materialization folded into k_binA as a block range
//     (rowptr[n] = boff[n>>8] + rloc[n]); binA's bucketing uses boff[b]
//     directly so no intra-kernel ordering dependency exists.

#define EPS_BN 1e-5f
#define LOG2E 1.4426950408889634f
#define LN2   0.6931471805599453f

#define BIN_SH 8
#define BIN_CHUNK 4096

typedef __attribute__((ext_vector_type(8))) short bf16x8;
typedef __attribute__((ext_vector_type(4))) float f32x4;
typedef __attribute__((ext_vector_type(2))) float f32x2;

__device__ __forceinline__ float fexp2(float x) {
#if __has_builtin(__builtin_amdgcn_exp2f)
    return __builtin_amdgcn_exp2f(x);
#else
    return __expf(x * LN2);
#endif
}
__device__ __forceinline__ float flog2(float x) {
#if __has_builtin(__builtin_amdgcn_logf)
    return __builtin_amdgcn_logf(x);
#else
    return __logf(x) * LOG2E;
#endif
}
__device__ __forceinline__ float softplus_fast(float x) {
    return LN2 * flog2(1.f + fexp2(x * LOG2E));
}

__device__ __forceinline__ f32x2 pk_fma2(f32x2 a, f32x2 b, f32x2 c) {
#if __has_builtin(__builtin_elementwise_fma)
    return __builtin_elementwise_fma(a, b, c);
#else
    return (f32x2){fmaf(a.x, b.x, c.x), fmaf(a.y, b.y, c.y)};
#endif
}

__device__ __forceinline__ unsigned short f2bf(float f) {
    unsigned u = __float_as_uint(f);
    unsigned r = (u + 0x7fffu + ((u >> 16) & 1u)) >> 16;   // RNE
    return (unsigned short)r;
}
__device__ __forceinline__ float bflo(unsigned u) { return __uint_as_float(u << 16); }
__device__ __forceinline__ float bfhi(unsigned u) { return __uint_as_float(u & 0xffff0000u); }
__device__ __forceinline__ float bfu16(unsigned short v) { return __uint_as_float(((unsigned)v) << 16); }
__device__ __forceinline__ unsigned pack2bf(float x, float y) {
    return (unsigned)f2bf(x) | ((unsigned)f2bf(y) << 16);
}

// ---- fp8 e4m3 encode/decode (OCP; HW path on gfx950) ----
#if __has_builtin(__builtin_amdgcn_cvt_pk_f32_fp8) && __has_builtin(__builtin_amdgcn_cvt_pk_fp8_f32)
#define HW_FP8 1
#else
#define HW_FP8 0
#endif

__device__ __forceinline__ unsigned char f2fp8(float f) {
#if HW_FP8
    int r = __builtin_amdgcn_cvt_pk_fp8_f32(f, f, 0, false);
    return (unsigned char)(r & 0xff);
#else
    unsigned u = __float_as_uint(f);
    unsigned s = (u >> 24) & 0x80u;
    float af = fabsf(f);
    if (!(af >= 0.015625f)) {
        int m = (int)rintf(af * 512.f);
        if (m > 7) m = 7;
        return (unsigned char)(s | (unsigned)m);
    }
    if (af > 448.f) return (unsigned char)(s | 0x7e);
    unsigned au = __float_as_uint(af);
    unsigned r = au + 0x7ffffu + ((au >> 20) & 1u);
    int e8 = (int)(r >> 23) - 120;
    unsigned m = (r >> 20) & 7u;
    if (e8 > 15 || (e8 == 15 && m == 7)) return (unsigned char)(s | 0x7e);
    return (unsigned char)(s | ((unsigned)e8 << 3) | m);
#endif
}

// decode packed word -> lo pair (bytes 0,1 = f channels), hi pair (bytes 2,3 = c channels)
__device__ __forceinline__ void fp8pair(unsigned p, f32x2& lo, f32x2& hi) {
#if HW_FP8
    lo = __builtin_amdgcn_cvt_pk_f32_fp8((int)p, false);
    hi = __builtin_amdgcn_cvt_pk_f32_fp8((int)p, true);
#else
    auto dec = [](unsigned byte) -> float {
        unsigned s = (byte & 0x80u) << 24;
        unsigned em = byte & 0x7fu;
        float nrm = __uint_as_float(s | ((em << 20) + 0x3C000000u));
        float sub = __uint_as_float(s | 0x3F800000u) * (float)em * 0.001953125f;
        return (em >= 8) ? nrm : sub;
    };
    lo = (f32x2){dec(p & 0xff), dec((p >> 8) & 0xff)};
    hi = (f32x2){dec((p >> 16) & 0xff), dec(p >> 24)};
#endif
}

__device__ __forceinline__ int perm256(int j) {
    return (j < 128) ? ((j >> 1) * 4 + (j & 1)) : (((j - 128) >> 1) * 4 + 2 + (j & 1));
}

// ---------------- weight prep: frag-major bf16 B tables ----------------
__global__ __launch_bounds__(256) void k_prepw(const float* __restrict__ ew, const float* __restrict__ bw,
                                               const float* __restrict__ lw,
                                               unsigned short* __restrict__ embB, unsigned short* __restrict__ bembB,
                                               unsigned short* __restrict__ waB, unsigned short* __restrict__ wcB) {
    int i = blockIdx.x * 256 + threadIdx.x;          // 0..81919
    if (i >= 81920) return;
    unsigned short* dst;
    int f, NKC, CT, mode;
    if (i < 12288)      { dst = embB;  f = i;         NKC = 3; CT = 2; mode = 0; }
    else if (i < 20480) { dst = bembB; f = i - 12288; NKC = 2; CT = 2; mode = 1; }
    else if (i < 53248) { dst = waB;   f = i - 20480; NKC = 4; CT = 4; mode = 2; }
    else                { dst = wcB;   f = i - 53248; NKC = 4; CT = 4; mode = 3; }
    int j = f & 7, l = (f >> 3) & 63;
    int r2 = f >> 9;
    int c = r2 % CT;
    int r3 = r2 / CT;
    int kc = r3 % NKC, w = r3 / NKC;
    int k = kc * 32 + ((l >> 4) & 3) * 8 + j;
    int n = (w * CT + c) * 16 + (l & 15);
    float v;
    if (mode == 0)      v = (k < 92) ? ew[k * 128 + n] : 0.f;
    else if (mode == 1) v = (k < 40) ? bw[k * 128 + n] : 0.f;
    else if (mode == 2) v = lw[k * 256 + n] + lw[(k + 256) * 256 + n];
    else                v = lw[(k + 128) * 256 + n];
    dst[f] = f2bf(v);
}

// ---------------- fused 2-stage MFMA GEMM (+ histogram atomic prologue) ----------------
// OMODE2: 1 = bf16-packed A + bf16 h out; 2 = fp8-packed C out
template<int KIN, int NKC1, int OMODE2>
__global__ __launch_bounds__(256) void mfma_fused(
    const float* __restrict__ in, const unsigned short* __restrict__ B1, const float* __restrict__ bias1,
    const unsigned short* __restrict__ B2, const float* __restrict__ bias2,
    unsigned short* __restrict__ hout, void* __restrict__ out2, int M,
    const int* __restrict__ aux_idx, int* __restrict__ aux_hist, int aux_cnt)
{
    const int r0 = blockIdx.x * 32;
    const int t = threadIdx.x;
    const int w = t >> 6;
    const int l = t & 63;
    const int m = l & 15, q = l >> 4;

    if (aux_idx) {
        const int T = gridDim.x * 256;
        for (int i = blockIdx.x * 256 + t; i < aux_cnt; i += T)
            atomicAdd(&aux_hist[aux_idx[i]], 1);
    }

    __shared__ __align__(16) unsigned short als[32 * NKC1 * 32];
    __shared__ __align__(16) unsigned short hls[32 * 136];

    const int KP = NKC1 * 32;
    for (int i = t; i < 32 * KP; i += 256) {
        int r = i / KP, k = i - r * KP;
        int gr = r0 + r;
        float v = (gr < M && k < KIN) ? in[(size_t)gr * KIN + k] : 0.f;
        int idx = (((r >> 4) * NKC1 + (k >> 5)) * 64 + ((k >> 3) & 3) * 16 + (r & 15)) * 8 + (k & 7);
        als[idx] = f2bf(v);
    }
    bf16x8 b1[NKC1][2];
    const bf16x8* B1f = (const bf16x8*)B1;
#pragma unroll
    for (int kc = 0; kc < NKC1; kc++)
#pragma unroll
        for (int c = 0; c < 2; c++)
            b1[kc][c] = B1f[((w * NKC1 + kc) * 2 + c) * 64 + l];
    __syncthreads();

    f32x4 acc1[2][2];
#pragma unroll
    for (int c = 0; c < 2; c++) { acc1[c][0] = (f32x4){0.f,0.f,0.f,0.f}; acc1[c][1] = (f32x4){0.f,0.f,0.f,0.f}; }
    const bf16x8* af = (const bf16x8*)als;
#pragma unroll
    for (int kc = 0; kc < NKC1; kc++) {
        bf16x8 a0 = af[kc * 64 + l];
        bf16x8 a1 = af[(NKC1 + kc) * 64 + l];
#pragma unroll
        for (int c = 0; c < 2; c++) {
            acc1[c][0] = __builtin_amdgcn_mfma_f32_16x16x32_bf16(a0, b1[kc][c], acc1[c][0], 0, 0, 0);
            acc1[c][1] = __builtin_amdgcn_mfma_f32_16x16x32_bf16(a1, b1[kc][c], acc1[c][1], 0, 0, 0);
        }
    }
#pragma unroll
    for (int c = 0; c < 2; c++) {
        int n1 = (w * 2 + c) * 16 + m;
        float bv = bias1[n1];
#pragma unroll
        for (int hh = 0; hh < 2; hh++) {
#pragma unroll
            for (int r = 0; r < 4; r++) {
                int row = hh * 16 + q * 4 + r;
                float val = acc1[c][hh][r] + bv;
                unsigned short bf = f2bf(val);
                hls[row * 136 + n1] = bf;
                if (OMODE2 == 1 && r0 + row < M) hout[(size_t)(r0 + row) * 128 + n1] = bf;
            }
        }
    }
    __syncthreads();

    bf16x8 b2[4][4];
    const bf16x8* B2f = (const bf16x8*)B2;
#pragma unroll
    for (int kc = 0; kc < 4; kc++)
#pragma unroll
        for (int c = 0; c < 4; c++)
            b2[kc][c] = B2f[((w * 4 + kc) * 4 + c) * 64 + l];

    f32x4 acc2[4][2];
#pragma unroll
    for (int c = 0; c < 4; c++) { acc2[c][0] = (f32x4){0.f,0.f,0.f,0.f}; acc2[c][1] = (f32x4){0.f,0.f,0.f,0.f}; }
#pragma unroll
    for (int kc = 0; kc < 4; kc++) {
        bf16x8 a0 = *(const bf16x8*)(hls + m * 136 + kc * 32 + q * 8);
        bf16x8 a1 = *(const bf16x8*)(hls + (m + 16) * 136 + kc * 32 + q * 8);
#pragma unroll
        for (int c = 0; c < 4; c++) {
            acc2[c][0] = __builtin_amdgcn_mfma_f32_16x16x32_bf16(a0, b2[kc][c], acc2[c][0], 0, 0, 0);
            acc2[c][1] = __builtin_amdgcn_mfma_f32_16x16x32_bf16(a1, b2[kc][c], acc2[c][1], 0, 0, 0);
        }
    }
#pragma unroll
    for (int c = 0; c < 4; c++) {
        int n = (w * 4 + c) * 16 + m;
        float bv = bias2 ? bias2[n] : 0.f;
        int pj = perm256(n);
#pragma unroll
        for (int hh = 0; hh < 2; hh++) {
#pragma unroll
            for (int r = 0; r < 4; r++) {
                int row = r0 + hh * 16 + q * 4 + r;
                if (row < M) {
                    float val = acc2[c][hh][r] + bv;
                    if (OMODE2 == 1) ((unsigned short*)out2)[(size_t)row * 256 + pj] = f2bf(val);
                    else             ((unsigned char*)out2)[(size_t)row * 256 + pj] = f2fp8(val);
                }
            }
        }
    }
}

// ---------------- scan stage A: per-bucket LDS scan ----------------
// rloc[n] = exclusive prefix of hist within bucket n>>8; bsum[b] = bucket total.
__global__ __launch_bounds__(256) void k_scanA(const int* __restrict__ hist, int* __restrict__ rloc,
                                               int* __restrict__ bsum, int N) {
    __shared__ int s[256];
    const int t = threadIdx.x;
    const int n0 = blockIdx.x << 8;
    const int nn = min(N - n0, 256);
    int v = (t < nn) ? hist[n0 + t] : 0;
    s[t] = v;
    __syncthreads();
#pragma unroll
    for (int ofs = 1; ofs < 256; ofs <<= 1) {
        int u = (t >= ofs) ? s[t - ofs] : 0;
        __syncthreads();
        s[t] += u;
        __syncthreads();
    }
    if (t < nn) rloc[n0 + t] = s[t] - v;             // exclusive in-bucket prefix
    if (t == 255) bsum[blockIdx.x] = s[255];
}

// ---------------- scan stage B: bucket totals + gptr (tiny, 1 block) ----------------
__global__ __launch_bounds__(256) void k_scanB(const int* __restrict__ bsum, int* __restrict__ boff,
                                               const int* __restrict__ gcount, int* __restrict__ gptr, int NB) {
    __shared__ int s[256];
    const int t = threadIdx.x;
    int v = (t < NB) ? bsum[t] : 0;
    s[t] = v;
    __syncthreads();
#pragma unroll
    for (int ofs = 1; ofs < 256; ofs <<= 1) {
        int u = (t >= ofs) ? s[t - ofs] : 0;
        __syncthreads();
        s[t] += u;
        __syncthreads();
    }
    if (t < NB) boff[t] = s[t] - v;                  // exclusive bucket offsets
    if (t == NB - 1) boff[NB] = s[t];                // total = E
    __syncthreads();
    int gv = (t < 128) ? gcount[t] : 0;
    s[t] = gv;
    __syncthreads();
#pragma unroll
    for (int ofs = 1; ofs < 128; ofs <<= 1) {
        int u = (t >= ofs && t < 128) ? s[t - ofs] : 0;
        __syncthreads();
        if (t < 128) s[t] += u;
        __syncthreads();
    }
    if (t < 128) gptr[t + 1] = s[t];
    if (t == 0) gptr[0] = 0;
}

// ---------------- pass A: bucket edges into staging + gnodes scatter + rowptr materialize ----------------
// Block ranges: [0,EB) bucketing (uses boff directly, NOT rowptr);
// [EB,EB+GB) gnodes scatter; [EB+GB, EB+GB+RB) rowptr[n]=boff[n>>8]+rloc[n].
__global__ __launch_bounds__(256) void k_binA(
    const int* __restrict__ idx0, const int* __restrict__ idx1,
    const int* __restrict__ boff, const int* __restrict__ rloc,
    int* __restrict__ rowptr, int* __restrict__ bfill,
    int* __restrict__ staging,
    const int* __restrict__ batch, const int* __restrict__ gptr,
    int* __restrict__ gfill, int* __restrict__ gnodes,
    int E, int N, int NB, int EB, int GB)
{
    const int t = threadIdx.x;
    const int bid = blockIdx.x;
    if (bid >= EB + GB) {                            // ---- rowptr materialize ----
        int i = ((bid - EB - GB) << 8) + t;
        if (i < N) rowptr[i] = boff[i >> BIN_SH] + rloc[i];
        if (bid == EB + GB && t == 0) rowptr[N] = boff[NB];
        return;
    }
    if (bid >= EB) {                                 // ---- gnodes scatter ----
        int i = (bid - EB) * 256 + t;
        if (i < N) {
            int g = batch[i];
            int pos = gptr[g] + atomicAdd(&gfill[g], 1);
            gnodes[pos] = i;
        }
        return;
    }
    __shared__ int svals[BIN_CHUNK];
    __shared__ unsigned char sbk[BIN_CHUNK];
    __shared__ int lhist[256], lbase[256];
    const int e0 = bid * BIN_CHUNK;
    const int cnt = min(E - e0, BIN_CHUNK);
    for (int b = t; b < NB; b += 256) lhist[b] = 0;
    __syncthreads();
    for (int i = t; i < cnt; i += 256) {
        int n = idx0[e0 + i];
        int m = idx1[e0 + i];
        int bk = n >> BIN_SH;
        sbk[i] = (unsigned char)bk;
        svals[i] = (m << BIN_SH) | (n & ((1 << BIN_SH) - 1));
        atomicAdd(&lhist[bk], 1);
    }
    __syncthreads();
    for (int b = t; b < NB; b += 256) {
        int h = lhist[b];
        int base = h ? atomicAdd(&bfill[b], h) : 0;
        lbase[b] = boff[b] + base;
        lhist[b] = 0;
    }
    __syncthreads();
    for (int i = t; i < cnt; i += 256) {
        int bk = sbk[i];
        int r = atomicAdd(&lhist[bk], 1);
        staging[lbase[bk] + r] = svals[i];
    }
}

// ---------------- merged: binB (staging->CSR) + slot table + deg0-weighted A moments ----------------
__global__ __launch_bounds__(256) void k_build2(
    const int* __restrict__ rowptr, const int* __restrict__ staging,
    int* __restrict__ sidx1, int2* __restrict__ slots,
    const uint2* __restrict__ A16, const int* __restrict__ hist0,
    float* __restrict__ gsum, float* __restrict__ gsq,
    int E, int N, int per_slot, int nslots, int NB, int SL_BLOCKS)
{
    __shared__ float4 lsm4[256], lsq4[256];
    __shared__ int rp[257];
    __shared__ int lcnt[256];
    const int t = threadIdx.x;
    const int bid = blockIdx.x;

    if (bid < NB) {                                  // ---- binB: bucket -> CSR ----
        const int n0 = bid << BIN_SH;
        const int nn = min(N - n0, 256);
        for (int j = t; j <= nn; j += 256) rp[j] = rowptr[n0 + j];
        lcnt[t] = 0;
        __syncthreads();
        const int s0 = rp[0], s1 = rp[nn];
        for (int i = s0 + t; i < s1; i += 256) {
            int v = staging[i];
            int nl = v & 255;
            int r = atomicAdd(&lcnt[nl], 1);
            sidx1[rp[nl] + r] = v & 0xffffff00;      // == idx1 << 8 (byte offset)
        }
        return;
    }
    if (bid < NB + SL_BLOCKS) {                      // ---- slot->node bounds ----
        int s = (bid - NB) * 256 + t;
        if (s > nslots) return;
        long base = (long)s * per_slot;
        if (base >= E) { slots[s] = (int2){N, N - 1}; return; }
        int e0 = (int)base;
        int lo = 0, hi = N;
        while (lo + 1 < hi) { int mid = (lo + hi) >> 1; if (rowptr[mid] <= e0) lo = mid; else hi = mid; }
        int nS = lo;
        int nA = 0;
        if (e0 > 0) {
            lo = 0; hi = N;
            while (lo + 1 < hi) { int mid = (lo + hi) >> 1; if (rowptr[mid] < e0) lo = mid; else hi = mid; }
            nA = hi;
        }
        slots[s] = (int2){nA, nS};
        return;
    }
    // ---- rowstats: sum(deg0*a), sum(deg0*a^2) ----
    const int s = t >> 6, l = t & 63;
    const int rb = bid - NB - SL_BLOCKS;
    const int w0 = rb * 4 + s;
    const int nw = (gridDim.x - NB - SL_BLOCKS) * 4;
    f32x2 smF = {0.f,0.f}, smC = {0.f,0.f}, sqF = {0.f,0.f}, sqC = {0.f,0.f};
    for (int n = w0; n < N; n += nw) {
        float dg = (float)hist0[n];
        uint2 a8 = A16[(size_t)n * 64 + l];
        f32x2 aF = {bflo(a8.x), bfhi(a8.x)};
        f32x2 aC = {bflo(a8.y), bfhi(a8.y)};
        f32x2 dF = aF * dg;
        f32x2 dC = aC * dg;
        smF += dF; smC += dC;
        sqF = pk_fma2(dF, aF, sqF);
        sqC = pk_fma2(dC, aC, sqC);
    }
    lsm4[t] = (float4){smF.x, smF.y, smC.x, smC.y};
    lsq4[t] = (float4){sqF.x, sqF.y, sqC.x, sqC.y};
    __syncthreads();
    const float* fm = (const float*)lsm4;
    const float* fq = (const float*)lsq4;
    float vs = fm[t] + fm[256 + t] + fm[512 + t] + fm[768 + t];
    float vq = fq[t] + fq[256 + t] + fq[512 + t] + fq[768 + t];
    atomicAdd(&gsum[t], vs);
    atomicAdd(&gsq[t], vq);
}

// ---------------- BN1 edge stats: sum(c), sum(c^2), cross 2*sum(a*csr) ----------------
// Scalarized: slot/cur_n/bound in SGPRs; node-switch guard is scalar branch.
__global__ __launch_bounds__(256) void k_stats(const uint2* __restrict__ A16, const unsigned char* __restrict__ Cp8b,
                                               const int* __restrict__ rowptr, const int* __restrict__ sidx1,
                                               const int2* __restrict__ slots,
                                               float* __restrict__ gsum, float* __restrict__ gsq,
                                               int E, int N, int per_slot) {
    __shared__ float4 lsm4[256], lsq4[256];
    const int t = threadIdx.x;
    const int l = t & 63;
    const int wid = __builtin_amdgcn_readfirstlane(t >> 6);
    const int slot = blockIdx.x * 4 + wid;
    const unsigned lo4 = (unsigned)(l << 2);
    const long base = (long)slot * per_slot;
    const int e0 = (int)min((long)E, base);
    const int e1 = (int)min((long)E, base + per_slot);
    f32x2 smF = {0.f,0.f}, smC = {0.f,0.f};
    f32x2 sqF = {0.f,0.f}, sqC = {0.f,0.f};        // accumulates c^2 AND 2*a*csr
    f32x2 csrF = {0.f,0.f}, csrC = {0.f,0.f};
    f32x2 aF2 = {0.f,0.f}, aC2 = {0.f,0.f};        // 2*a of current node
    int cur_n = 0, bound = 0;

    auto flush = [&]() {
        smF += csrF; smC += csrC;
        sqF = pk_fma2(aF2, csrF, sqF);
        sqC = pk_fma2(aC2, csrC, sqC);
        csrF = (f32x2){0.f,0.f}; csrC = (f32x2){0.f,0.f};
    };
    auto loadA = [&](int n) {
        uint2 a8 = A16[(size_t)n * 64 + l];
        aF2 = (f32x2){bflo(a8.x) * 2.f, bfhi(a8.x) * 2.f};
        aC2 = (f32x2){bflo(a8.y) * 2.f, bfhi(a8.y) * 2.f};
    };

    if (e0 < e1) {
        cur_n = __builtin_amdgcn_readfirstlane(slots[slot].y);
        bound = __builtin_amdgcn_readfirstlane(rowptr[cur_n + 1]);
        loadA(cur_n);
    }

    auto proc = [&](int e, unsigned p) {
        if (e >= bound) {                            // scalar branch (e, bound in SGPR)
            flush();
            do { cur_n++; bound = __builtin_amdgcn_readfirstlane(rowptr[cur_n + 1]); } while (bound <= e);
            loadA(cur_n);
        }
        f32x2 vf, vc;
        fp8pair(p, vf, vc);
        csrF += vf; csrC += vc;
        sqF = pk_fma2(vf, vf, sqF);
        sqC = pk_fma2(vc, vc, sqC);
    };

    int e = e0;
    for (; e + 8 <= e1; e += 8) {
        int4 mm0 = *(const int4*)(sidx1 + e);
        int4 mm1 = *(const int4*)(sidx1 + e + 4);
        unsigned p0 = *(const unsigned*)(Cp8b + ((unsigned)mm0.x + lo4));
        unsigned p1 = *(const unsigned*)(Cp8b + ((unsigned)mm0.y + lo4));
        unsigned p2 = *(const unsigned*)(Cp8b + ((unsigned)mm0.z + lo4));
        unsigned p3 = *(const unsigned*)(Cp8b + ((unsigned)mm0.w + lo4));
        unsigned p4 = *(const unsigned*)(Cp8b + ((unsigned)mm1.x + lo4));
        unsigned p5 = *(const unsigned*)(Cp8b + ((unsigned)mm1.y + lo4));
        unsigned p6 = *(const unsigned*)(Cp8b + ((unsigned)mm1.z + lo4));
        unsigned p7 = *(const unsigned*)(Cp8b + ((unsigned)mm1.w + lo4));
        proc(e, p0); proc(e + 1, p1); proc(e + 2, p2); proc(e + 3, p3);
        proc(e + 4, p4); proc(e + 5, p5); proc(e + 6, p6); proc(e + 7, p7);
    }
    for (; e < e1; e++) proc(e, *(const unsigned*)(Cp8b + ((unsigned)sidx1[e] + lo4)));
    flush();

    lsm4[t] = (float4){smF.x, smF.y, smC.x, smC.y};
    lsq4[t] = (float4){sqF.x, sqF.y, sqC.x, sqC.y};
    __syncthreads();
    const float* fm = (const float*)lsm4;
    const float* fq = (const float*)lsq4;
    float vs = fm[t] + fm[256 + t] + fm[512 + t] + fm[768 + t];
    float vq = fq[t] + fq[256 + t] + fq[512 + t] + fq[768 + t];
    atomicAdd(&gsum[t], vs);
    atomicAdd(&gsq[t], vq);
}

// ---------------- fused BN1-finalize + msg + segment softmax ----------------
// One node per wave, fully scalarized: e0/e1 via readfirstlane, 8-deep
// scalar-guarded prefetch, gathers = global_load v,v_lo4,s[base].
__global__ __launch_bounds__(256) void k_aggr(const uint2* __restrict__ A16, const unsigned char* __restrict__ Cp8b,
                                              const int* __restrict__ rowptr, const int* __restrict__ sidx1,
                                              const float* __restrict__ bn1_sum, const float* __restrict__ bn1_sq,
                                              const float* __restrict__ g1, const float* __restrict__ b1,
                                              const float* __restrict__ tptr, unsigned* __restrict__ out,
                                              float invE, int N) {
    const int t = threadIdx.x;
    const int l = t & 63;
    const int wid = __builtin_amdgcn_readfirstlane(t >> 6);
    const int n = blockIdx.x * 4 + wid;
    if (n >= N) return;

    const int e0 = __builtin_amdgcn_readfirstlane(rowptr[n]);
    const int e1 = __builtin_amdgcn_readfirstlane(rowptr[n + 1]);

    const float tt = tptr[0];
    const float4 sum4 = ((const float4*)bn1_sum)[l];
    const float4 sq4  = ((const float4*)bn1_sq)[l];
    const float2 gf = ((const float2*)g1)[l];
    const float2 gc = ((const float2*)(g1 + 128))[l];
    const float2 bf2 = ((const float2*)b1)[l];
    const float2 bc2 = ((const float2*)(b1 + 128))[l];
    auto mkss = [&](float sum, float sq, float gg, float bb, float& sc, float& sh) {
        float mu = sum * invE;
        float var = sq * invE - mu * mu;
        sc = gg * rsqrtf(var + EPS_BN);
        sh = fmaf(-mu, sc, bb);
    };
    float scx, shx, scy, shy, scz, shz, scw, shw;
    mkss(sum4.x, sq4.x, gf.x, bf2.x, scx, shx);
    mkss(sum4.y, sq4.y, gf.y, bf2.y, scy, shy);
    mkss(sum4.z, sq4.z, gc.x, bc2.x, scz, shz);
    mkss(sum4.w, sq4.w, gc.y, bc2.y, scw, shw);
    const f32x2 sF  = {-scx * LOG2E, -scy * LOG2E};
    const f32x2 sC  = { scz * LOG2E,  scw * LOG2E};

    uint2 a8 = A16[(size_t)n * 64 + l];
    f32x2 aF = {bflo(a8.x), bfhi(a8.x)}, aC = {bflo(a8.y), bfhi(a8.y)};
    const f32x2 bF = pk_fma2(aF, sF, (f32x2){-shx * LOG2E, -shy * LOG2E});
    const f32x2 bC = pk_fma2(aC, sC, (f32x2){ shz * LOG2E,  shw * LOG2E});

    if (e0 >= e1) { out[(size_t)n * 64 + l] = 0u; return; }

    const unsigned lo4 = (unsigned)(l << 2);
    f32x2 den = {0.f,0.f}, num = {0.f,0.f};

    auto G = [&](int e) -> unsigned {
        return *(const unsigned*)(Cp8b + ((unsigned)sidx1[e] + lo4));
    };
    auto procg = [&](unsigned p) {
        f32x2 vf, vc;
        fp8pair(p, vf, vc);
        f32x2 argf = pk_fma2(vf, sF, bF);            // -zf_hat * log2e
        f32x2 argc = pk_fma2(vc, sC, bC);            //  zc_hat * log2e
        f32x2 ef = {fexp2(argf.x), fexp2(argf.y)};
        f32x2 uu = {fexp2(argc.x), fexp2(argc.y)};
        f32x2 d1 = ef + 1.f;
        f32x2 u1 = uu + 1.f;
        f32x2 sig = {__builtin_amdgcn_rcpf(d1.x), __builtin_amdgcn_rcpf(d1.y)};
        f32x2 lg = {flog2(u1.x), flog2(u1.y)};
        f32x2 M = sig * lg;
        f32x2 tM = M * tt;
        f32x2 w = {fexp2(tM.x), fexp2(tM.y)};
        den += w;
        num = pk_fma2(M, w, num);
    };

    const int cnt = e1 - e0;                         // scalar
    unsigned cur[8];
#pragma unroll
    for (int i = 0; i < 8; i++)
        if (i < cnt) cur[i] = G(e0 + i);             // scalar-guarded loads

    int e = e0;
    while (e + 8 < e1) {                             // full group of 8 present
        unsigned nxt[8];
#pragma unroll
        for (int i = 0; i < 8; i++)
            if (e + 8 + i < e1) nxt[i] = G(e + 8 + i);   // scalar-guarded prefetch
#pragma unroll
        for (int i = 0; i < 8; i++) procg(cur[i]);
#pragma unroll
        for (int i = 0; i < 8; i++) cur[i] = nxt[i];
        e += 8;
    }
    const int rem = e1 - e;                          // 1..8, scalar
#pragma unroll
    for (int i = 0; i < 8; i++)
        if (i < rem) procg(cur[i]);                  // scalar-branch tail

    float ox = LN2 * num.x * __builtin_amdgcn_rcpf(den.x);
    float oy = LN2 * num.y * __builtin_amdgcn_rcpf(den.y);
    out[(size_t)n * 64 + l] = pack2bf(ox, oy);
}

// ---------------- BN2 stats (packed-word loads + LDS reduce) ----------------
__global__ __launch_bounds__(256) void k_bn2stats(const unsigned* __restrict__ outw, float* __restrict__ sum,
                                                  float* __restrict__ sq, int N) {
    __shared__ float4 ls[256];
    const int t = threadIdx.x;
    const int w = t & 63;
    const int rg = t >> 6;
    f32x2 sm = {0.f,0.f}, s2 = {0.f,0.f};
    for (int n = blockIdx.x * 4 + rg; n < N; n += gridDim.x * 4) {
        unsigned v = outw[(size_t)n * 64 + w];
        f32x2 x = {bflo(v), bfhi(v)};
        sm += x;
        s2 = pk_fma2(x, x, s2);
    }
    ls[t] = (float4){sm.x, sm.y, s2.x, s2.y};
    __syncthreads();
    if (t < 64) {
        float4 a = ls[t], b = ls[t + 64], c = ls[t + 128], d = ls[t + 192];
        atomicAdd(&sum[2 * w],     a.x + b.x + c.x + d.x);
        atomicAdd(&sum[2 * w + 1], a.y + b.y + c.y + d.y);
        atomicAdd(&sq[2 * w],      a.z + b.z + c.z + d.z);
        atomicAdd(&sq[2 * w + 1],  a.w + b.w + c.w + d.w);
    }
}

// ---------------- fused BN2-finalize + residual+softplus + mean-pool (bf16 inputs) ----------------
template<int SPLIT>
__global__ __launch_bounds__(128) void k_h2pool(const unsigned short* __restrict__ out,
                                                const unsigned short* __restrict__ h,
                                                const int* __restrict__ gptr, const int* __restrict__ gnodes,
                                                const float* __restrict__ bn2_sum, const float* __restrict__ bn2_sq,
                                                const float* __restrict__ g2, const float* __restrict__ b2,
                                                float* __restrict__ pooled, float invN) {
    const int g = blockIdx.x & 127;
    const int sp = blockIdx.x >> 7;
    const int c = threadIdx.x;
    float mu = bn2_sum[c] * invN;
    float var = bn2_sq[c] * invN - mu * mu;
    float sc = g2[c] * rsqrtf(var + EPS_BN);
    float sh = fmaf(-mu, sc, b2[c]);
    const int i0 = gptr[g], i1 = gptr[g + 1];
    float acc = 0.f;
    for (int i = i0 + sp; i < i1; i += SPLIT) {
        int n = gnodes[i];
        float v = fmaf(bfu16(out[(size_t)n * 128 + c]), sc, sh) + bfu16(h[(size_t)n * 128 + c]);
        acc += softplus_fast(v);
    }
    if (acc != 0.f) atomicAdd(&pooled[g * 128 + c], acc);
}

// ---------------- head ----------------
__global__ __launch_bounds__(256) void k_head(const float* __restrict__ pooled, const int* __restrict__ gcount,
                                              const float* __restrict__ l1w, const float* __restrict__ l1b,
                                              const float* __restrict__ outw, const float* __restrict__ outb,
                                              float* __restrict__ dout) {
    __shared__ float p[128];
    __shared__ float red[256];
    const int g = blockIdx.x;
    const int j = threadIdx.x;
    if (j < 128) {
        float cnt = (float)max(gcount[g], 1);
        p[j] = pooled[g * 128 + j] / cnt;
    }
    __syncthreads();
    float acc = l1b[j];
    for (int k = 0; k < 128; k++) acc = fmaf(p[k], l1w[k * 256 + j], acc);
    red[j] = softplus_fast(acc) * outw[j];
    __syncthreads();
    for (int s = 128; s > 0; s >>= 1) {
        if (j < s) red[j] += red[j + s];
        __syncthreads();
    }
    if (j == 0) dout[g] = red[0] + outb[0];
}

// ---------------- launch ----------------
extern "C" void kernel_launch(void* const* d_in, const int* in_sizes, int n_in,
                              void* d_out, int out_size, void* d_ws, size_t ws_size,
                              hipStream_t stream) {
    const float* x        = (const float*)d_in[0];
    const float* hedge    = (const float*)d_in[1];
    const int*   iri      = (const int*)d_in[2];
    const int*   batch    = (const int*)d_in[3];
    const float* embed_w  = (const float*)d_in[5];
    const float* embed_b  = (const float*)d_in[6];
    const float* bembed_w = (const float*)d_in[7];
    const float* bembed_b = (const float*)d_in[8];
    const float* lin_w    = (const float*)d_in[9];
    const float* lin_b    = (const float*)d_in[10];
    const float* bn1_g    = (const float*)d_in[11];
    const float* bn1_b    = (const float*)d_in[12];
    const float* bn2_g    = (const float*)d_in[13];
    const float* bn2_b    = (const float*)d_in[14];
    const float* aggr_t   = (const float*)d_in[15];
    const float* l1_w     = (const float*)d_in[16];
    const float* l1_b     = (const float*)d_in[17];
    const float* out_w    = (const float*)d_in[18];
    const float* out_b    = (const float*)d_in[19];

    const int N   = in_sizes[0] / 92;
    const int NHE = in_sizes[1] / 40;
    const int E   = in_sizes[2] / 3;
    const int* idx0 = iri;
    const int* idx1 = iri + E;

    float* ws = (float*)d_ws;
    size_t off = 0;
    auto alloc = [&](size_t elems) -> float* {
        float* p = ws + off;
        off += (elems + 63) & ~(size_t)63;
        return p;
    };
    unsigned short* h16 = (unsigned short*)alloc((size_t)N * 64);   // N*128 bf16
    uint2* A16    = (uint2*)alloc((size_t)N * 128);                 // N*256 bf16 packed
    unsigned* Cp8 = (unsigned*)alloc((size_t)NHE * 64);             // NHE*256 fp8 packed
    unsigned short* embB  = (unsigned short*)alloc(6144);
    unsigned short* bembB = (unsigned short*)alloc(4096);
    unsigned short* waB   = (unsigned short*)alloc(16384);
    unsigned short* wcB   = (unsigned short*)alloc(16384);
    int*   rowptr = (int*)alloc((size_t)N + 1);
    int*   rloc   = (int*)alloc((size_t)N);
    int*   bsum   = (int*)alloc(256);
    int*   boff   = (int*)alloc(260);
    int*   sidx1  = (int*)alloc((size_t)E + 8);
    int*   staging = (int*)alloc((size_t)E + 8);
    int*   gptr   = (int*)alloc(129);
    int*   gnodes = (int*)alloc((size_t)N);
    unsigned* outbuf = (unsigned*)alloc((size_t)N * 64);            // N*128 bf16
    int2*  slots  = (int2*)alloc(2 * 8200);                         // slot->node bounds (+sentinel)
    // contiguous zero region
    float* zbase  = ws + off;
    int*   hist   = (int*)alloc((size_t)N);
    int*   bfill  = (int*)alloc(256);
    int*   gfill  = (int*)alloc(128);
    float* bn1_sum = alloc(256);
    float* bn1_sq  = alloc(256);
    float* bn2_sum = alloc(128);
    float* bn2_sq  = alloc(128);
    float* pooled  = alloc(128 * 128);
    int*   gcount  = (int*)alloc(128);
    size_t zbytes = (size_t)((ws + off) - zbase) * sizeof(float);
    (void)ws_size;  // ~81MB; fit verified

    hipMemsetAsync(zbase, 0, zbytes, stream);

    // frag-major bf16 weight prep + fused MFMA GEMM chains.
    // GEMM1 also builds hist0 (idx0 degree); GEMM2 builds gcount.
    k_prepw<<<320, 256, 0, stream>>>(embed_w, bembed_w, lin_w, embB, bembB, waB, wcB);
    const int mtN   = (N + 31) / 32;
    const int mtNHE = (NHE + 31) / 32;
    mfma_fused<92, 3, 1><<<mtN, 256, 0, stream>>>(x, embB, embed_b, waB, lin_b, h16, A16, N,
                                                  idx0, hist, E);
    mfma_fused<40, 2, 2><<<mtNHE, 256, 0, stream>>>(hedge, bembB, bembed_b, wcB, nullptr, nullptr, Cp8, NHE,
                                                    batch, gcount, N);

    // hierarchical prefix scan (bucket = 256 nodes)
    const int NB = (N + 255) >> BIN_SH;
    k_scanA<<<NB, 256, 0, stream>>>(hist, rloc, bsum, N);
    k_scanB<<<1, 256, 0, stream>>>(bsum, boff, gcount, gptr, NB);

    // bucket pass A + gnodes scatter + rowptr materialize
    const int EB = (E + BIN_CHUNK - 1) / BIN_CHUNK;
    const int GB = (N + 255) / 256;
    k_binA<<<EB + GB + NB, 256, 0, stream>>>(idx0, idx1, boff, rloc, rowptr, bfill, staging,
                                             batch, gptr, gfill, gnodes, E, N, NB, EB, GB);

    // unified slot geometry for k_stats (8 | per_slot)
    const int EDGE_BLOCKS = 2048;
    const int NSLOTS = EDGE_BLOCKS * 4;
    int per_slot = ((E + NSLOTS - 1) / NSLOTS + 7) & ~7;
    int nslots_used = (E + per_slot - 1) / per_slot;

    // merged binB + slot table + deg0-weighted A moments
    const int SL_BLOCKS = (nslots_used + 1 + 255) / 256;
    const int RS_BLOCKS = 256;
    k_build2<<<NB + SL_BLOCKS + RS_BLOCKS, 256, 0, stream>>>(
        rowptr, staging, sidx1, slots, A16, hist, bn1_sum, bn1_sq,
        E, N, per_slot, nslots_used, NB, SL_BLOCKS);

    // BN1 edge stats (C moments + cross term)
    k_stats<<<EDGE_BLOCKS, 256, 0, stream>>>(A16, (const unsigned char*)Cp8, rowptr, sidx1, slots,
                                             bn1_sum, bn1_sq, E, N, per_slot);

    // fused BN1-finalize + message + softmax aggregation (1 node/wave, scalarized)
    k_aggr<<<(N + 3) / 4, 256, 0, stream>>>(A16, (const unsigned char*)Cp8, rowptr, sidx1,
                                            bn1_sum, bn1_sq, bn1_g, bn1_b, aggr_t, outbuf,
                                            1.0f / (float)E, N);

    // BN2 stats + fused finalize/residual/softplus/pool
    k_bn2stats<<<256, 256, 0, stream>>>((const unsigned*)outbuf, bn2_sum, bn2_sq, N);
    k_h2pool<16><<<128 * 16, 128, 0, stream>>>((const unsigned short*)outbuf, h16, gptr, gnodes,
                                               bn2_sum, bn2_sq, bn2_g, bn2_b, pooled, 1.0f / (float)N);

    // head
    k_head<<<128, 256, 0, stream>>>(pooled, gcount, l1_w, l1_b, out_w, out_b, (float*)d_out);
}